// Round 3
// baseline (454.391 us; speedup 1.0000x reference)
//
#include <hip/hip_runtime.h>

constexpr int NSRC = 50000;
constexpr int NTGT = 10000;
constexpr int NEDGE = 250000;
constexpr int NLBL = 200000;
constexpr int HD = 64;     // hidden dim (per head)
constexpr int NH = 4;      // heads
constexpr int QK = 256;    // HD*NH
constexpr int NTOT = NSRC + NTGT;

typedef __attribute__((ext_vector_type(8))) short bf16x8;
typedef __attribute__((ext_vector_type(4))) float f32x4;

// ---------------- bf16 helpers ----------------
__device__ __forceinline__ unsigned short f2bf(float f) {
  unsigned u = __float_as_uint(f);
  u += 0x7FFFu + ((u >> 16) & 1u);   // round-to-nearest-even
  return (unsigned short)(u >> 16);
}
__device__ __forceinline__ float bf2f(unsigned short b) {
  return __uint_as_float((unsigned)b << 16);
}
struct bf4 { unsigned short x, y, z, w; };
__device__ __forceinline__ float4 bf4_to_f4(bf4 u) {
  return make_float4(bf2f(u.x), bf2f(u.y), bf2f(u.z), bf2f(u.w));
}
__device__ __forceinline__ float lo_f(unsigned u) { return __uint_as_float(u << 16); }
__device__ __forceinline__ float hi_f(unsigned u) { return __uint_as_float(u & 0xFFFF0000u); }

// ---------------- DPP 16-lane sum reduction (no LDS pipe, pure VALU) ----------------
template<int CTRL>
__device__ __forceinline__ float dpp_addf(float x) {
  int p = __builtin_amdgcn_update_dpp(0, __float_as_int(x), CTRL, 0xf, 0xf, true);
  return x + __int_as_float(p);
}
__device__ __forceinline__ float red16(float x) {
  x = dpp_addf<0xB1>(x);    // + lane^1 within quad
  x = dpp_addf<0x4E>(x);    // + lane^2 within quad
  x = dpp_addf<0x141>(x);   // + mirrored half-row (combines quads)
  x = dpp_addf<0x140>(x);   // + mirrored row (combines halves)
  return x;                 // all 16 lanes of the row hold the row sum
}

// ---------------- fused setup: weight transpose + feature gather + counts zero ----------------
__global__ __launch_bounds__(256) void setup_kernel(
    const float* __restrict__ Wq, const float* __restrict__ Wk, const float* __restrict__ Wv,
    unsigned short* __restrict__ Wtq, unsigned short* __restrict__ Wtk, unsigned short* __restrict__ Wtv,
    const float* __restrict__ semb, const int* __restrict__ sids,
    const float* __restrict__ temb, const int* __restrict__ tids,
    float* __restrict__ xs, unsigned short* __restrict__ xsb,
    float* __restrict__ xt, unsigned short* __restrict__ xtb,
    int* __restrict__ counts, int nGatherBlk) {
  __shared__ float tile[64][65];
  int b = blockIdx.x;
  int t = threadIdx.x;
  if (b < 48) {
    int mat = b >> 2, ct = b & 3;
    int grp = mat >> 2, p = mat & 3;
    const float* W = (grp == 0) ? Wq : (grp == 1) ? Wk : Wv;
    unsigned short* Wt = (grp == 0) ? Wtq : (grp == 1) ? Wtk : Wtv;
    W += (size_t)p * 16384;
    Wt += (size_t)p * 16384;
    int c = t & 63, r4 = t >> 6;
    for (int rr = 0; rr < 64; rr += 4)
      tile[rr + r4][c] = W[(size_t)(rr + r4) * 256 + ct * 64 + c];
    __syncthreads();
    for (int rr = 0; rr < 64; rr += 4) {
      int nloc = rr + r4;
      Wt[(size_t)(ct * 64 + nloc) * 64 + c] = f2bf(tile[c][nloc]);
    }
  } else if (b < 48 + nGatherBlk) {
    int i = (b - 48) * 256 + t;
    if (i < NSRC * HD) {
      float v = semb[(size_t)sids[i >> 6] * HD + (i & 63)];
      xs[i] = v;
      xsb[i] = f2bf(v);
    } else if (i < NTOT * HD) {
      int j = i - NSRC * HD;
      float v = temb[(size_t)tids[j >> 6] * HD + (j & 63)];
      xt[j] = v;
      xtb[j] = f2bf(v);
    }
  } else {
    int i = (b - 48 - nGatherBlk) * 256 + t;
    if (i < NTOT) counts[i] = 0;
  }
}

// ---------------- CSR build (both edge sets, concatenated counts) ----------------

__global__ __launch_bounds__(256) void hist_all_kernel(const int* __restrict__ e_st, const int* __restrict__ e_ts,
                                                       int* __restrict__ counts) {
  int i = blockIdx.x * 256 + threadIdx.x;
  if (i < NEDGE) atomicAdd(&counts[e_st[NEDGE + i]], 1);
  else if (i < 2 * NEDGE) atomicAdd(&counts[NTGT + e_ts[NEDGE + (i - NEDGE)]], 1);
}

__global__ __launch_bounds__(256) void scan1_kernel(const int* __restrict__ counts, int* __restrict__ incl,
                                                    int* __restrict__ blocksums, int n) {
  __shared__ int wtot[4];
  int t = threadIdx.x;
  int i0 = blockIdx.x * 1024 + t * 4;
  int e0 = (i0 + 0 < n) ? counts[i0 + 0] : 0;
  int e1 = (i0 + 1 < n) ? counts[i0 + 1] : 0;
  int e2 = (i0 + 2 < n) ? counts[i0 + 2] : 0;
  int e3 = (i0 + 3 < n) ? counts[i0 + 3] : 0;
  int s0 = e0, s1 = s0 + e1, s2 = s1 + e2, s3 = s2 + e3;
  int tsum = s3;
  int inc = tsum;
#pragma unroll
  for (int o = 1; o < 64; o <<= 1) {
    int u = __shfl_up(inc, o, 64);
    if ((t & 63) >= o) inc += u;
  }
  int wave = t >> 6;
  if ((t & 63) == 63) wtot[wave] = inc;
  __syncthreads();
  int woff = 0;
#pragma unroll
  for (int w_ = 0; w_ < 4; ++w_) if (w_ < wave) woff += wtot[w_];
  int toff = woff + inc - tsum;
  if (i0 + 0 < n) incl[i0 + 0] = toff + s0;
  if (i0 + 1 < n) incl[i0 + 1] = toff + s1;
  if (i0 + 2 < n) incl[i0 + 2] = toff + s2;
  if (i0 + 3 < n) incl[i0 + 3] = toff + s3;
  if (t == 255) blocksums[blockIdx.x] = woff + inc;
}

__global__ __launch_bounds__(64) void scan2_kernel(const int* __restrict__ blocksums, int* __restrict__ boff, int nb) {
  int t = threadIdx.x;
  int v = (t < nb) ? blocksums[t] : 0;
  int inc = v;
#pragma unroll
  for (int o = 1; o < 64; o <<= 1) {
    int u = __shfl_up(inc, o, 64);
    if (t >= o) inc += u;
  }
  if (t < nb) boff[t] = inc - v;
}

__global__ __launch_bounds__(256) void scan3_kernel(const int* __restrict__ incl, const int* __restrict__ counts,
                                                    const int* __restrict__ boff, int* __restrict__ rp_st,
                                                    int* __restrict__ rp_ts, int* __restrict__ cursor) {
  int i = blockIdx.x * 256 + threadIdx.x;
  if (i < NTOT) {
    int val = incl[i] + boff[i >> 10];
    if (i < NTGT) {
      rp_st[i + 1] = val;
      cursor[i] = val - counts[i];
      if (i == 0) rp_st[0] = 0;
    } else {
      int v2 = val - NEDGE;
      rp_ts[i - NTGT + 1] = v2;
      cursor[i] = v2 - counts[i];
      if (i == NTGT) rp_ts[0] = 0;
    }
  }
}

__global__ __launch_bounds__(256) void scatter_all_kernel(const int* __restrict__ e_st, const int* __restrict__ e_ts,
                                                          int* __restrict__ cursor, int* __restrict__ es_st,
                                                          int* __restrict__ es_ts) {
  int i = blockIdx.x * 256 + threadIdx.x;
  if (i < NEDGE) {
    int d = e_st[NEDGE + i];
    int p = atomicAdd(&cursor[d], 1);
    es_st[p] = e_st[i];
  } else if (i < 2 * NEDGE) {
    int j = i - NEDGE;
    int d = e_ts[NEDGE + j];
    int p = atomicAdd(&cursor[NTGT + d], 1);
    es_ts[p] = e_ts[j];
  }
}

// ---------------- MFMA projection dispatch per layer (kv + q only — R12-proven) ----------------
__global__ __launch_bounds__(256) void proj_all(
    const unsigned short* __restrict__ xsb, const unsigned short* __restrict__ xtb,
    const unsigned short* __restrict__ Wtq, const unsigned short* __restrict__ Wtk,
    const unsigned short* __restrict__ Wtv,
    const float* __restrict__ bq, const float* __restrict__ bk, const float* __restrict__ bv,
    unsigned int* __restrict__ kv_big, unsigned short* __restrict__ q_big,
    unsigned int* __restrict__ kv_small, unsigned short* __restrict__ q_small,
    int p_st, int p_ts) {
  constexpr int B1 = NSRC / 16;   // 3125
  constexpr int B2 = NTGT / 16;   // 625
  int b = blockIdx.x;
  int w = threadIdx.x >> 6, l = threadIdx.x & 63;
  int m = l & 15, qd = l >> 4;
  const unsigned short* xb; const unsigned short* WtA; const unsigned short* WtB = nullptr;
  const float* biasA; const float* biasB = nullptr;
  unsigned int* okv = nullptr; unsigned short* oq = nullptr;
  int R0, mode;
  if (b < B1) {                       // kv_s (params p_st)
    xb = xsb; R0 = b * 16; mode = 0;
    WtA = Wtk + (size_t)p_st * 16384; biasA = bk + p_st * 256;
    WtB = Wtv + (size_t)p_st * 16384; biasB = bv + p_st * 256;
    okv = kv_big;
  } else if (b < B1 + B2) {           // kv_t (params p_ts)
    xb = xtb; R0 = (b - B1) * 16; mode = 0;
    WtA = Wtk + (size_t)p_ts * 16384; biasA = bk + p_ts * 256;
    WtB = Wtv + (size_t)p_ts * 16384; biasB = bv + p_ts * 256;
    okv = kv_small;
  } else if (b < 2 * B1 + B2) {       // q_s (params p_ts)
    xb = xsb; R0 = (b - B1 - B2) * 16; mode = 1;
    WtA = Wtq + (size_t)p_ts * 16384; biasA = bq + p_ts * 256;
    oq = q_big;
  } else {                            // q_t (params p_st)
    xb = xtb; R0 = (b - 2 * B1 - B2) * 16; mode = 1;
    WtA = Wtq + (size_t)p_st * 16384; biasA = bq + p_st * 256;
    oq = q_small;
  }
  const unsigned short* xrow = xb + (size_t)(R0 + m) * 64 + qd * 8;
  bf16x8 a_lo = *(const bf16x8*)xrow;
  bf16x8 a_hi = *(const bf16x8*)(xrow + 32);
  if (mode == 0) {
#pragma unroll
    for (int i = 0; i < 4; ++i) {
      int col = (w * 4 + i) * 16 + m;
      const unsigned short* wk = WtA + (size_t)col * 64 + qd * 8;
      const unsigned short* wv = WtB + (size_t)col * 64 + qd * 8;
      bf16x8 bk_lo = *(const bf16x8*)wk, bk_hi = *(const bf16x8*)(wk + 32);
      bf16x8 bv_lo = *(const bf16x8*)wv, bv_hi = *(const bf16x8*)(wv + 32);
      f32x4 ak = {0.f, 0.f, 0.f, 0.f}, av = {0.f, 0.f, 0.f, 0.f};
      ak = __builtin_amdgcn_mfma_f32_16x16x32_bf16(a_lo, bk_lo, ak, 0, 0, 0);
      ak = __builtin_amdgcn_mfma_f32_16x16x32_bf16(a_hi, bk_hi, ak, 0, 0, 0);
      av = __builtin_amdgcn_mfma_f32_16x16x32_bf16(a_lo, bv_lo, av, 0, 0, 0);
      av = __builtin_amdgcn_mfma_f32_16x16x32_bf16(a_hi, bv_hi, av, 0, 0, 0);
      float bkc = biasA[col], bvc = biasB[col];
      unsigned int* obase = okv + (size_t)(R0 + qd * 4) * 256 + col;
#pragma unroll
      for (int r = 0; r < 4; ++r) {
        unsigned word = (unsigned)f2bf(ak[r] + bkc) | ((unsigned)f2bf(av[r] + bvc) << 16);
        obase[(size_t)r * 256] = word;
      }
    }
  } else {
#pragma unroll
    for (int i = 0; i < 4; ++i) {
      int col = (w * 4 + i) * 16 + m;
      const unsigned short* wq = WtA + (size_t)col * 64 + qd * 8;
      bf16x8 b_lo = *(const bf16x8*)wq, b_hi = *(const bf16x8*)(wq + 32);
      f32x4 acc = {0.f, 0.f, 0.f, 0.f};
      acc = __builtin_amdgcn_mfma_f32_16x16x32_bf16(a_lo, b_lo, acc, 0, 0, 0);
      acc = __builtin_amdgcn_mfma_f32_16x16x32_bf16(a_hi, b_hi, acc, 0, 0, 0);
      float bc = biasA[col];
      unsigned short* obase = oq + (size_t)(R0 + qd * 4) * 256 + col;
#pragma unroll
      for (int r = 0; r < 4; ++r)
        obase[(size_t)r * 256] = f2bf(acc[r] + bc);
    }
  }
}

// ---------------- fused fp32 skip GEMM for both directions (LDS-tiled, R12-proven) ----------------
__global__ __launch_bounds__(256) void skip_all(const float* __restrict__ xs, const float* __restrict__ xt,
    const float* __restrict__ Wsk, const float* __restrict__ bsk,
    float* __restrict__ xs_nxt, float* __restrict__ xt_nxt, int p_st, int p_ts, int rtS) {
  __shared__ float Xt[64][68];
  __shared__ float Wl[64][68];
  __shared__ float bias[64];
  int t = threadIdx.x;
  const float* x; const float* W; const float* bb; float* o; int N, rbase;
  if ((int)blockIdx.x < rtS) {
    x = xs; N = NSRC; rbase = blockIdx.x * 64;
    W = Wsk + (size_t)p_ts * 4096; bb = bsk + p_ts * 64; o = xs_nxt;
  } else {
    x = xt; N = NTGT; rbase = (blockIdx.x - rtS) * 64;
    W = Wsk + (size_t)p_st * 4096; bb = bsk + p_st * 64; o = xt_nxt;
  }
#pragma unroll
  for (int i = 0; i < 4; ++i) {
    int slot = i * 256 + t;
    int row = slot >> 4;
    int k4 = slot & 15;
    float4 xv = make_float4(0.f, 0.f, 0.f, 0.f);
    if (rbase + row < N) xv = *(const float4*)&x[(size_t)(rbase + row) * 64 + k4 * 4];
    Xt[k4 * 4 + 0][row] = xv.x;
    Xt[k4 * 4 + 1][row] = xv.y;
    Xt[k4 * 4 + 2][row] = xv.z;
    Xt[k4 * 4 + 3][row] = xv.w;
  }
#pragma unroll
  for (int i = 0; i < 4; ++i) {
    int slot = i * 256 + t;
    int kk = slot >> 4;
    int c4 = slot & 15;
    float4 wv = *(const float4*)&W[(size_t)kk * 64 + c4 * 4];
    *(float4*)&Wl[kk][c4 * 4] = wv;
  }
  if (t < 64) bias[t] = bb[t];
  __syncthreads();

  int c0 = (t & 15) * 4;
  int r0 = (t >> 4) * 4;
  float acc[4][4];
#pragma unroll
  for (int i = 0; i < 4; ++i)
#pragma unroll
    for (int j = 0; j < 4; ++j) acc[i][j] = 0.f;
#pragma unroll 8
  for (int kk = 0; kk < 64; ++kk) {
    float4 xv = *(const float4*)&Xt[kk][r0];
    float4 wv = *(const float4*)&Wl[kk][c0];
    float xr[4] = {xv.x, xv.y, xv.z, xv.w};
    float wc[4] = {wv.x, wv.y, wv.z, wv.w};
#pragma unroll
    for (int i = 0; i < 4; ++i)
#pragma unroll
      for (int j = 0; j < 4; ++j) acc[i][j] = fmaf(xr[i], wc[j], acc[i][j]);
  }
#pragma unroll
  for (int i = 0; i < 4; ++i) {
    int row = rbase + r0 + i;
    if (row < N) {
      float4 ov;
      ov.x = acc[i][0] + bias[c0 + 0];
      ov.y = acc[i][1] + bias[c0 + 1];
      ov.z = acc[i][2] + bias[c0 + 2];
      ov.w = acc[i][3] + bias[c0 + 3];
      *(float4*)&o[(size_t)row * 64 + c0] = ov;
    }
  }
}

// ---------------- fused aggregation for BOTH directions ----------------
// R17: 4 nodes per wave, concatenated CSR edge walk. Monotone node crossings
// handled by a shift-register of {q, skip, boundary}; flush inline (skip values
// preloaded so flush never stalls). Amortizes per-wave overhead 4x — targets the
// ts half (deg~5) where serial chain overhead dominated (R14/R16: 73 us, VALU 42%,
// HBM 44% -> latency-bound).
__global__ __launch_bounds__(256) void agg_all(
    const unsigned short* __restrict__ q_small, const unsigned short* __restrict__ kv_big,
    const int* __restrict__ rp_st, const int* __restrict__ es_st,
    float* __restrict__ xt_nxt, unsigned short* __restrict__ xtb_nxt,
    const unsigned short* __restrict__ q_big, const unsigned short* __restrict__ kv_small,
    const int* __restrict__ rp_ts, const int* __restrict__ es_ts,
    float* __restrict__ xs_nxt, unsigned short* __restrict__ xsb_nxt,
    int relu, int stBlocks) {
  const unsigned short* q; const unsigned short* kvi; const int* rowptr; const int* eisrc;
  float* xout; unsigned short* xoutb; int nbase, N;
  int wv = threadIdx.x >> 6, l = threadIdx.x & 63;
  if ((int)blockIdx.x < stBlocks) {
    nbase = (blockIdx.x * 4 + wv) * 4;
    if (nbase >= NTGT) return;
    N = NTGT;
    q = q_small; kvi = kv_big; rowptr = rp_st; eisrc = es_st; xout = xt_nxt; xoutb = xtb_nxt;
  } else {
    nbase = ((blockIdx.x - stBlocks) * 4 + wv) * 4;
    if (nbase >= NSRC) return;
    N = NSRC;
    q = q_big; kvi = kv_small; rowptr = rp_ts; eisrc = es_ts; xout = xs_nxt; xoutb = xsb_nxt;
  }
  int j = l & 15;
  const float QS = 0.125f * 1.44269504088896340736f;   // 1/sqrt(H) * log2(e)

  // clamped node ids (N divisible by 4, clamps are belt-and-suspenders)
  int n0 = nbase;
  int n1 = (nbase + 1 < N) ? nbase + 1 : N - 1;
  int n2 = (nbase + 2 < N) ? nbase + 2 : N - 1;
  int n3 = (nbase + 3 < N) ? nbase + 3 : N - 1;

  // boundaries: rB = end of current node; shift on flush
  int rA = rowptr[n0];
  int rB = rowptr[n0 + 1];
  int rC = rowptr[((nbase + 2 < N) ? nbase + 2 : N)];
  int rD = rowptr[((nbase + 3 < N) ? nbase + 3 : N)];
  int rE = rowptr[((nbase + 4 < N) ? nbase + 4 : N)];

  // 4 q rows (scaled), 4 skip rows preloaded (flush never stalls)
  float4 q0 = bf4_to_f4(*(const bf4*)&q[(size_t)n0 * QK + l * 4]);
  float4 q1 = bf4_to_f4(*(const bf4*)&q[(size_t)n1 * QK + l * 4]);
  float4 q2 = bf4_to_f4(*(const bf4*)&q[(size_t)n2 * QK + l * 4]);
  float4 q3 = bf4_to_f4(*(const bf4*)&q[(size_t)n3 * QK + l * 4]);
  q0.x *= QS; q0.y *= QS; q0.z *= QS; q0.w *= QS;
  q1.x *= QS; q1.y *= QS; q1.z *= QS; q1.w *= QS;
  q2.x *= QS; q2.y *= QS; q2.z *= QS; q2.w *= QS;
  q3.x *= QS; q3.y *= QS; q3.z *= QS; q3.w *= QS;
  float4 sk0 = *(const float4*)&xout[(size_t)n0 * HD + j * 4];
  float4 sk1 = *(const float4*)&xout[(size_t)n1 * HD + j * 4];
  float4 sk2 = *(const float4*)&xout[(size_t)n2 * HD + j * 4];
  float4 sk3 = *(const float4*)&xout[(size_t)n3 * HD + j * 4];

  float lsum = 0.f;
  float4 acc = make_float4(0.f, 0.f, 0.f, 0.f);
  int cur = 0;

  auto FLUSH = [&]() {
    float inv = (lsum > 0.f) ? 1.f / lsum : 0.f;
    float4 r;
    r.x = acc.x * inv; r.y = acc.y * inv; r.z = acc.z * inv; r.w = acc.w * inv;
    r.x += __shfl_xor(r.x, 16, 64); r.x += __shfl_xor(r.x, 32, 64);
    r.y += __shfl_xor(r.y, 16, 64); r.y += __shfl_xor(r.y, 32, 64);
    r.z += __shfl_xor(r.z, 16, 64); r.z += __shfl_xor(r.z, 32, 64);
    r.w += __shfl_xor(r.w, 16, 64); r.w += __shfl_xor(r.w, 32, 64);
    int node = nbase + cur;
    if (l < 16 && node < N) {
      float4 o;
      o.x = sk0.x + 0.25f * r.x;
      o.y = sk0.y + 0.25f * r.y;
      o.z = sk0.z + 0.25f * r.z;
      o.w = sk0.w + 0.25f * r.w;
      if (relu) {
        o.x = fmaxf(o.x, 0.f); o.y = fmaxf(o.y, 0.f);
        o.z = fmaxf(o.z, 0.f); o.w = fmaxf(o.w, 0.f);
      }
      *(float4*)&xout[(size_t)node * HD + j * 4] = o;
      bf4 ob;
      ob.x = f2bf(o.x); ob.y = f2bf(o.y); ob.z = f2bf(o.z); ob.w = f2bf(o.w);
      *(bf4*)&xoutb[(size_t)node * HD + j * 4] = ob;
    }
    // shift registers (monotone crossings)
    q0 = q1; q1 = q2; q2 = q3;
    sk0 = sk1; sk1 = sk2; sk2 = sk3;
    rB = rC; rC = rD; rD = rE;
    acc = make_float4(0.f, 0.f, 0.f, 0.f);
    lsum = 0.f;
    cur++;
  };

  auto EDGE = [&](uint4 A, int eidx) {
    while (eidx >= rB) FLUSH();
    float t = q0.x * lo_f(A.x) + q0.y * lo_f(A.y) + q0.z * lo_f(A.z) + q0.w * lo_f(A.w);
    t = red16(t);
    float w = __builtin_amdgcn_exp2f(t);
    lsum += w;
    acc.x = fmaf(w, hi_f(A.x), acc.x);
    acc.y = fmaf(w, hi_f(A.y), acc.y);
    acc.z = fmaf(w, hi_f(A.z), acc.z);
    acc.w = fmaf(w, hi_f(A.w), acc.w);
  };

  int p = rA, pend = rE;
  for (; p + 4 <= pend; p += 4) {
    int s0 = eisrc[p], s1 = eisrc[p + 1], s2 = eisrc[p + 2], s3 = eisrc[p + 3];
    uint4 a0 = *(const uint4*)&kvi[(size_t)s0 * 512 + l * 8];
    uint4 a1 = *(const uint4*)&kvi[(size_t)s1 * 512 + l * 8];
    uint4 a2 = *(const uint4*)&kvi[(size_t)s2 * 512 + l * 8];
    uint4 a3 = *(const uint4*)&kvi[(size_t)s3 * 512 + l * 8];
    EDGE(a0, p);
    EDGE(a1, p + 1);
    EDGE(a2, p + 2);
    EDGE(a3, p + 3);
  }
  for (; p < pend; ++p) {
    int s0 = eisrc[p];
    uint4 a0 = *(const uint4*)&kvi[(size_t)s0 * 512 + l * 8];
    EDGE(a0, p);
  }
  while (cur < 4) FLUSH();
}

// ---------------- classifier: 16 lanes per pair, float4 loads ----------------
__global__ __launch_bounds__(256) void classifier_kernel(const float* __restrict__ xs, const float* __restrict__ xt,
    const int* __restrict__ ls, const int* __restrict__ lt, float* __restrict__ out, int n) {
  int g = blockIdx.x * 256 + threadIdx.x;
  int pair = g >> 4, j = g & 15;
  if (pair >= n) return;
  int a = ls[pair], b = lt[pair];
  float4 xa = *(const float4*)&xs[(size_t)a * HD + j * 4];
  float4 xb = *(const float4*)&xt[(size_t)b * HD + j * 4];
  float s = xa.x * xb.x + xa.y * xb.y + xa.z * xb.z + xa.w * xb.w;
  s = red16(s);
  if (j == 0) out[pair] = s;
}

// ---------------- launch ----------------
extern "C" void kernel_launch(void* const* d_in, const int* in_sizes, int n_in,
                              void* d_out, int out_size, void* d_ws, size_t ws_size,
                              hipStream_t stream) {
  const float* src_emb = (const float*)d_in[0];
  const float* tgt_emb = (const float*)d_in[1];
  const float* Wq = (const float*)d_in[2];
  const float* bq = (const float*)d_in[3];
  const float* Wk = (const float*)d_in[4];
  const float* bk = (const float*)d_in[5];
  const float* Wv = (const float*)d_in[6];
  const float* bv = (const float*)d_in[7];
  const float* Wsk = (const float*)d_in[8];
  const float* bsk = (const float*)d_in[9];
  const int* nid_s = (const int*)d_in[10];
  const int* nid_t = (const int*)d_in[11];
  const int* e_st = (const int*)d_in[12];
  const int* e_ts = (const int*)d_in[13];
  const int* e_lbl = (const int*)d_in[14];
  float* out = (float*)d_out;

  char* ws = (char*)d_ws;
  size_t off = 0;
  auto alloc = [&](size_t bytes) -> void* {
    void* p = ws + off;
    off += (bytes + 255) & ~(size_t)255;
    return p;
  };
  unsigned int*   kv_big   = (unsigned int*)alloc((size_t)NSRC * 256 * 4);   // st k/v packed words
  unsigned short* q_big    = (unsigned short*)alloc((size_t)NSRC * QK * 2);  // ts q
  unsigned int*   kv_small = (unsigned int*)alloc((size_t)NTGT * 256 * 4);   // ts k/v packed words
  unsigned short* q_small  = (unsigned short*)alloc((size_t)NTGT * QK * 2);  // st q
  float* xsA = (float*)alloc((size_t)NSRC * HD * 4);
  float* xsB = (float*)alloc((size_t)NSRC * HD * 4);
  float* xtA = (float*)alloc((size_t)NTGT * HD * 4);
  float* xtB = (float*)alloc((size_t)NTGT * HD * 4);
  unsigned short* xsAb = (unsigned short*)alloc((size_t)NSRC * HD * 2);
  unsigned short* xsBb = (unsigned short*)alloc((size_t)NSRC * HD * 2);
  unsigned short* xtAb = (unsigned short*)alloc((size_t)NTGT * HD * 2);
  unsigned short* xtBb = (unsigned short*)alloc((size_t)NTGT * HD * 2);
  unsigned short* Wtq = (unsigned short*)alloc((size_t)4 * 16384 * 2);
  unsigned short* Wtk = (unsigned short*)alloc((size_t)4 * 16384 * 2);
  unsigned short* Wtv = (unsigned short*)alloc((size_t)4 * 16384 * 2);
  int* rp_st = (int*)alloc((size_t)(NTGT + 1) * 4);
  int* es_st = (int*)alloc((size_t)NEDGE * 4);
  int* rp_ts = (int*)alloc((size_t)(NSRC + 1) * 4);
  int* es_ts = (int*)alloc((size_t)NEDGE * 4);
  int* cursor = (int*)alloc((size_t)NTOT * 4);
  int* counts = (int*)alloc((size_t)NTOT * 4);
  int* incl_buf = (int*)alloc((size_t)NTOT * 4);
  int* blocksums = (int*)alloc(64 * 4);
  int* boff = (int*)alloc(64 * 4);
  (void)ws_size; (void)in_sizes; (void)n_in; (void)out_size;

  auto cdiv = [](int a, int b) { return (a + b - 1) / b; };
  const int GATHER_BLK = cdiv(NTOT * HD, 256);          // 15000
  const int SETUP_BLK = 48 + GATHER_BLK + cdiv(NTOT, 256);
  const int RT_S = cdiv(NSRC, 64);                      // 782
  const int RT_T = cdiv(NTGT, 64);                      // 157
  const int NBLK_PROJ = 2 * (NSRC / 16) + 2 * (NTGT / 16);  // kv+q = 7500
  const int ST_BLK = cdiv(NTGT, 16);                    // 625 (4 nodes/wave, 4 waves/block)
  const int NBLK_AGG = ST_BLK + cdiv(NSRC, 16);         // 3750

  // fused setup: weight transpose + feature gather + counts zero
  setup_kernel<<<SETUP_BLK, 256, 0, stream>>>(Wq, Wk, Wv, Wtq, Wtk, Wtv,
                                              src_emb, nid_s, tgt_emb, nid_t,
                                              xsA, xsAb, xtA, xtAb, counts, GATHER_BLK);

  // CSR build for both edge sets
  hist_all_kernel<<<cdiv(2 * NEDGE, 256), 256, 0, stream>>>(e_st, e_ts, counts);
  scan1_kernel<<<cdiv(NTOT, 1024), 256, 0, stream>>>(counts, incl_buf, blocksums, NTOT);
  scan2_kernel<<<1, 64, 0, stream>>>(blocksums, boff, cdiv(NTOT, 1024));
  scan3_kernel<<<cdiv(NTOT, 256), 256, 0, stream>>>(incl_buf, counts, boff, rp_st, rp_ts, cursor);
  scatter_all_kernel<<<cdiv(2 * NEDGE, 256), 256, 0, stream>>>(e_st, e_ts, cursor, es_st, es_ts);

  const float* xs_cur = xsA; float* xs_nxt = xsB;
  const float* xt_cur = xtA; float* xt_nxt = xtB;
  const unsigned short* xsb_cur = xsAb; unsigned short* xsb_nxt = xsBb;
  const unsigned short* xtb_cur = xtAb; unsigned short* xtb_nxt = xtBb;
  for (int l = 0; l < 2; ++l) {
    int relu = (l == 0) ? 1 : 0;
    int p_st = l * 2 + 0, p_ts = l * 2 + 1;
    proj_all<<<NBLK_PROJ, 256, 0, stream>>>(xsb_cur, xtb_cur, Wtq, Wtk, Wtv, bq, bk, bv,
                                            kv_big, q_big, kv_small, q_small, p_st, p_ts);
    skip_all<<<RT_S + RT_T, 256, 0, stream>>>(xs_cur, xt_cur, Wsk, bsk, xs_nxt, xt_nxt, p_st, p_ts, RT_S);
    agg_all<<<NBLK_AGG, 256, 0, stream>>>(q_small, (const unsigned short*)kv_big, rp_st, es_st, xt_nxt, xtb_nxt,
                                          q_big, (const unsigned short*)kv_small, rp_ts, es_ts, xs_nxt, xsb_nxt,
                                          relu, ST_BLK);
    { const float* t = xs_nxt; xs_nxt = (float*)xs_cur; xs_cur = t; }
    { const float* t = xt_nxt; xt_nxt = (float*)xt_cur; xt_cur = t; }
    { const unsigned short* t = xsb_nxt; xsb_nxt = (unsigned short*)xsb_cur; xsb_cur = t; }
    { const unsigned short* t = xtb_nxt; xtb_nxt = (unsigned short*)xtb_cur; xtb_cur = t; }
  }

  classifier_kernel<<<cdiv(NLBL * 16, 256), 256, 0, stream>>>(xs_cur, xt_cur, e_lbl, e_lbl + NLBL, out, NLBL);
}

// Round 5
// 391.075 us; speedup vs baseline: 1.1619x; 1.1619x over previous
//
#include <hip/hip_runtime.h>

constexpr int NSRC = 50000;
constexpr int NTGT = 10000;
constexpr int NEDGE = 250000;
constexpr int NLBL = 200000;
constexpr int HD = 64;     // hidden dim (per head)
constexpr int NH = 4;      // heads
constexpr int QK = 256;    // HD*NH
constexpr int NTOT = NSRC + NTGT;

typedef __attribute__((ext_vector_type(8))) short bf16x8;
typedef __attribute__((ext_vector_type(4))) float f32x4;
typedef __attribute__((ext_vector_type(2))) float f32x2;

// ---------------- bf16 helpers ----------------
__device__ __forceinline__ unsigned short f2bf(float f) {
  unsigned u = __float_as_uint(f);
  u += 0x7FFFu + ((u >> 16) & 1u);   // round-to-nearest-even
  return (unsigned short)(u >> 16);
}
__device__ __forceinline__ float bf2f(unsigned short b) {
  return __uint_as_float((unsigned)b << 16);
}
struct bf4 { unsigned short x, y, z, w; };
__device__ __forceinline__ float4 bf4_to_f4(bf4 u) {
  return make_float4(bf2f(u.x), bf2f(u.y), bf2f(u.z), bf2f(u.w));
}

// ---------------- DPP 16-lane sum reduction (no LDS pipe, pure VALU) ----------------
template<int CTRL>
__device__ __forceinline__ float dpp_addf(float x) {
  int p = __builtin_amdgcn_update_dpp(0, __float_as_int(x), CTRL, 0xf, 0xf, true);
  return x + __int_as_float(p);
}
__device__ __forceinline__ float red16(float x) {
  x = dpp_addf<0xB1>(x);    // + lane^1 within quad
  x = dpp_addf<0x4E>(x);    // + lane^2 within quad
  x = dpp_addf<0x141>(x);   // + mirrored half-row (combines quads)
  x = dpp_addf<0x140>(x);   // + mirrored row (combines halves)
  return x;                 // all 16 lanes of the row hold the row sum
}

// ---------------- fused setup: weight transpose + feature gather + counts zero ----------------
__global__ __launch_bounds__(256) void setup_kernel(
    const float* __restrict__ Wq, const float* __restrict__ Wk, const float* __restrict__ Wv,
    unsigned short* __restrict__ Wtq, unsigned short* __restrict__ Wtk, unsigned short* __restrict__ Wtv,
    const float* __restrict__ semb, const int* __restrict__ sids,
    const float* __restrict__ temb, const int* __restrict__ tids,
    float* __restrict__ xs, unsigned short* __restrict__ xsb,
    float* __restrict__ xt, unsigned short* __restrict__ xtb,
    int* __restrict__ counts, int nGatherBlk) {
  __shared__ float tile[64][65];
  int b = blockIdx.x;
  int t = threadIdx.x;
  if (b < 48) {
    int mat = b >> 2, ct = b & 3;
    int grp = mat >> 2, p = mat & 3;
    const float* W = (grp == 0) ? Wq : (grp == 1) ? Wk : Wv;
    unsigned short* Wt = (grp == 0) ? Wtq : (grp == 1) ? Wtk : Wtv;
    W += (size_t)p * 16384;
    Wt += (size_t)p * 16384;
    int c = t & 63, r4 = t >> 6;
    for (int rr = 0; rr < 64; rr += 4)
      tile[rr + r4][c] = W[(size_t)(rr + r4) * 256 + ct * 64 + c];
    __syncthreads();
    for (int rr = 0; rr < 64; rr += 4) {
      int nloc = rr + r4;
      Wt[(size_t)(ct * 64 + nloc) * 64 + c] = f2bf(tile[c][nloc]);
    }
  } else if (b < 48 + nGatherBlk) {
    int i = (b - 48) * 256 + t;
    if (i < NSRC * HD) {
      float v = semb[(size_t)sids[i >> 6] * HD + (i & 63)];
      xs[i] = v;
      xsb[i] = f2bf(v);
    } else if (i < NTOT * HD) {
      int j = i - NSRC * HD;
      float v = temb[(size_t)tids[j >> 6] * HD + (j & 63)];
      xt[j] = v;
      xtb[j] = f2bf(v);
    }
  } else {
    int i = (b - 48 - nGatherBlk) * 256 + t;
    if (i < NTOT) counts[i] = 0;
  }
}

// ---------------- CSR build (both edge sets, concatenated counts) ----------------

__global__ __launch_bounds__(256) void hist_all_kernel(const int* __restrict__ e_st, const int* __restrict__ e_ts,
                                                       int* __restrict__ counts) {
  int i = blockIdx.x * 256 + threadIdx.x;
  if (i < NEDGE) atomicAdd(&counts[e_st[NEDGE + i]], 1);
  else if (i < 2 * NEDGE) atomicAdd(&counts[NTGT + e_ts[NEDGE + (i - NEDGE)]], 1);
}

__global__ __launch_bounds__(256) void scan1_kernel(const int* __restrict__ counts, int* __restrict__ incl,
                                                    int* __restrict__ blocksums, int n) {
  __shared__ int wtot[4];
  int t = threadIdx.x;
  int i0 = blockIdx.x * 1024 + t * 4;
  int e0 = (i0 + 0 < n) ? counts[i0 + 0] : 0;
  int e1 = (i0 + 1 < n) ? counts[i0 + 1] : 0;
  int e2 = (i0 + 2 < n) ? counts[i0 + 2] : 0;
  int e3 = (i0 + 3 < n) ? counts[i0 + 3] : 0;
  int s0 = e0, s1 = s0 + e1, s2 = s1 + e2, s3 = s2 + e3;
  int tsum = s3;
  int inc = tsum;
#pragma unroll
  for (int o = 1; o < 64; o <<= 1) {
    int u = __shfl_up(inc, o, 64);
    if ((t & 63) >= o) inc += u;
  }
  int wave = t >> 6;
  if ((t & 63) == 63) wtot[wave] = inc;
  __syncthreads();
  int woff = 0;
#pragma unroll
  for (int w_ = 0; w_ < 4; ++w_) if (w_ < wave) woff += wtot[w_];
  int toff = woff + inc - tsum;
  if (i0 + 0 < n) incl[i0 + 0] = toff + s0;
  if (i0 + 1 < n) incl[i0 + 1] = toff + s1;
  if (i0 + 2 < n) incl[i0 + 2] = toff + s2;
  if (i0 + 3 < n) incl[i0 + 3] = toff + s3;
  if (t == 255) blocksums[blockIdx.x] = woff + inc;
}

__global__ __launch_bounds__(64) void scan2_kernel(const int* __restrict__ blocksums, int* __restrict__ boff, int nb) {
  int t = threadIdx.x;
  int v = (t < nb) ? blocksums[t] : 0;
  int inc = v;
#pragma unroll
  for (int o = 1; o < 64; o <<= 1) {
    int u = __shfl_up(inc, o, 64);
    if (t >= o) inc += u;
  }
  if (t < nb) boff[t] = inc - v;
}

__global__ __launch_bounds__(256) void scan3_kernel(const int* __restrict__ incl, const int* __restrict__ counts,
                                                    const int* __restrict__ boff, int* __restrict__ rp_st,
                                                    int* __restrict__ rp_ts, int* __restrict__ cursor) {
  int i = blockIdx.x * 256 + threadIdx.x;
  if (i < NTOT) {
    int val = incl[i] + boff[i >> 10];
    if (i < NTGT) {
      rp_st[i + 1] = val;
      cursor[i] = val - counts[i];
      if (i == 0) rp_st[0] = 0;
    } else {
      int v2 = val - NEDGE;
      rp_ts[i - NTGT + 1] = v2;
      cursor[i] = v2 - counts[i];
      if (i == NTGT) rp_ts[0] = 0;
    }
  }
}

__global__ __launch_bounds__(256) void scatter_all_kernel(const int* __restrict__ e_st, const int* __restrict__ e_ts,
                                                          int* __restrict__ cursor, int* __restrict__ es_st,
                                                          int* __restrict__ es_ts) {
  int i = blockIdx.x * 256 + threadIdx.x;
  if (i < NEDGE) {
    int d = e_st[NEDGE + i];
    int p = atomicAdd(&cursor[d], 1);
    es_st[p] = e_st[i];
  } else if (i < 2 * NEDGE) {
    int j = i - NEDGE;
    int d = e_ts[NEDGE + j];
    int p = atomicAdd(&cursor[NTGT + d], 1);
    es_ts[p] = e_ts[j];
  }
}

// ---------------- MFMA projection dispatch per layer (kv + q only) ----------------
// R18/R19: kv stored as packed fp8 e4m3 (k byte0, v byte1 per col) — halves agg gather bytes.
__global__ __launch_bounds__(256) void proj_all(
    const unsigned short* __restrict__ xsb, const unsigned short* __restrict__ xtb,
    const unsigned short* __restrict__ Wtq, const unsigned short* __restrict__ Wtk,
    const unsigned short* __restrict__ Wtv,
    const float* __restrict__ bq, const float* __restrict__ bk, const float* __restrict__ bv,
    unsigned short* __restrict__ kv_big, unsigned short* __restrict__ q_big,
    unsigned short* __restrict__ kv_small, unsigned short* __restrict__ q_small,
    int p_st, int p_ts) {
  constexpr int B1 = NSRC / 16;   // 3125
  constexpr int B2 = NTGT / 16;   // 625
  int b = blockIdx.x;
  int w = threadIdx.x >> 6, l = threadIdx.x & 63;
  int m = l & 15, qd = l >> 4;
  const unsigned short* xb; const unsigned short* WtA; const unsigned short* WtB = nullptr;
  const float* biasA; const float* biasB = nullptr;
  unsigned short* okv = nullptr; unsigned short* oq = nullptr;
  int R0, mode;
  if (b < B1) {                       // kv_s (params p_st)
    xb = xsb; R0 = b * 16; mode = 0;
    WtA = Wtk + (size_t)p_st * 16384; biasA = bk + p_st * 256;
    WtB = Wtv + (size_t)p_st * 16384; biasB = bv + p_st * 256;
    okv = kv_big;
  } else if (b < B1 + B2) {           // kv_t (params p_ts)
    xb = xtb; R0 = (b - B1) * 16; mode = 0;
    WtA = Wtk + (size_t)p_ts * 16384; biasA = bk + p_ts * 256;
    WtB = Wtv + (size_t)p_ts * 16384; biasB = bv + p_ts * 256;
    okv = kv_small;
  } else if (b < 2 * B1 + B2) {       // q_s (params p_ts)
    xb = xsb; R0 = (b - B1 - B2) * 16; mode = 1;
    WtA = Wtq + (size_t)p_ts * 16384; biasA = bq + p_ts * 256;
    oq = q_big;
  } else {                            // q_t (params p_st)
    xb = xtb; R0 = (b - 2 * B1 - B2) * 16; mode = 1;
    WtA = Wtq + (size_t)p_st * 16384; biasA = bq + p_st * 256;
    oq = q_small;
  }
  const unsigned short* xrow = xb + (size_t)(R0 + m) * 64 + qd * 8;
  bf16x8 a_lo = *(const bf16x8*)xrow;
  bf16x8 a_hi = *(const bf16x8*)(xrow + 32);
  if (mode == 0) {
#pragma unroll
    for (int i = 0; i < 4; ++i) {
      int col = (w * 4 + i) * 16 + m;
      const unsigned short* wk = WtA + (size_t)col * 64 + qd * 8;
      const unsigned short* wv = WtB + (size_t)col * 64 + qd * 8;
      bf16x8 bk_lo = *(const bf16x8*)wk, bk_hi = *(const bf16x8*)(wk + 32);
      bf16x8 bv_lo = *(const bf16x8*)wv, bv_hi = *(const bf16x8*)(wv + 32);
      f32x4 ak = {0.f, 0.f, 0.f, 0.f}, av = {0.f, 0.f, 0.f, 0.f};
      ak = __builtin_amdgcn_mfma_f32_16x16x32_bf16(a_lo, bk_lo, ak, 0, 0, 0);
      ak = __builtin_amdgcn_mfma_f32_16x16x32_bf16(a_hi, bk_hi, ak, 0, 0, 0);
      av = __builtin_amdgcn_mfma_f32_16x16x32_bf16(a_lo, bv_lo, av, 0, 0, 0);
      av = __builtin_amdgcn_mfma_f32_16x16x32_bf16(a_hi, bv_hi, av, 0, 0, 0);
      float bkc = biasA[col], bvc = biasB[col];
      unsigned short* obase = okv + (size_t)(R0 + qd * 4) * 256 + col;
#pragma unroll
      for (int r = 0; r < 4; ++r) {
        // pack fp8(k) into byte0, fp8(v) into byte1 (e4m3 on gfx950)
        unsigned pk = __builtin_amdgcn_cvt_pk_fp8_f32(ak[r] + bkc, av[r] + bvc, 0, false);
        obase[(size_t)r * 256] = (unsigned short)pk;
      }
    }
  } else {
#pragma unroll
    for (int i = 0; i < 4; ++i) {
      int col = (w * 4 + i) * 16 + m;
      const unsigned short* wq = WtA + (size_t)col * 64 + qd * 8;
      bf16x8 b_lo = *(const bf16x8*)wq, b_hi = *(const bf16x8*)(wq + 32);
      f32x4 acc = {0.f, 0.f, 0.f, 0.f};
      acc = __builtin_amdgcn_mfma_f32_16x16x32_bf16(a_lo, b_lo, acc, 0, 0, 0);
      acc = __builtin_amdgcn_mfma_f32_16x16x32_bf16(a_hi, b_hi, acc, 0, 0, 0);
      float bc = biasA[col];
      unsigned short* obase = oq + (size_t)(R0 + qd * 4) * 256 + col;
#pragma unroll
      for (int r = 0; r < 4; ++r)
        obase[(size_t)r * 256] = f2bf(acc[r] + bc);
    }
  }
}

// ---------------- fused fp32 skip GEMM for both directions (LDS-tiled, R12-proven) ----------------
__global__ __launch_bounds__(256) void skip_all(const float* __restrict__ xs, const float* __restrict__ xt,
    const float* __restrict__ Wsk, const float* __restrict__ bsk,
    float* __restrict__ xs_nxt, float* __restrict__ xt_nxt, int p_st, int p_ts, int rtS) {
  __shared__ float Xt[64][68];
  __shared__ float Wl[64][68];
  __shared__ float bias[64];
  int t = threadIdx.x;
  const float* x; const float* W; const float* bb; float* o; int N, rbase;
  if ((int)blockIdx.x < rtS) {
    x = xs; N = NSRC; rbase = blockIdx.x * 64;
    W = Wsk + (size_t)p_ts * 4096; bb = bsk + p_ts * 64; o = xs_nxt;
  } else {
    x = xt; N = NTGT; rbase = (blockIdx.x - rtS) * 64;
    W = Wsk + (size_t)p_st * 4096; bb = bsk + p_st * 64; o = xt_nxt;
  }
#pragma unroll
  for (int i = 0; i < 4; ++i) {
    int slot = i * 256 + t;
    int row = slot >> 4;
    int k4 = slot & 15;
    float4 xv = make_float4(0.f, 0.f, 0.f, 0.f);
    if (rbase + row < N) xv = *(const float4*)&x[(size_t)(rbase + row) * 64 + k4 * 4];
    Xt[k4 * 4 + 0][row] = xv.x;
    Xt[k4 * 4 + 1][row] = xv.y;
    Xt[k4 * 4 + 2][row] = xv.z;
    Xt[k4 * 4 + 3][row] = xv.w;
  }
#pragma unroll
  for (int i = 0; i < 4; ++i) {
    int slot = i * 256 + t;
    int kk = slot >> 4;
    int c4 = slot & 15;
    float4 wv = *(const float4*)&W[(size_t)kk * 64 + c4 * 4];
    *(float4*)&Wl[kk][c4 * 4] = wv;
  }
  if (t < 64) bias[t] = bb[t];
  __syncthreads();

  int c0 = (t & 15) * 4;
  int r0 = (t >> 4) * 4;
  float acc[4][4];
#pragma unroll
  for (int i = 0; i < 4; ++i)
#pragma unroll
    for (int j = 0; j < 4; ++j) acc[i][j] = 0.f;
#pragma unroll 8
  for (int kk = 0; kk < 64; ++kk) {
    float4 xv = *(const float4*)&Xt[kk][r0];
    float4 wv = *(const float4*)&Wl[kk][c0];
    float xr[4] = {xv.x, xv.y, xv.z, xv.w};
    float wc[4] = {wv.x, wv.y, wv.z, wv.w};
#pragma unroll
    for (int i = 0; i < 4; ++i)
#pragma unroll
      for (int j = 0; j < 4; ++j) acc[i][j] = fmaf(xr[i], wc[j], acc[i][j]);
  }
#pragma unroll
  for (int i = 0; i < 4; ++i) {
    int row = rbase + r0 + i;
    if (row < N) {
      float4 ov;
      ov.x = acc[i][0] + bias[c0 + 0];
      ov.y = acc[i][1] + bias[c0 + 1];
      ov.z = acc[i][2] + bias[c0 + 2];
      ov.w = acc[i][3] + bias[c0 + 3];
      *(float4*)&o[(size_t)row * 64 + c0] = ov;
    }
  }
}

// ---------------- fused aggregation for BOTH directions: one WAVE per node ----------------
// R18/R19: fp8 kv rows (512B, uint2/lane gather — halves L2-miss lines vs bf16) on the
// proven R16 structure (unroll-4, DPP reduce, exp2 prefolded scale).
// Decode: each dword holds (k0,v0,k1,v1) e4m3 bytes -> 2x v_cvt_pk_f32_fp8.
__global__ __launch_bounds__(256) void agg_all(
    const unsigned short* __restrict__ q_small, const unsigned short* __restrict__ kv_big,
    const int* __restrict__ rp_st, const int* __restrict__ es_st,
    float* __restrict__ xt_nxt, unsigned short* __restrict__ xtb_nxt,
    const unsigned short* __restrict__ q_big, const unsigned short* __restrict__ kv_small,
    const int* __restrict__ rp_ts, const int* __restrict__ es_ts,
    float* __restrict__ xs_nxt, unsigned short* __restrict__ xsb_nxt,
    int relu, int stBlocks) {
  const unsigned short* q; const unsigned short* kvi; const int* rowptr; const int* eisrc;
  float* xout; unsigned short* xoutb; int node;
  int wv = threadIdx.x >> 6, l = threadIdx.x & 63;
  if ((int)blockIdx.x < stBlocks) {
    node = blockIdx.x * 4 + wv;
    if (node >= NTGT) return;
    q = q_small; kvi = kv_big; rowptr = rp_st; eisrc = es_st; xout = xt_nxt; xoutb = xtb_nxt;
  } else {
    node = (blockIdx.x - stBlocks) * 4 + wv;
    if (node >= NSRC) return;
    q = q_big; kvi = kv_small; rowptr = rp_ts; eisrc = es_ts; xout = xs_nxt; xoutb = xsb_nxt;
  }
  int j = l & 15;
  float4 qf = bf4_to_f4(*(const bf4*)&q[(size_t)node * QK + l * 4]);
  // fold 1/sqrt(H)=0.125 and log2(e) so the softmax uses raw v_exp (base-2)
  const float QS = 0.125f * 1.44269504088896340736f;
  qf.x *= QS; qf.y *= QS; qf.z *= QS; qf.w *= QS;
  int beg = rowptr[node], end = rowptr[node + 1];

  float lsum = 0.f;
  float4 acc = make_float4(0.f, 0.f, 0.f, 0.f);
  int p = beg;
  for (; p + 4 <= end; p += 4) {
    int s0 = eisrc[p], s1 = eisrc[p + 1], s2 = eisrc[p + 2], s3 = eisrc[p + 3];
    uint2 a0 = *(const uint2*)&kvi[(size_t)s0 * 256 + l * 4];
    uint2 a1 = *(const uint2*)&kvi[(size_t)s1 * 256 + l * 4];
    uint2 a2 = *(const uint2*)&kvi[(size_t)s2 * 256 + l * 4];
    uint2 a3 = *(const uint2*)&kvi[(size_t)s3 * 256 + l * 4];
    f32x2 p00 = __builtin_amdgcn_cvt_pk_f32_fp8(a0.x, false);
    f32x2 p01 = __builtin_amdgcn_cvt_pk_f32_fp8(a0.x, true);
    f32x2 p02 = __builtin_amdgcn_cvt_pk_f32_fp8(a0.y, false);
    f32x2 p03 = __builtin_amdgcn_cvt_pk_f32_fp8(a0.y, true);
    f32x2 p10 = __builtin_amdgcn_cvt_pk_f32_fp8(a1.x, false);
    f32x2 p11 = __builtin_amdgcn_cvt_pk_f32_fp8(a1.x, true);
    f32x2 p12 = __builtin_amdgcn_cvt_pk_f32_fp8(a1.y, false);
    f32x2 p13 = __builtin_amdgcn_cvt_pk_f32_fp8(a1.y, true);
    f32x2 p20 = __builtin_amdgcn_cvt_pk_f32_fp8(a2.x, false);
    f32x2 p21 = __builtin_amdgcn_cvt_pk_f32_fp8(a2.x, true);
    f32x2 p22 = __builtin_amdgcn_cvt_pk_f32_fp8(a2.y, false);
    f32x2 p23 = __builtin_amdgcn_cvt_pk_f32_fp8(a2.y, true);
    f32x2 p30 = __builtin_amdgcn_cvt_pk_f32_fp8(a3.x, false);
    f32x2 p31 = __builtin_amdgcn_cvt_pk_f32_fp8(a3.x, true);
    f32x2 p32 = __builtin_amdgcn_cvt_pk_f32_fp8(a3.y, false);
    f32x2 p33 = __builtin_amdgcn_cvt_pk_f32_fp8(a3.y, true);
    float t0 = qf.x * p00.x + qf.y * p01.x + qf.z * p02.x + qf.w * p03.x;
    float t1 = qf.x * p10.x + qf.y * p11.x + qf.z * p12.x + qf.w * p13.x;
    float t2 = qf.x * p20.x + qf.y * p21.x + qf.z * p22.x + qf.w * p23.x;
    float t3 = qf.x * p30.x + qf.y * p31.x + qf.z * p32.x + qf.w * p33.x;
    t0 = red16(t0); t1 = red16(t1); t2 = red16(t2); t3 = red16(t3);
    float w0 = __builtin_amdgcn_exp2f(t0), w1 = __builtin_amdgcn_exp2f(t1);
    float w2 = __builtin_amdgcn_exp2f(t2), w3 = __builtin_amdgcn_exp2f(t3);
    lsum += (w0 + w1) + (w2 + w3);
    acc.x = fmaf(w0, p00.y, fmaf(w1, p10.y, fmaf(w2, p20.y, fmaf(w3, p30.y, acc.x))));
    acc.y = fmaf(w0, p01.y, fmaf(w1, p11.y, fmaf(w2, p21.y, fmaf(w3, p31.y, acc.y))));
    acc.z = fmaf(w0, p02.y, fmaf(w1, p12.y, fmaf(w2, p22.y, fmaf(w3, p32.y, acc.z))));
    acc.w = fmaf(w0, p03.y, fmaf(w1, p13.y, fmaf(w2, p23.y, fmaf(w3, p33.y, acc.w))));
  }
  for (; p < end; ++p) {
    int s0 = eisrc[p];
    uint2 a0 = *(const uint2*)&kvi[(size_t)s0 * 256 + l * 4];
    f32x2 p00 = __builtin_amdgcn_cvt_pk_f32_fp8(a0.x, false);
    f32x2 p01 = __builtin_amdgcn_cvt_pk_f32_fp8(a0.x, true);
    f32x2 p02 = __builtin_amdgcn_cvt_pk_f32_fp8(a0.y, false);
    f32x2 p03 = __builtin_amdgcn_cvt_pk_f32_fp8(a0.y, true);
    float s = qf.x * p00.x + qf.y * p01.x + qf.z * p02.x + qf.w * p03.x;
    s = red16(s);
    float w = __builtin_amdgcn_exp2f(s);
    lsum += w;
    acc.x = fmaf(w, p00.y, acc.x);
    acc.y = fmaf(w, p01.y, acc.y);
    acc.z = fmaf(w, p02.y, acc.z);
    acc.w = fmaf(w, p03.y, acc.w);
  }

  float inv = (lsum > 0.f) ? 1.f / lsum : 0.f;
  float4 r;
  r.x = acc.x * inv; r.y = acc.y * inv; r.z = acc.z * inv; r.w = acc.w * inv;
  r.x += __shfl_xor(r.x, 16, 64); r.x += __shfl_xor(r.x, 32, 64);
  r.y += __shfl_xor(r.y, 16, 64); r.y += __shfl_xor(r.y, 32, 64);
  r.z += __shfl_xor(r.z, 16, 64); r.z += __shfl_xor(r.z, 32, 64);
  r.w += __shfl_xor(r.w, 16, 64); r.w += __shfl_xor(r.w, 32, 64);
  if (l < 16) {
    float4 sk = *(const float4*)&xout[(size_t)node * HD + j * 4];
    float4 o;
    o.x = sk.x + 0.25f * r.x;
    o.y = sk.y + 0.25f * r.y;
    o.z = sk.z + 0.25f * r.z;
    o.w = sk.w + 0.25f * r.w;
    if (relu) {
      o.x = fmaxf(o.x, 0.f); o.y = fmaxf(o.y, 0.f);
      o.z = fmaxf(o.z, 0.f); o.w = fmaxf(o.w, 0.f);
    }
    *(float4*)&xout[(size_t)node * HD + j * 4] = o;
    bf4 ob;
    ob.x = f2bf(o.x); ob.y = f2bf(o.y); ob.z = f2bf(o.z); ob.w = f2bf(o.w);
    *(bf4*)&xoutb[(size_t)node * HD + j * 4] = ob;
  }
}

// ---------------- classifier: 16 lanes per pair, float4 loads ----------------
__global__ __launch_bounds__(256) void classifier_kernel(const float* __restrict__ xs, const float* __restrict__ xt,
    const int* __restrict__ ls, const int* __restrict__ lt, float* __restrict__ out, int n) {
  int g = blockIdx.x * 256 + threadIdx.x;
  int pair = g >> 4, j = g & 15;
  if (pair >= n) return;
  int a = ls[pair], b = lt[pair];
  float4 xa = *(const float4*)&xs[(size_t)a * HD + j * 4];
  float4 xb = *(const float4*)&xt[(size_t)b * HD + j * 4];
  float s = xa.x * xb.x + xa.y * xb.y + xa.z * xb.z + xa.w * xb.w;
  s = red16(s);
  if (j == 0) out[pair] = s;
}

// ---------------- launch ----------------
extern "C" void kernel_launch(void* const* d_in, const int* in_sizes, int n_in,
                              void* d_out, int out_size, void* d_ws, size_t ws_size,
                              hipStream_t stream) {
  const float* src_emb = (const float*)d_in[0];
  const float* tgt_emb = (const float*)d_in[1];
  const float* Wq = (const float*)d_in[2];
  const float* bq = (const float*)d_in[3];
  const float* Wk = (const float*)d_in[4];
  const float* bk = (const float*)d_in[5];
  const float* Wv = (const float*)d_in[6];
  const float* bv = (const float*)d_in[7];
  const float* Wsk = (const float*)d_in[8];
  const float* bsk = (const float*)d_in[9];
  const int* nid_s = (const int*)d_in[10];
  const int* nid_t = (const int*)d_in[11];
  const int* e_st = (const int*)d_in[12];
  const int* e_ts = (const int*)d_in[13];
  const int* e_lbl = (const int*)d_in[14];
  float* out = (float*)d_out;

  char* ws = (char*)d_ws;
  size_t off = 0;
  auto alloc = [&](size_t bytes) -> void* {
    void* p = ws + off;
    off += (bytes + 255) & ~(size_t)255;
    return p;
  };
  unsigned short* kv_big   = (unsigned short*)alloc((size_t)NSRC * 256 * 2);  // st k/v fp8 pairs
  unsigned short* q_big    = (unsigned short*)alloc((size_t)NSRC * QK * 2);   // ts q
  unsigned short* kv_small = (unsigned short*)alloc((size_t)NTGT * 256 * 2);  // ts k/v fp8 pairs
  unsigned short* q_small  = (unsigned short*)alloc((size_t)NTGT * QK * 2);   // st q
  float* xsA = (float*)alloc((size_t)NSRC * HD * 4);
  float* xsB = (float*)alloc((size_t)NSRC * HD * 4);
  float* xtA = (float*)alloc((size_t)NTGT * HD * 4);
  float* xtB = (float*)alloc((size_t)NTGT * HD * 4);
  unsigned short* xsAb = (unsigned short*)alloc((size_t)NSRC * HD * 2);
  unsigned short* xsBb = (unsigned short*)alloc((size_t)NSRC * HD * 2);
  unsigned short* xtAb = (unsigned short*)alloc((size_t)NTGT * HD * 2);
  unsigned short* xtBb = (unsigned short*)alloc((size_t)NTGT * HD * 2);
  unsigned short* Wtq = (unsigned short*)alloc((size_t)4 * 16384 * 2);
  unsigned short* Wtk = (unsigned short*)alloc((size_t)4 * 16384 * 2);
  unsigned short* Wtv = (unsigned short*)alloc((size_t)4 * 16384 * 2);
  int* rp_st = (int*)alloc((size_t)(NTGT + 1) * 4);
  int* es_st = (int*)alloc((size_t)NEDGE * 4);
  int* rp_ts = (int*)alloc((size_t)(NSRC + 1) * 4);
  int* es_ts = (int*)alloc((size_t)NEDGE * 4);
  int* cursor = (int*)alloc((size_t)NTOT * 4);
  int* counts = (int*)alloc((size_t)NTOT * 4);
  int* incl_buf = (int*)alloc((size_t)NTOT * 4);
  int* blocksums = (int*)alloc(64 * 4);
  int* boff = (int*)alloc(64 * 4);
  (void)ws_size; (void)in_sizes; (void)n_in; (void)out_size;

  auto cdiv = [](int a, int b) { return (a + b - 1) / b; };
  const int GATHER_BLK = cdiv(NTOT * HD, 256);          // 15000
  const int SETUP_BLK = 48 + GATHER_BLK + cdiv(NTOT, 256);
  const int RT_S = cdiv(NSRC, 64);                      // 782
  const int RT_T = cdiv(NTGT, 64);                      // 157
  const int NBLK_PROJ = 2 * (NSRC / 16) + 2 * (NTGT / 16);  // kv+q = 7500
  const int ST_BLK = cdiv(NTGT, 4);                     // 2500
  const int NBLK_AGG = ST_BLK + cdiv(NSRC, 4);          // 15000

  // fused setup: weight transpose + feature gather + counts zero
  setup_kernel<<<SETUP_BLK, 256, 0, stream>>>(Wq, Wk, Wv, Wtq, Wtk, Wtv,
                                              src_emb, nid_s, tgt_emb, nid_t,
                                              xsA, xsAb, xtA, xtAb, counts, GATHER_BLK);

  // CSR build for both edge sets
  hist_all_kernel<<<cdiv(2 * NEDGE, 256), 256, 0, stream>>>(e_st, e_ts, counts);
  scan1_kernel<<<cdiv(NTOT, 1024), 256, 0, stream>>>(counts, incl_buf, blocksums, NTOT);
  scan2_kernel<<<1, 64, 0, stream>>>(blocksums, boff, cdiv(NTOT, 1024));
  scan3_kernel<<<cdiv(NTOT, 256), 256, 0, stream>>>(incl_buf, counts, boff, rp_st, rp_ts, cursor);
  scatter_all_kernel<<<cdiv(2 * NEDGE, 256), 256, 0, stream>>>(e_st, e_ts, cursor, es_st, es_ts);

  const float* xs_cur = xsA; float* xs_nxt = xsB;
  const float* xt_cur = xtA; float* xt_nxt = xtB;
  const unsigned short* xsb_cur = xsAb; unsigned short* xsb_nxt = xsBb;
  const unsigned short* xtb_cur = xtAb; unsigned short* xtb_nxt = xtBb;
  for (int l = 0; l < 2; ++l) {
    int relu = (l == 0) ? 1 : 0;
    int p_st = l * 2 + 0, p_ts = l * 2 + 1;
    proj_all<<<NBLK_PROJ, 256, 0, stream>>>(xsb_cur, xtb_cur, Wtq, Wtk, Wtv, bq, bk, bv,
                                            kv_big, q_big, kv_small, q_small, p_st, p_ts);
    skip_all<<<RT_S + RT_T, 256, 0, stream>>>(xs_cur, xt_cur, Wsk, bsk, xs_nxt, xt_nxt, p_st, p_ts, RT_S);
    agg_all<<<NBLK_AGG, 256, 0, stream>>>(q_small, kv_big, rp_st, es_st, xt_nxt, xtb_nxt,
                                          q_big, kv_small, rp_ts, es_ts, xs_nxt, xsb_nxt,
                                          relu, ST_BLK);
    { const float* t = xs_nxt; xs_nxt = (float*)xs_cur; xs_cur = t; }
    { const float* t = xt_nxt; xt_nxt = (float*)xt_cur; xt_cur = t; }
    { const unsigned short* t = xsb_nxt; xsb_nxt = (unsigned short*)xsb_cur; xsb_cur = t; }
    { const unsigned short* t = xtb_nxt; xtb_nxt = (unsigned short*)xtb_cur; xtb_cur = t; }
  }

  classifier_kernel<<<cdiv(NLBL * 16, 256), 256, 0, stream>>>(xs_cur, xt_cur, e_lbl, e_lbl + NLBL, out, NLBL);
}

// Round 6
// 390.342 us; speedup vs baseline: 1.1641x; 1.0019x over previous
//
#include <hip/hip_runtime.h>

constexpr int NSRC = 50000;
constexpr int NTGT = 10000;
constexpr int NEDGE = 250000;
constexpr int NLBL = 200000;
constexpr int HD = 64;     // hidden dim (per head)
constexpr int NH = 4;      // heads
constexpr int QK = 256;    // HD*NH
constexpr int NTOT = NSRC + NTGT;

typedef __attribute__((ext_vector_type(8))) short bf16x8;
typedef __attribute__((ext_vector_type(4))) float f32x4;
typedef __attribute__((ext_vector_type(2))) float f32x2;

// ---------------- bf16 helpers ----------------
__device__ __forceinline__ unsigned short f2bf(float f) {
  unsigned u = __float_as_uint(f);
  u += 0x7FFFu + ((u >> 16) & 1u);   // round-to-nearest-even
  return (unsigned short)(u >> 16);
}
__device__ __forceinline__ float bf2f(unsigned short b) {
  return __uint_as_float((unsigned)b << 16);
}
struct bf4 { unsigned short x, y, z, w; };
__device__ __forceinline__ float4 bf4_to_f4(bf4 u) {
  return make_float4(bf2f(u.x), bf2f(u.y), bf2f(u.z), bf2f(u.w));
}

// ---------------- DPP 16-lane sum reduction (no LDS pipe, pure VALU) ----------------
template<int CTRL>
__device__ __forceinline__ float dpp_addf(float x) {
  int p = __builtin_amdgcn_update_dpp(0, __float_as_int(x), CTRL, 0xf, 0xf, true);
  return x + __int_as_float(p);
}
__device__ __forceinline__ float red16(float x) {
  x = dpp_addf<0xB1>(x);    // + lane^1 within quad
  x = dpp_addf<0x4E>(x);    // + lane^2 within quad
  x = dpp_addf<0x141>(x);   // + mirrored half-row (combines quads)
  x = dpp_addf<0x140>(x);   // + mirrored row (combines halves)
  return x;                 // all 16 lanes of the row hold the row sum
}

// ---------------- fused setup: weight transpose + feature gather + counts zero ----------------
__global__ __launch_bounds__(256) void setup_kernel(
    const float* __restrict__ Wq, const float* __restrict__ Wk, const float* __restrict__ Wv,
    unsigned short* __restrict__ Wtq, unsigned short* __restrict__ Wtk, unsigned short* __restrict__ Wtv,
    const float* __restrict__ semb, const int* __restrict__ sids,
    const float* __restrict__ temb, const int* __restrict__ tids,
    float* __restrict__ xs, unsigned short* __restrict__ xsb,
    float* __restrict__ xt, unsigned short* __restrict__ xtb,
    int* __restrict__ counts, int nGatherBlk) {
  __shared__ float tile[64][65];
  int b = blockIdx.x;
  int t = threadIdx.x;
  if (b < 48) {
    int mat = b >> 2, ct = b & 3;
    int grp = mat >> 2, p = mat & 3;
    const float* W = (grp == 0) ? Wq : (grp == 1) ? Wk : Wv;
    unsigned short* Wt = (grp == 0) ? Wtq : (grp == 1) ? Wtk : Wtv;
    W += (size_t)p * 16384;
    Wt += (size_t)p * 16384;
    int c = t & 63, r4 = t >> 6;
    for (int rr = 0; rr < 64; rr += 4)
      tile[rr + r4][c] = W[(size_t)(rr + r4) * 256 + ct * 64 + c];
    __syncthreads();
    for (int rr = 0; rr < 64; rr += 4) {
      int nloc = rr + r4;
      Wt[(size_t)(ct * 64 + nloc) * 64 + c] = f2bf(tile[c][nloc]);
    }
  } else if (b < 48 + nGatherBlk) {
    int i = (b - 48) * 256 + t;
    if (i < NSRC * HD) {
      float v = semb[(size_t)sids[i >> 6] * HD + (i & 63)];
      xs[i] = v;
      xsb[i] = f2bf(v);
    } else if (i < NTOT * HD) {
      int j = i - NSRC * HD;
      float v = temb[(size_t)tids[j >> 6] * HD + (j & 63)];
      xt[j] = v;
      xtb[j] = f2bf(v);
    }
  } else {
    int i = (b - 48 - nGatherBlk) * 256 + t;
    if (i < NTOT) counts[i] = 0;
  }
}

// ---------------- CSR build (both edge sets, concatenated counts) ----------------

__global__ __launch_bounds__(256) void hist_all_kernel(const int* __restrict__ e_st, const int* __restrict__ e_ts,
                                                       int* __restrict__ counts) {
  int i = blockIdx.x * 256 + threadIdx.x;
  if (i < NEDGE) atomicAdd(&counts[e_st[NEDGE + i]], 1);
  else if (i < 2 * NEDGE) atomicAdd(&counts[NTGT + e_ts[NEDGE + (i - NEDGE)]], 1);
}

__global__ __launch_bounds__(256) void scan1_kernel(const int* __restrict__ counts, int* __restrict__ incl,
                                                    int* __restrict__ blocksums, int n) {
  __shared__ int wtot[4];
  int t = threadIdx.x;
  int i0 = blockIdx.x * 1024 + t * 4;
  int e0 = (i0 + 0 < n) ? counts[i0 + 0] : 0;
  int e1 = (i0 + 1 < n) ? counts[i0 + 1] : 0;
  int e2 = (i0 + 2 < n) ? counts[i0 + 2] : 0;
  int e3 = (i0 + 3 < n) ? counts[i0 + 3] : 0;
  int s0 = e0, s1 = s0 + e1, s2 = s1 + e2, s3 = s2 + e3;
  int tsum = s3;
  int inc = tsum;
#pragma unroll
  for (int o = 1; o < 64; o <<= 1) {
    int u = __shfl_up(inc, o, 64);
    if ((t & 63) >= o) inc += u;
  }
  int wave = t >> 6;
  if ((t & 63) == 63) wtot[wave] = inc;
  __syncthreads();
  int woff = 0;
#pragma unroll
  for (int w_ = 0; w_ < 4; ++w_) if (w_ < wave) woff += wtot[w_];
  int toff = woff + inc - tsum;
  if (i0 + 0 < n) incl[i0 + 0] = toff + s0;
  if (i0 + 1 < n) incl[i0 + 1] = toff + s1;
  if (i0 + 2 < n) incl[i0 + 2] = toff + s2;
  if (i0 + 3 < n) incl[i0 + 3] = toff + s3;
  if (t == 255) blocksums[blockIdx.x] = woff + inc;
}

__global__ __launch_bounds__(64) void scan2_kernel(const int* __restrict__ blocksums, int* __restrict__ boff, int nb) {
  int t = threadIdx.x;
  int v = (t < nb) ? blocksums[t] : 0;
  int inc = v;
#pragma unroll
  for (int o = 1; o < 64; o <<= 1) {
    int u = __shfl_up(inc, o, 64);
    if (t >= o) inc += u;
  }
  if (t < nb) boff[t] = inc - v;
}

__global__ __launch_bounds__(256) void scan3_kernel(const int* __restrict__ incl, const int* __restrict__ counts,
                                                    const int* __restrict__ boff, int* __restrict__ rp_st,
                                                    int* __restrict__ rp_ts, int* __restrict__ cursor) {
  int i = blockIdx.x * 256 + threadIdx.x;
  if (i < NTOT) {
    int val = incl[i] + boff[i >> 10];
    if (i < NTGT) {
      rp_st[i + 1] = val;
      cursor[i] = val - counts[i];
      if (i == 0) rp_st[0] = 0;
    } else {
      int v2 = val - NEDGE;
      rp_ts[i - NTGT + 1] = v2;
      cursor[i] = v2 - counts[i];
      if (i == NTGT) rp_ts[0] = 0;
    }
  }
}

__global__ __launch_bounds__(256) void scatter_all_kernel(const int* __restrict__ e_st, const int* __restrict__ e_ts,
                                                          int* __restrict__ cursor, int* __restrict__ es_st,
                                                          int* __restrict__ es_ts) {
  int i = blockIdx.x * 256 + threadIdx.x;
  if (i < NEDGE) {
    int d = e_st[NEDGE + i];
    int p = atomicAdd(&cursor[d], 1);
    es_st[p] = e_st[i];
  } else if (i < 2 * NEDGE) {
    int j = i - NEDGE;
    int d = e_ts[NEDGE + j];
    int p = atomicAdd(&cursor[NTGT + d], 1);
    es_ts[p] = e_ts[j];
  }
}

// ---------------- MFMA projection dispatch per layer (kv + q only) ----------------
// R18: kv stored as packed fp8 e4m3 (k byte0, v byte1 per col).
// R20: LDS-staged epilogue — MFMA fragments land in LDS (2B DS writes, cheap issue),
// then one cooperative uint4 copy to global. Replaces 16 scalar 2B global stores/lane
// (31M store insts/dispatch ~= 50us issue time; proj was store-issue-bound: MfmaUtil 3.6%,
// VALU 10%, HBM 15% all idle).
__global__ __launch_bounds__(256) void proj_all(
    const unsigned short* __restrict__ xsb, const unsigned short* __restrict__ xtb,
    const unsigned short* __restrict__ Wtq, const unsigned short* __restrict__ Wtk,
    const unsigned short* __restrict__ Wtv,
    const float* __restrict__ bq, const float* __restrict__ bk, const float* __restrict__ bv,
    unsigned short* __restrict__ kv_big, unsigned short* __restrict__ q_big,
    unsigned short* __restrict__ kv_small, unsigned short* __restrict__ q_small,
    int p_st, int p_ts) {
  constexpr int B1 = NSRC / 16;   // 3125
  constexpr int B2 = NTGT / 16;   // 625
  __shared__ unsigned short tile[16 * 256];   // 8KB output staging
  int b = blockIdx.x;
  int t = threadIdx.x;
  int w = t >> 6, l = t & 63;
  int m = l & 15, qd = l >> 4;
  const unsigned short* xb; const unsigned short* WtA; const unsigned short* WtB = nullptr;
  const float* biasA; const float* biasB = nullptr;
  unsigned short* obuf;
  int R0, mode;
  if (b < B1) {                       // kv_s (params p_st)
    xb = xsb; R0 = b * 16; mode = 0;
    WtA = Wtk + (size_t)p_st * 16384; biasA = bk + p_st * 256;
    WtB = Wtv + (size_t)p_st * 16384; biasB = bv + p_st * 256;
    obuf = kv_big;
  } else if (b < B1 + B2) {           // kv_t (params p_ts)
    xb = xtb; R0 = (b - B1) * 16; mode = 0;
    WtA = Wtk + (size_t)p_ts * 16384; biasA = bk + p_ts * 256;
    WtB = Wtv + (size_t)p_ts * 16384; biasB = bv + p_ts * 256;
    obuf = kv_small;
  } else if (b < 2 * B1 + B2) {       // q_s (params p_ts)
    xb = xsb; R0 = (b - B1 - B2) * 16; mode = 1;
    WtA = Wtq + (size_t)p_ts * 16384; biasA = bq + p_ts * 256;
    obuf = q_big;
  } else {                            // q_t (params p_st)
    xb = xtb; R0 = (b - 2 * B1 - B2) * 16; mode = 1;
    WtA = Wtq + (size_t)p_st * 16384; biasA = bq + p_st * 256;
    obuf = q_small;
  }
  const unsigned short* xrow = xb + (size_t)(R0 + m) * 64 + qd * 8;
  bf16x8 a_lo = *(const bf16x8*)xrow;
  bf16x8 a_hi = *(const bf16x8*)(xrow + 32);
  if (mode == 0) {
#pragma unroll
    for (int i = 0; i < 4; ++i) {
      int col = (w * 4 + i) * 16 + m;
      const unsigned short* wk = WtA + (size_t)col * 64 + qd * 8;
      const unsigned short* wv = WtB + (size_t)col * 64 + qd * 8;
      bf16x8 bk_lo = *(const bf16x8*)wk, bk_hi = *(const bf16x8*)(wk + 32);
      bf16x8 bv_lo = *(const bf16x8*)wv, bv_hi = *(const bf16x8*)(wv + 32);
      f32x4 ak = {0.f, 0.f, 0.f, 0.f}, av = {0.f, 0.f, 0.f, 0.f};
      ak = __builtin_amdgcn_mfma_f32_16x16x32_bf16(a_lo, bk_lo, ak, 0, 0, 0);
      ak = __builtin_amdgcn_mfma_f32_16x16x32_bf16(a_hi, bk_hi, ak, 0, 0, 0);
      av = __builtin_amdgcn_mfma_f32_16x16x32_bf16(a_lo, bv_lo, av, 0, 0, 0);
      av = __builtin_amdgcn_mfma_f32_16x16x32_bf16(a_hi, bv_hi, av, 0, 0, 0);
      float bkc = biasA[col], bvc = biasB[col];
#pragma unroll
      for (int r = 0; r < 4; ++r) {
        // pack fp8(k) into byte0, fp8(v) into byte1 (e4m3 on gfx950)
        unsigned pk = __builtin_amdgcn_cvt_pk_fp8_f32(ak[r] + bkc, av[r] + bvc, 0, false);
        tile[(qd * 4 + r) * 256 + col] = (unsigned short)pk;
      }
    }
  } else {
#pragma unroll
    for (int i = 0; i < 4; ++i) {
      int col = (w * 4 + i) * 16 + m;
      const unsigned short* wq = WtA + (size_t)col * 64 + qd * 8;
      bf16x8 b_lo = *(const bf16x8*)wq, b_hi = *(const bf16x8*)(wq + 32);
      f32x4 acc = {0.f, 0.f, 0.f, 0.f};
      acc = __builtin_amdgcn_mfma_f32_16x16x32_bf16(a_lo, b_lo, acc, 0, 0, 0);
      acc = __builtin_amdgcn_mfma_f32_16x16x32_bf16(a_hi, b_hi, acc, 0, 0, 0);
      float bc = biasA[col];
#pragma unroll
      for (int r = 0; r < 4; ++r)
        tile[(qd * 4 + r) * 256 + col] = f2bf(acc[r] + bc);
    }
  }
  __syncthreads();
  // cooperative coalesced copy: 16 rows x 256 shorts = 8KB = 512 x 16B chunks
  unsigned short* dst = obuf + (size_t)R0 * 256;
  uint4* d4 = (uint4*)dst;
  const uint4* s4 = (const uint4*)tile;
  d4[t] = s4[t];
  d4[t + 256] = s4[t + 256];
}

// ---------------- fused fp32 skip GEMM for both directions (LDS-tiled, R12-proven) ----------------
__global__ __launch_bounds__(256) void skip_all(const float* __restrict__ xs, const float* __restrict__ xt,
    const float* __restrict__ Wsk, const float* __restrict__ bsk,
    float* __restrict__ xs_nxt, float* __restrict__ xt_nxt, int p_st, int p_ts, int rtS) {
  __shared__ float Xt[64][68];
  __shared__ float Wl[64][68];
  __shared__ float bias[64];
  int t = threadIdx.x;
  const float* x; const float* W; const float* bb; float* o; int N, rbase;
  if ((int)blockIdx.x < rtS) {
    x = xs; N = NSRC; rbase = blockIdx.x * 64;
    W = Wsk + (size_t)p_ts * 4096; bb = bsk + p_ts * 64; o = xs_nxt;
  } else {
    x = xt; N = NTGT; rbase = (blockIdx.x - rtS) * 64;
    W = Wsk + (size_t)p_st * 4096; bb = bsk + p_st * 64; o = xt_nxt;
  }
#pragma unroll
  for (int i = 0; i < 4; ++i) {
    int slot = i * 256 + t;
    int row = slot >> 4;
    int k4 = slot & 15;
    float4 xv = make_float4(0.f, 0.f, 0.f, 0.f);
    if (rbase + row < N) xv = *(const float4*)&x[(size_t)(rbase + row) * 64 + k4 * 4];
    Xt[k4 * 4 + 0][row] = xv.x;
    Xt[k4 * 4 + 1][row] = xv.y;
    Xt[k4 * 4 + 2][row] = xv.z;
    Xt[k4 * 4 + 3][row] = xv.w;
  }
#pragma unroll
  for (int i = 0; i < 4; ++i) {
    int slot = i * 256 + t;
    int kk = slot >> 4;
    int c4 = slot & 15;
    float4 wv = *(const float4*)&W[(size_t)kk * 64 + c4 * 4];
    *(float4*)&Wl[kk][c4 * 4] = wv;
  }
  if (t < 64) bias[t] = bb[t];
  __syncthreads();

  int c0 = (t & 15) * 4;
  int r0 = (t >> 4) * 4;
  float acc[4][4];
#pragma unroll
  for (int i = 0; i < 4; ++i)
#pragma unroll
    for (int j = 0; j < 4; ++j) acc[i][j] = 0.f;
#pragma unroll 8
  for (int kk = 0; kk < 64; ++kk) {
    float4 xv = *(const float4*)&Xt[kk][r0];
    float4 wv = *(const float4*)&Wl[kk][c0];
    float xr[4] = {xv.x, xv.y, xv.z, xv.w};
    float wc[4] = {wv.x, wv.y, wv.z, wv.w};
#pragma unroll
    for (int i = 0; i < 4; ++i)
#pragma unroll
      for (int j = 0; j < 4; ++j) acc[i][j] = fmaf(xr[i], wc[j], acc[i][j]);
  }
#pragma unroll
  for (int i = 0; i < 4; ++i) {
    int row = rbase + r0 + i;
    if (row < N) {
      float4 ov;
      ov.x = acc[i][0] + bias[c0 + 0];
      ov.y = acc[i][1] + bias[c0 + 1];
      ov.z = acc[i][2] + bias[c0 + 2];
      ov.w = acc[i][3] + bias[c0 + 3];
      *(float4*)&o[(size_t)row * 64 + c0] = ov;
    }
  }
}

// ---------------- fused aggregation for BOTH directions: one WAVE per node ----------------
// R18: fp8 kv rows (512B, uint2/lane gather — halves L2-miss lines vs bf16) on the
// proven R16 structure (unroll-4, DPP reduce, exp2 prefolded scale).
__global__ __launch_bounds__(256) void agg_all(
    const unsigned short* __restrict__ q_small, const unsigned short* __restrict__ kv_big,
    const int* __restrict__ rp_st, const int* __restrict__ es_st,
    float* __restrict__ xt_nxt, unsigned short* __restrict__ xtb_nxt,
    const unsigned short* __restrict__ q_big, const unsigned short* __restrict__ kv_small,
    const int* __restrict__ rp_ts, const int* __restrict__ es_ts,
    float* __restrict__ xs_nxt, unsigned short* __restrict__ xsb_nxt,
    int relu, int stBlocks) {
  const unsigned short* q; const unsigned short* kvi; const int* rowptr; const int* eisrc;
  float* xout; unsigned short* xoutb; int node;
  int wv = threadIdx.x >> 6, l = threadIdx.x & 63;
  if ((int)blockIdx.x < stBlocks) {
    node = blockIdx.x * 4 + wv;
    if (node >= NTGT) return;
    q = q_small; kvi = kv_big; rowptr = rp_st; eisrc = es_st; xout = xt_nxt; xoutb = xtb_nxt;
  } else {
    node = (blockIdx.x - stBlocks) * 4 + wv;
    if (node >= NSRC) return;
    q = q_big; kvi = kv_small; rowptr = rp_ts; eisrc = es_ts; xout = xs_nxt; xoutb = xsb_nxt;
  }
  int j = l & 15;
  float4 qf = bf4_to_f4(*(const bf4*)&q[(size_t)node * QK + l * 4]);
  // fold 1/sqrt(H)=0.125 and log2(e) so the softmax uses raw v_exp (base-2)
  const float QS = 0.125f * 1.44269504088896340736f;
  qf.x *= QS; qf.y *= QS; qf.z *= QS; qf.w *= QS;
  int beg = rowptr[node], end = rowptr[node + 1];

  float lsum = 0.f;
  float4 acc = make_float4(0.f, 0.f, 0.f, 0.f);
  int p = beg;
  for (; p + 4 <= end; p += 4) {
    int s0 = eisrc[p], s1 = eisrc[p + 1], s2 = eisrc[p + 2], s3 = eisrc[p + 3];
    uint2 a0 = *(const uint2*)&kvi[(size_t)s0 * 256 + l * 4];
    uint2 a1 = *(const uint2*)&kvi[(size_t)s1 * 256 + l * 4];
    uint2 a2 = *(const uint2*)&kvi[(size_t)s2 * 256 + l * 4];
    uint2 a3 = *(const uint2*)&kvi[(size_t)s3 * 256 + l * 4];
    f32x2 p00 = __builtin_amdgcn_cvt_pk_f32_fp8(a0.x, false);
    f32x2 p01 = __builtin_amdgcn_cvt_pk_f32_fp8(a0.x, true);
    f32x2 p02 = __builtin_amdgcn_cvt_pk_f32_fp8(a0.y, false);
    f32x2 p03 = __builtin_amdgcn_cvt_pk_f32_fp8(a0.y, true);
    f32x2 p10 = __builtin_amdgcn_cvt_pk_f32_fp8(a1.x, false);
    f32x2 p11 = __builtin_amdgcn_cvt_pk_f32_fp8(a1.x, true);
    f32x2 p12 = __builtin_amdgcn_cvt_pk_f32_fp8(a1.y, false);
    f32x2 p13 = __builtin_amdgcn_cvt_pk_f32_fp8(a1.y, true);
    f32x2 p20 = __builtin_amdgcn_cvt_pk_f32_fp8(a2.x, false);
    f32x2 p21 = __builtin_amdgcn_cvt_pk_f32_fp8(a2.x, true);
    f32x2 p22 = __builtin_amdgcn_cvt_pk_f32_fp8(a2.y, false);
    f32x2 p23 = __builtin_amdgcn_cvt_pk_f32_fp8(a2.y, true);
    f32x2 p30 = __builtin_amdgcn_cvt_pk_f32_fp8(a3.x, false);
    f32x2 p31 = __builtin_amdgcn_cvt_pk_f32_fp8(a3.x, true);
    f32x2 p32 = __builtin_amdgcn_cvt_pk_f32_fp8(a3.y, false);
    f32x2 p33 = __builtin_amdgcn_cvt_pk_f32_fp8(a3.y, true);
    float t0 = qf.x * p00.x + qf.y * p01.x + qf.z * p02.x + qf.w * p03.x;
    float t1 = qf.x * p10.x + qf.y * p11.x + qf.z * p12.x + qf.w * p13.x;
    float t2 = qf.x * p20.x + qf.y * p21.x + qf.z * p22.x + qf.w * p23.x;
    float t3 = qf.x * p30.x + qf.y * p31.x + qf.z * p32.x + qf.w * p33.x;
    t0 = red16(t0); t1 = red16(t1); t2 = red16(t2); t3 = red16(t3);
    float w0 = __builtin_amdgcn_exp2f(t0), w1 = __builtin_amdgcn_exp2f(t1);
    float w2 = __builtin_amdgcn_exp2f(t2), w3 = __builtin_amdgcn_exp2f(t3);
    lsum += (w0 + w1) + (w2 + w3);
    acc.x = fmaf(w0, p00.y, fmaf(w1, p10.y, fmaf(w2, p20.y, fmaf(w3, p30.y, acc.x))));
    acc.y = fmaf(w0, p01.y, fmaf(w1, p11.y, fmaf(w2, p21.y, fmaf(w3, p31.y, acc.y))));
    acc.z = fmaf(w0, p02.y, fmaf(w1, p12.y, fmaf(w2, p22.y, fmaf(w3, p32.y, acc.z))));
    acc.w = fmaf(w0, p03.y, fmaf(w1, p13.y, fmaf(w2, p23.y, fmaf(w3, p33.y, acc.w))));
  }
  for (; p < end; ++p) {
    int s0 = eisrc[p];
    uint2 a0 = *(const uint2*)&kvi[(size_t)s0 * 256 + l * 4];
    f32x2 p00 = __builtin_amdgcn_cvt_pk_f32_fp8(a0.x, false);
    f32x2 p01 = __builtin_amdgcn_cvt_pk_f32_fp8(a0.x, true);
    f32x2 p02 = __builtin_amdgcn_cvt_pk_f32_fp8(a0.y, false);
    f32x2 p03 = __builtin_amdgcn_cvt_pk_f32_fp8(a0.y, true);
    float s = qf.x * p00.x + qf.y * p01.x + qf.z * p02.x + qf.w * p03.x;
    s = red16(s);
    float w = __builtin_amdgcn_exp2f(s);
    lsum += w;
    acc.x = fmaf(w, p00.y, acc.x);
    acc.y = fmaf(w, p01.y, acc.y);
    acc.z = fmaf(w, p02.y, acc.z);
    acc.w = fmaf(w, p03.y, acc.w);
  }

  float inv = (lsum > 0.f) ? 1.f / lsum : 0.f;
  float4 r;
  r.x = acc.x * inv; r.y = acc.y * inv; r.z = acc.z * inv; r.w = acc.w * inv;
  r.x += __shfl_xor(r.x, 16, 64); r.x += __shfl_xor(r.x, 32, 64);
  r.y += __shfl_xor(r.y, 16, 64); r.y += __shfl_xor(r.y, 32, 64);
  r.z += __shfl_xor(r.z, 16, 64); r.z += __shfl_xor(r.z, 32, 64);
  r.w += __shfl_xor(r.w, 16, 64); r.w += __shfl_xor(r.w, 32, 64);
  if (l < 16) {
    float4 sk = *(const float4*)&xout[(size_t)node * HD + j * 4];
    float4 o;
    o.x = sk.x + 0.25f * r.x;
    o.y = sk.y + 0.25f * r.y;
    o.z = sk.z + 0.25f * r.z;
    o.w = sk.w + 0.25f * r.w;
    if (relu) {
      o.x = fmaxf(o.x, 0.f); o.y = fmaxf(o.y, 0.f);
      o.z = fmaxf(o.z, 0.f); o.w = fmaxf(o.w, 0.f);
    }
    *(float4*)&xout[(size_t)node * HD + j * 4] = o;
    bf4 ob;
    ob.x = f2bf(o.x); ob.y = f2bf(o.y); ob.z = f2bf(o.z); ob.w = f2bf(o.w);
    *(bf4*)&xoutb[(size_t)node * HD + j * 4] = ob;
  }
}

// ---------------- classifier: 16 lanes per pair, float4 loads ----------------
__global__ __launch_bounds__(256) void classifier_kernel(const float* __restrict__ xs, const float* __restrict__ xt,
    const int* __restrict__ ls, const int* __restrict__ lt, float* __restrict__ out, int n) {
  int g = blockIdx.x * 256 + threadIdx.x;
  int pair = g >> 4, j = g & 15;
  if (pair >= n) return;
  int a = ls[pair], b = lt[pair];
  float4 xa = *(const float4*)&xs[(size_t)a * HD + j * 4];
  float4 xb = *(const float4*)&xt[(size_t)b * HD + j * 4];
  float s = xa.x * xb.x + xa.y * xb.y + xa.z * xb.z + xa.w * xb.w;
  s = red16(s);
  if (j == 0) out[pair] = s;
}

// ---------------- launch ----------------
extern "C" void kernel_launch(void* const* d_in, const int* in_sizes, int n_in,
                              void* d_out, int out_size, void* d_ws, size_t ws_size,
                              hipStream_t stream) {
  const float* src_emb = (const float*)d_in[0];
  const float* tgt_emb = (const float*)d_in[1];
  const float* Wq = (const float*)d_in[2];
  const float* bq = (const float*)d_in[3];
  const float* Wk = (const float*)d_in[4];
  const float* bk = (const float*)d_in[5];
  const float* Wv = (const float*)d_in[6];
  const float* bv = (const float*)d_in[7];
  const float* Wsk = (const float*)d_in[8];
  const float* bsk = (const float*)d_in[9];
  const int* nid_s = (const int*)d_in[10];
  const int* nid_t = (const int*)d_in[11];
  const int* e_st = (const int*)d_in[12];
  const int* e_ts = (const int*)d_in[13];
  const int* e_lbl = (const int*)d_in[14];
  float* out = (float*)d_out;

  char* ws = (char*)d_ws;
  size_t off = 0;
  auto alloc = [&](size_t bytes) -> void* {
    void* p = ws + off;
    off += (bytes + 255) & ~(size_t)255;
    return p;
  };
  unsigned short* kv_big   = (unsigned short*)alloc((size_t)NSRC * 256 * 2);  // st k/v fp8 pairs
  unsigned short* q_big    = (unsigned short*)alloc((size_t)NSRC * QK * 2);   // ts q
  unsigned short* kv_small = (unsigned short*)alloc((size_t)NTGT * 256 * 2);  // ts k/v fp8 pairs
  unsigned short* q_small  = (unsigned short*)alloc((size_t)NTGT * QK * 2);   // st q
  float* xsA = (float*)alloc((size_t)NSRC * HD * 4);
  float* xsB = (float*)alloc((size_t)NSRC * HD * 4);
  float* xtA = (float*)alloc((size_t)NTGT * HD * 4);
  float* xtB = (float*)alloc((size_t)NTGT * HD * 4);
  unsigned short* xsAb = (unsigned short*)alloc((size_t)NSRC * HD * 2);
  unsigned short* xsBb = (unsigned short*)alloc((size_t)NSRC * HD * 2);
  unsigned short* xtAb = (unsigned short*)alloc((size_t)NTGT * HD * 2);
  unsigned short* xtBb = (unsigned short*)alloc((size_t)NTGT * HD * 2);
  unsigned short* Wtq = (unsigned short*)alloc((size_t)4 * 16384 * 2);
  unsigned short* Wtk = (unsigned short*)alloc((size_t)4 * 16384 * 2);
  unsigned short* Wtv = (unsigned short*)alloc((size_t)4 * 16384 * 2);
  int* rp_st = (int*)alloc((size_t)(NTGT + 1) * 4);
  int* es_st = (int*)alloc((size_t)NEDGE * 4);
  int* rp_ts = (int*)alloc((size_t)(NSRC + 1) * 4);
  int* es_ts = (int*)alloc((size_t)NEDGE * 4);
  int* cursor = (int*)alloc((size_t)NTOT * 4);
  int* counts = (int*)alloc((size_t)NTOT * 4);
  int* incl_buf = (int*)alloc((size_t)NTOT * 4);
  int* blocksums = (int*)alloc(64 * 4);
  int* boff = (int*)alloc(64 * 4);
  (void)ws_size; (void)in_sizes; (void)n_in; (void)out_size;

  auto cdiv = [](int a, int b) { return (a + b - 1) / b; };
  const int GATHER_BLK = cdiv(NTOT * HD, 256);          // 15000
  const int SETUP_BLK = 48 + GATHER_BLK + cdiv(NTOT, 256);
  const int RT_S = cdiv(NSRC, 64);                      // 782
  const int RT_T = cdiv(NTGT, 64);                      // 157
  const int NBLK_PROJ = 2 * (NSRC / 16) + 2 * (NTGT / 16);  // kv+q = 7500
  const int ST_BLK = cdiv(NTGT, 4);                     // 2500
  const int NBLK_AGG = ST_BLK + cdiv(NSRC, 4);          // 15000

  // fused setup: weight transpose + feature gather + counts zero
  setup_kernel<<<SETUP_BLK, 256, 0, stream>>>(Wq, Wk, Wv, Wtq, Wtk, Wtv,
                                              src_emb, nid_s, tgt_emb, nid_t,
                                              xsA, xsAb, xtA, xtAb, counts, GATHER_BLK);

  // CSR build for both edge sets
  hist_all_kernel<<<cdiv(2 * NEDGE, 256), 256, 0, stream>>>(e_st, e_ts, counts);
  scan1_kernel<<<cdiv(NTOT, 1024), 256, 0, stream>>>(counts, incl_buf, blocksums, NTOT);
  scan2_kernel<<<1, 64, 0, stream>>>(blocksums, boff, cdiv(NTOT, 1024));
  scan3_kernel<<<cdiv(NTOT, 256), 256, 0, stream>>>(incl_buf, counts, boff, rp_st, rp_ts, cursor);
  scatter_all_kernel<<<cdiv(2 * NEDGE, 256), 256, 0, stream>>>(e_st, e_ts, cursor, es_st, es_ts);

  const float* xs_cur = xsA; float* xs_nxt = xsB;
  const float* xt_cur = xtA; float* xt_nxt = xtB;
  const unsigned short* xsb_cur = xsAb; unsigned short* xsb_nxt = xsBb;
  const unsigned short* xtb_cur = xtAb; unsigned short* xtb_nxt = xtBb;
  for (int l = 0; l < 2; ++l) {
    int relu = (l == 0) ? 1 : 0;
    int p_st = l * 2 + 0, p_ts = l * 2 + 1;
    proj_all<<<NBLK_PROJ, 256, 0, stream>>>(xsb_cur, xtb_cur, Wtq, Wtk, Wtv, bq, bk, bv,
                                            kv_big, q_big, kv_small, q_small, p_st, p_ts);
    skip_all<<<RT_S + RT_T, 256, 0, stream>>>(xs_cur, xt_cur, Wsk, bsk, xs_nxt, xt_nxt, p_st, p_ts, RT_S);
    agg_all<<<NBLK_AGG, 256, 0, stream>>>(q_small, kv_big, rp_st, es_st, xt_nxt, xtb_nxt,
                                          q_big, kv_small, rp_ts, es_ts, xs_nxt, xsb_nxt,
                                          relu, ST_BLK);
    { const float* t = xs_nxt; xs_nxt = (float*)xs_cur; xs_cur = t; }
    { const float* t = xt_nxt; xt_nxt = (float*)xt_cur; xt_cur = t; }
    { const unsigned short* t = xsb_nxt; xsb_nxt = (unsigned short*)xsb_cur; xsb_cur = t; }
    { const unsigned short* t = xtb_nxt; xtb_nxt = (unsigned short*)xtb_cur; xtb_cur = t; }
  }

  classifier_kernel<<<cdiv(NLBL * 16, 256), 256, 0, stream>>>(xs_cur, xt_cur, e_lbl, e_lbl + NLBL, out, NLBL);
}

// Round 7
// 331.952 us; speedup vs baseline: 1.3688x; 1.1759x over previous
//
#include <hip/hip_runtime.h>

constexpr int NSRC = 50000;
constexpr int NTGT = 10000;
constexpr int NEDGE = 250000;
constexpr int NLBL = 200000;
constexpr int HD = 64;     // hidden dim (per head)
constexpr int NH = 4;      // heads
constexpr int QK = 256;    // HD*NH
constexpr int NTOT = NSRC + NTGT;

typedef __attribute__((ext_vector_type(8))) short bf16x8;
typedef __attribute__((ext_vector_type(4))) float f32x4;
typedef __attribute__((ext_vector_type(2))) float f32x2;

// ---------------- bf16 helpers ----------------
__device__ __forceinline__ unsigned short f2bf(float f) {
  unsigned u = __float_as_uint(f);
  u += 0x7FFFu + ((u >> 16) & 1u);   // round-to-nearest-even
  return (unsigned short)(u >> 16);
}
__device__ __forceinline__ float bf2f(unsigned short b) {
  return __uint_as_float((unsigned)b << 16);
}
struct bf4 { unsigned short x, y, z, w; };
__device__ __forceinline__ float4 bf4_to_f4(bf4 u) {
  return make_float4(bf2f(u.x), bf2f(u.y), bf2f(u.z), bf2f(u.w));
}

// ---------------- DPP 16-lane sum reduction (no LDS pipe, pure VALU) ----------------
template<int CTRL>
__device__ __forceinline__ float dpp_addf(float x) {
  int p = __builtin_amdgcn_update_dpp(0, __float_as_int(x), CTRL, 0xf, 0xf, true);
  return x + __int_as_float(p);
}
__device__ __forceinline__ float red16(float x) {
  x = dpp_addf<0xB1>(x);    // + lane^1 within quad
  x = dpp_addf<0x4E>(x);    // + lane^2 within quad
  x = dpp_addf<0x141>(x);   // + mirrored half-row (combines quads)
  x = dpp_addf<0x140>(x);   // + mirrored row (combines halves)
  return x;                 // all 16 lanes of the row hold the row sum
}

// ---------------- fused setup: weight transpose + feature gather + counts zero ----------------
__global__ __launch_bounds__(256) void setup_kernel(
    const float* __restrict__ Wq, const float* __restrict__ Wk, const float* __restrict__ Wv,
    unsigned short* __restrict__ Wtq, unsigned short* __restrict__ Wtk, unsigned short* __restrict__ Wtv,
    const float* __restrict__ semb, const int* __restrict__ sids,
    const float* __restrict__ temb, const int* __restrict__ tids,
    float* __restrict__ xs, unsigned short* __restrict__ xsb,
    float* __restrict__ xt, unsigned short* __restrict__ xtb,
    int* __restrict__ counts, int nGatherBlk) {
  __shared__ float tile[64][65];
  int b = blockIdx.x;
  int t = threadIdx.x;
  if (b < 48) {
    int mat = b >> 2, ct = b & 3;
    int grp = mat >> 2, p = mat & 3;
    const float* W = (grp == 0) ? Wq : (grp == 1) ? Wk : Wv;
    unsigned short* Wt = (grp == 0) ? Wtq : (grp == 1) ? Wtk : Wtv;
    W += (size_t)p * 16384;
    Wt += (size_t)p * 16384;
    int c = t & 63, r4 = t >> 6;
    for (int rr = 0; rr < 64; rr += 4)
      tile[rr + r4][c] = W[(size_t)(rr + r4) * 256 + ct * 64 + c];
    __syncthreads();
    for (int rr = 0; rr < 64; rr += 4) {
      int nloc = rr + r4;
      Wt[(size_t)(ct * 64 + nloc) * 64 + c] = f2bf(tile[c][nloc]);
    }
  } else if (b < 48 + nGatherBlk) {
    int i = (b - 48) * 256 + t;
    if (i < NSRC * HD) {
      float v = semb[(size_t)sids[i >> 6] * HD + (i & 63)];
      xs[i] = v;
      xsb[i] = f2bf(v);
    } else if (i < NTOT * HD) {
      int j = i - NSRC * HD;
      float v = temb[(size_t)tids[j >> 6] * HD + (j & 63)];
      xt[j] = v;
      xtb[j] = f2bf(v);
    }
  } else {
    int i = (b - 48 - nGatherBlk) * 256 + t;
    if (i < NTOT) counts[i] = 0;
  }
}

// ---------------- CSR build (both edge sets, concatenated counts) ----------------

__global__ __launch_bounds__(256) void hist_all_kernel(const int* __restrict__ e_st, const int* __restrict__ e_ts,
                                                       int* __restrict__ counts) {
  int i = blockIdx.x * 256 + threadIdx.x;
  if (i < NEDGE) atomicAdd(&counts[e_st[NEDGE + i]], 1);
  else if (i < 2 * NEDGE) atomicAdd(&counts[NTGT + e_ts[NEDGE + (i - NEDGE)]], 1);
}

__global__ __launch_bounds__(256) void scan1_kernel(const int* __restrict__ counts, int* __restrict__ incl,
                                                    int* __restrict__ blocksums, int n) {
  __shared__ int wtot[4];
  int t = threadIdx.x;
  int i0 = blockIdx.x * 1024 + t * 4;
  int e0 = (i0 + 0 < n) ? counts[i0 + 0] : 0;
  int e1 = (i0 + 1 < n) ? counts[i0 + 1] : 0;
  int e2 = (i0 + 2 < n) ? counts[i0 + 2] : 0;
  int e3 = (i0 + 3 < n) ? counts[i0 + 3] : 0;
  int s0 = e0, s1 = s0 + e1, s2 = s1 + e2, s3 = s2 + e3;
  int tsum = s3;
  int inc = tsum;
#pragma unroll
  for (int o = 1; o < 64; o <<= 1) {
    int u = __shfl_up(inc, o, 64);
    if ((t & 63) >= o) inc += u;
  }
  int wave = t >> 6;
  if ((t & 63) == 63) wtot[wave] = inc;
  __syncthreads();
  int woff = 0;
#pragma unroll
  for (int w_ = 0; w_ < 4; ++w_) if (w_ < wave) woff += wtot[w_];
  int toff = woff + inc - tsum;
  if (i0 + 0 < n) incl[i0 + 0] = toff + s0;
  if (i0 + 1 < n) incl[i0 + 1] = toff + s1;
  if (i0 + 2 < n) incl[i0 + 2] = toff + s2;
  if (i0 + 3 < n) incl[i0 + 3] = toff + s3;
  if (t == 255) blocksums[blockIdx.x] = woff + inc;
}

__global__ __launch_bounds__(64) void scan2_kernel(const int* __restrict__ blocksums, int* __restrict__ boff, int nb) {
  int t = threadIdx.x;
  int v = (t < nb) ? blocksums[t] : 0;
  int inc = v;
#pragma unroll
  for (int o = 1; o < 64; o <<= 1) {
    int u = __shfl_up(inc, o, 64);
    if (t >= o) inc += u;
  }
  if (t < nb) boff[t] = inc - v;
}

__global__ __launch_bounds__(256) void scan3_kernel(const int* __restrict__ incl, const int* __restrict__ counts,
                                                    const int* __restrict__ boff, int* __restrict__ rp_st,
                                                    int* __restrict__ rp_ts, int* __restrict__ cursor) {
  int i = blockIdx.x * 256 + threadIdx.x;
  if (i < NTOT) {
    int val = incl[i] + boff[i >> 10];
    if (i < NTGT) {
      rp_st[i + 1] = val;
      cursor[i] = val - counts[i];
      if (i == 0) rp_st[0] = 0;
    } else {
      int v2 = val - NEDGE;
      rp_ts[i - NTGT + 1] = v2;
      cursor[i] = v2 - counts[i];
      if (i == NTGT) rp_ts[0] = 0;
    }
  }
}

__global__ __launch_bounds__(256) void scatter_all_kernel(const int* __restrict__ e_st, const int* __restrict__ e_ts,
                                                          int* __restrict__ cursor, int* __restrict__ es_st,
                                                          int* __restrict__ es_ts) {
  int i = blockIdx.x * 256 + threadIdx.x;
  if (i < NEDGE) {
    int d = e_st[NEDGE + i];
    int p = atomicAdd(&cursor[d], 1);
    es_st[p] = e_st[i];
  } else if (i < 2 * NEDGE) {
    int j = i - NEDGE;
    int d = e_ts[NEDGE + j];
    int p = atomicAdd(&cursor[NTGT + d], 1);
    es_ts[p] = e_ts[j];
  }
}

// ---------------- MFMA projection dispatch per layer (kv + q only) ----------------
// R18: kv stored as packed fp8 e4m3 (k byte0, v byte1 per col).
// R21: weights-in-register + T=8 row-tile loop per block. R20 showed proj is NOT
// store-bound (31M->3.9M stores changed nothing); it is latency-bound: 16-row blocks
// die after one serial mem chain (Mfma 3.7 / VALU 10 / HBM 15% all idle). Loop keeps
// B-fragments resident, 8x fewer blocks (7500->940), per-wave loads independent
// across iterations -> real MLP. Direct stores, no barrier, 1-deep clamped prefetch.
__global__ __launch_bounds__(256) void proj_all(
    const unsigned short* __restrict__ xsb, const unsigned short* __restrict__ xtb,
    const unsigned short* __restrict__ Wtq, const unsigned short* __restrict__ Wtk,
    const unsigned short* __restrict__ Wtv,
    const float* __restrict__ bq, const float* __restrict__ bk, const float* __restrict__ bv,
    unsigned short* __restrict__ kv_big, unsigned short* __restrict__ q_big,
    unsigned short* __restrict__ kv_small, unsigned short* __restrict__ q_small,
    int p_st, int p_ts) {
  constexpr int T = 8;
  constexpr int T1 = NSRC / 16;             // 3125 row tiles (big)
  constexpr int T2 = NTGT / 16;             // 625 row tiles (small)
  constexpr int G1 = (T1 + T - 1) / T;      // 391
  constexpr int G2 = (T2 + T - 1) / T;      // 79
  int b = blockIdx.x;
  int t = threadIdx.x;
  int w = t >> 6, l = t & 63;
  int m = l & 15, qd = l >> 4;
  const unsigned short* xb; const unsigned short* WtA; const unsigned short* WtB = nullptr;
  const float* biasA; const float* biasB = nullptr;
  unsigned short* obuf;
  int tile0, ntiles, mode;
  if (b < G1) {                       // kv_s (params p_st)
    xb = xsb; tile0 = b * T; ntiles = min(T, T1 - tile0); mode = 0;
    WtA = Wtk + (size_t)p_st * 16384; biasA = bk + p_st * 256;
    WtB = Wtv + (size_t)p_st * 16384; biasB = bv + p_st * 256;
    obuf = kv_big;
  } else if (b < G1 + G2) {           // kv_t (params p_ts)
    xb = xtb; tile0 = (b - G1) * T; ntiles = min(T, T2 - tile0); mode = 0;
    WtA = Wtk + (size_t)p_ts * 16384; biasA = bk + p_ts * 256;
    WtB = Wtv + (size_t)p_ts * 16384; biasB = bv + p_ts * 256;
    obuf = kv_small;
  } else if (b < 2 * G1 + G2) {       // q_s (params p_ts)
    xb = xsb; tile0 = (b - G1 - G2) * T; ntiles = min(T, T1 - tile0); mode = 1;
    WtA = Wtq + (size_t)p_ts * 16384; biasA = bq + p_ts * 256;
    obuf = q_big;
  } else {                            // q_t (params p_st)
    xb = xtb; tile0 = (b - 2 * G1 - G2) * T; ntiles = min(T, T2 - tile0); mode = 1;
    WtA = Wtq + (size_t)p_st * 16384; biasA = bq + p_st * 256;
    obuf = q_small;
  }

  if (mode == 0) {
    // resident weight fragments: 16 x bf16x8 = 64 VGPRs + 8 bias floats
    bf16x8 wkl[4], wkh[4], wvl[4], wvh[4];
    float bkc[4], bvc[4];
#pragma unroll
    for (int i = 0; i < 4; ++i) {
      int col = (w * 4 + i) * 16 + m;
      const unsigned short* wk = WtA + (size_t)col * 64 + qd * 8;
      const unsigned short* wv = WtB + (size_t)col * 64 + qd * 8;
      wkl[i] = *(const bf16x8*)wk; wkh[i] = *(const bf16x8*)(wk + 32);
      wvl[i] = *(const bf16x8*)wv; wvh[i] = *(const bf16x8*)(wv + 32);
      bkc[i] = biasA[col]; bvc[i] = biasB[col];
    }
    const unsigned short* xr0 = xb + (size_t)(tile0 * 16 + m) * 64 + qd * 8;
    bf16x8 a_lo = *(const bf16x8*)xr0;
    bf16x8 a_hi = *(const bf16x8*)(xr0 + 32);
    for (int tt = 0; tt < ntiles; ++tt) {
      int ntt = (tt + 1 < ntiles) ? tt + 1 : tt;   // clamped prefetch
      const unsigned short* xn = xb + (size_t)((tile0 + ntt) * 16 + m) * 64 + qd * 8;
      bf16x8 n_lo = *(const bf16x8*)xn;
      bf16x8 n_hi = *(const bf16x8*)(xn + 32);
      int R0 = (tile0 + tt) * 16;
#pragma unroll
      for (int i = 0; i < 4; ++i) {
        f32x4 ak = {0.f, 0.f, 0.f, 0.f}, av = {0.f, 0.f, 0.f, 0.f};
        ak = __builtin_amdgcn_mfma_f32_16x16x32_bf16(a_lo, wkl[i], ak, 0, 0, 0);
        ak = __builtin_amdgcn_mfma_f32_16x16x32_bf16(a_hi, wkh[i], ak, 0, 0, 0);
        av = __builtin_amdgcn_mfma_f32_16x16x32_bf16(a_lo, wvl[i], av, 0, 0, 0);
        av = __builtin_amdgcn_mfma_f32_16x16x32_bf16(a_hi, wvh[i], av, 0, 0, 0);
        int col = (w * 4 + i) * 16 + m;
        unsigned short* obase = obuf + (size_t)(R0 + qd * 4) * 256 + col;
#pragma unroll
        for (int r = 0; r < 4; ++r) {
          unsigned pk = __builtin_amdgcn_cvt_pk_fp8_f32(ak[r] + bkc[i], av[r] + bvc[i], 0, false);
          obase[(size_t)r * 256] = (unsigned short)pk;
        }
      }
      a_lo = n_lo; a_hi = n_hi;
    }
  } else {
    bf16x8 wql[4], wqh[4];
    float bqc[4];
#pragma unroll
    for (int i = 0; i < 4; ++i) {
      int col = (w * 4 + i) * 16 + m;
      const unsigned short* wq = WtA + (size_t)col * 64 + qd * 8;
      wql[i] = *(const bf16x8*)wq; wqh[i] = *(const bf16x8*)(wq + 32);
      bqc[i] = biasA[col];
    }
    const unsigned short* xr0 = xb + (size_t)(tile0 * 16 + m) * 64 + qd * 8;
    bf16x8 a_lo = *(const bf16x8*)xr0;
    bf16x8 a_hi = *(const bf16x8*)(xr0 + 32);
    for (int tt = 0; tt < ntiles; ++tt) {
      int ntt = (tt + 1 < ntiles) ? tt + 1 : tt;
      const unsigned short* xn = xb + (size_t)((tile0 + ntt) * 16 + m) * 64 + qd * 8;
      bf16x8 n_lo = *(const bf16x8*)xn;
      bf16x8 n_hi = *(const bf16x8*)(xn + 32);
      int R0 = (tile0 + tt) * 16;
#pragma unroll
      for (int i = 0; i < 4; ++i) {
        f32x4 acc = {0.f, 0.f, 0.f, 0.f};
        acc = __builtin_amdgcn_mfma_f32_16x16x32_bf16(a_lo, wql[i], acc, 0, 0, 0);
        acc = __builtin_amdgcn_mfma_f32_16x16x32_bf16(a_hi, wqh[i], acc, 0, 0, 0);
        int col = (w * 4 + i) * 16 + m;
        unsigned short* obase = obuf + (size_t)(R0 + qd * 4) * 256 + col;
#pragma unroll
        for (int r = 0; r < 4; ++r)
          obase[(size_t)r * 256] = f2bf(acc[r] + bqc[i]);
      }
      a_lo = n_lo; a_hi = n_hi;
    }
  }
}

// ---------------- fused fp32 skip GEMM for both directions (LDS-tiled, R12-proven) ----------------
__global__ __launch_bounds__(256) void skip_all(const float* __restrict__ xs, const float* __restrict__ xt,
    const float* __restrict__ Wsk, const float* __restrict__ bsk,
    float* __restrict__ xs_nxt, float* __restrict__ xt_nxt, int p_st, int p_ts, int rtS) {
  __shared__ float Xt[64][68];
  __shared__ float Wl[64][68];
  __shared__ float bias[64];
  int t = threadIdx.x;
  const float* x; const float* W; const float* bb; float* o; int N, rbase;
  if ((int)blockIdx.x < rtS) {
    x = xs; N = NSRC; rbase = blockIdx.x * 64;
    W = Wsk + (size_t)p_ts * 4096; bb = bsk + p_ts * 64; o = xs_nxt;
  } else {
    x = xt; N = NTGT; rbase = (blockIdx.x - rtS) * 64;
    W = Wsk + (size_t)p_st * 4096; bb = bsk + p_st * 64; o = xt_nxt;
  }
#pragma unroll
  for (int i = 0; i < 4; ++i) {
    int slot = i * 256 + t;
    int row = slot >> 4;
    int k4 = slot & 15;
    float4 xv = make_float4(0.f, 0.f, 0.f, 0.f);
    if (rbase + row < N) xv = *(const float4*)&x[(size_t)(rbase + row) * 64 + k4 * 4];
    Xt[k4 * 4 + 0][row] = xv.x;
    Xt[k4 * 4 + 1][row] = xv.y;
    Xt[k4 * 4 + 2][row] = xv.z;
    Xt[k4 * 4 + 3][row] = xv.w;
  }
#pragma unroll
  for (int i = 0; i < 4; ++i) {
    int slot = i * 256 + t;
    int kk = slot >> 4;
    int c4 = slot & 15;
    float4 wv = *(const float4*)&W[(size_t)kk * 64 + c4 * 4];
    *(float4*)&Wl[kk][c4 * 4] = wv;
  }
  if (t < 64) bias[t] = bb[t];
  __syncthreads();

  int c0 = (t & 15) * 4;
  int r0 = (t >> 4) * 4;
  float acc[4][4];
#pragma unroll
  for (int i = 0; i < 4; ++i)
#pragma unroll
    for (int j = 0; j < 4; ++j) acc[i][j] = 0.f;
#pragma unroll 8
  for (int kk = 0; kk < 64; ++kk) {
    float4 xv = *(const float4*)&Xt[kk][r0];
    float4 wv = *(const float4*)&Wl[kk][c0];
    float xr[4] = {xv.x, xv.y, xv.z, xv.w};
    float wc[4] = {wv.x, wv.y, wv.z, wv.w};
#pragma unroll
    for (int i = 0; i < 4; ++i)
#pragma unroll
      for (int j = 0; j < 4; ++j) acc[i][j] = fmaf(xr[i], wc[j], acc[i][j]);
  }
#pragma unroll
  for (int i = 0; i < 4; ++i) {
    int row = rbase + r0 + i;
    if (row < N) {
      float4 ov;
      ov.x = acc[i][0] + bias[c0 + 0];
      ov.y = acc[i][1] + bias[c0 + 1];
      ov.z = acc[i][2] + bias[c0 + 2];
      ov.w = acc[i][3] + bias[c0 + 3];
      *(float4*)&o[(size_t)row * 64 + c0] = ov;
    }
  }
}

// ---------------- fused aggregation for BOTH directions: one WAVE per node ----------------
// R18: fp8 kv rows (512B, uint2/lane gather — halves L2-miss lines vs bf16) on the
// proven R16 structure (unroll-4, DPP reduce, exp2 prefolded scale).
__global__ __launch_bounds__(256) void agg_all(
    const unsigned short* __restrict__ q_small, const unsigned short* __restrict__ kv_big,
    const int* __restrict__ rp_st, const int* __restrict__ es_st,
    float* __restrict__ xt_nxt, unsigned short* __restrict__ xtb_nxt,
    const unsigned short* __restrict__ q_big, const unsigned short* __restrict__ kv_small,
    const int* __restrict__ rp_ts, const int* __restrict__ es_ts,
    float* __restrict__ xs_nxt, unsigned short* __restrict__ xsb_nxt,
    int relu, int stBlocks) {
  const unsigned short* q; const unsigned short* kvi; const int* rowptr; const int* eisrc;
  float* xout; unsigned short* xoutb; int node;
  int wv = threadIdx.x >> 6, l = threadIdx.x & 63;
  if ((int)blockIdx.x < stBlocks) {
    node = blockIdx.x * 4 + wv;
    if (node >= NTGT) return;
    q = q_small; kvi = kv_big; rowptr = rp_st; eisrc = es_st; xout = xt_nxt; xoutb = xtb_nxt;
  } else {
    node = (blockIdx.x - stBlocks) * 4 + wv;
    if (node >= NSRC) return;
    q = q_big; kvi = kv_small; rowptr = rp_ts; eisrc = es_ts; xout = xs_nxt; xoutb = xsb_nxt;
  }
  int j = l & 15;
  float4 qf = bf4_to_f4(*(const bf4*)&q[(size_t)node * QK + l * 4]);
  // fold 1/sqrt(H)=0.125 and log2(e) so the softmax uses raw v_exp (base-2)
  const float QS = 0.125f * 1.44269504088896340736f;
  qf.x *= QS; qf.y *= QS; qf.z *= QS; qf.w *= QS;
  int beg = rowptr[node], end = rowptr[node + 1];

  float lsum = 0.f;
  float4 acc = make_float4(0.f, 0.f, 0.f, 0.f);
  int p = beg;
  for (; p + 4 <= end; p += 4) {
    int s0 = eisrc[p], s1 = eisrc[p + 1], s2 = eisrc[p + 2], s3 = eisrc[p + 3];
    uint2 a0 = *(const uint2*)&kvi[(size_t)s0 * 256 + l * 4];
    uint2 a1 = *(const uint2*)&kvi[(size_t)s1 * 256 + l * 4];
    uint2 a2 = *(const uint2*)&kvi[(size_t)s2 * 256 + l * 4];
    uint2 a3 = *(const uint2*)&kvi[(size_t)s3 * 256 + l * 4];
    f32x2 p00 = __builtin_amdgcn_cvt_pk_f32_fp8(a0.x, false);
    f32x2 p01 = __builtin_amdgcn_cvt_pk_f32_fp8(a0.x, true);
    f32x2 p02 = __builtin_amdgcn_cvt_pk_f32_fp8(a0.y, false);
    f32x2 p03 = __builtin_amdgcn_cvt_pk_f32_fp8(a0.y, true);
    f32x2 p10 = __builtin_amdgcn_cvt_pk_f32_fp8(a1.x, false);
    f32x2 p11 = __builtin_amdgcn_cvt_pk_f32_fp8(a1.x, true);
    f32x2 p12 = __builtin_amdgcn_cvt_pk_f32_fp8(a1.y, false);
    f32x2 p13 = __builtin_amdgcn_cvt_pk_f32_fp8(a1.y, true);
    f32x2 p20 = __builtin_amdgcn_cvt_pk_f32_fp8(a2.x, false);
    f32x2 p21 = __builtin_amdgcn_cvt_pk_f32_fp8(a2.x, true);
    f32x2 p22 = __builtin_amdgcn_cvt_pk_f32_fp8(a2.y, false);
    f32x2 p23 = __builtin_amdgcn_cvt_pk_f32_fp8(a2.y, true);
    f32x2 p30 = __builtin_amdgcn_cvt_pk_f32_fp8(a3.x, false);
    f32x2 p31 = __builtin_amdgcn_cvt_pk_f32_fp8(a3.x, true);
    f32x2 p32 = __builtin_amdgcn_cvt_pk_f32_fp8(a3.y, false);
    f32x2 p33 = __builtin_amdgcn_cvt_pk_f32_fp8(a3.y, true);
    float t0 = qf.x * p00.x + qf.y * p01.x + qf.z * p02.x + qf.w * p03.x;
    float t1 = qf.x * p10.x + qf.y * p11.x + qf.z * p12.x + qf.w * p13.x;
    float t2 = qf.x * p20.x + qf.y * p21.x + qf.z * p22.x + qf.w * p23.x;
    float t3 = qf.x * p30.x + qf.y * p31.x + qf.z * p32.x + qf.w * p33.x;
    t0 = red16(t0); t1 = red16(t1); t2 = red16(t2); t3 = red16(t3);
    float w0 = __builtin_amdgcn_exp2f(t0), w1 = __builtin_amdgcn_exp2f(t1);
    float w2 = __builtin_amdgcn_exp2f(t2), w3 = __builtin_amdgcn_exp2f(t3);
    lsum += (w0 + w1) + (w2 + w3);
    acc.x = fmaf(w0, p00.y, fmaf(w1, p10.y, fmaf(w2, p20.y, fmaf(w3, p30.y, acc.x))));
    acc.y = fmaf(w0, p01.y, fmaf(w1, p11.y, fmaf(w2, p21.y, fmaf(w3, p31.y, acc.y))));
    acc.z = fmaf(w0, p02.y, fmaf(w1, p12.y, fmaf(w2, p22.y, fmaf(w3, p32.y, acc.z))));
    acc.w = fmaf(w0, p03.y, fmaf(w1, p13.y, fmaf(w2, p23.y, fmaf(w3, p33.y, acc.w))));
  }
  for (; p < end; ++p) {
    int s0 = eisrc[p];
    uint2 a0 = *(const uint2*)&kvi[(size_t)s0 * 256 + l * 4];
    f32x2 p00 = __builtin_amdgcn_cvt_pk_f32_fp8(a0.x, false);
    f32x2 p01 = __builtin_amdgcn_cvt_pk_f32_fp8(a0.x, true);
    f32x2 p02 = __builtin_amdgcn_cvt_pk_f32_fp8(a0.y, false);
    f32x2 p03 = __builtin_amdgcn_cvt_pk_f32_fp8(a0.y, true);
    float s = qf.x * p00.x + qf.y * p01.x + qf.z * p02.x + qf.w * p03.x;
    s = red16(s);
    float w = __builtin_amdgcn_exp2f(s);
    lsum += w;
    acc.x = fmaf(w, p00.y, acc.x);
    acc.y = fmaf(w, p01.y, acc.y);
    acc.z = fmaf(w, p02.y, acc.z);
    acc.w = fmaf(w, p03.y, acc.w);
  }

  float inv = (lsum > 0.f) ? 1.f / lsum : 0.f;
  float4 r;
  r.x = acc.x * inv; r.y = acc.y * inv; r.z = acc.z * inv; r.w = acc.w * inv;
  r.x += __shfl_xor(r.x, 16, 64); r.x += __shfl_xor(r.x, 32, 64);
  r.y += __shfl_xor(r.y, 16, 64); r.y += __shfl_xor(r.y, 32, 64);
  r.z += __shfl_xor(r.z, 16, 64); r.z += __shfl_xor(r.z, 32, 64);
  r.w += __shfl_xor(r.w, 16, 64); r.w += __shfl_xor(r.w, 32, 64);
  if (l < 16) {
    float4 sk = *(const float4*)&xout[(size_t)node * HD + j * 4];
    float4 o;
    o.x = sk.x + 0.25f * r.x;
    o.y = sk.y + 0.25f * r.y;
    o.z = sk.z + 0.25f * r.z;
    o.w = sk.w + 0.25f * r.w;
    if (relu) {
      o.x = fmaxf(o.x, 0.f); o.y = fmaxf(o.y, 0.f);
      o.z = fmaxf(o.z, 0.f); o.w = fmaxf(o.w, 0.f);
    }
    *(float4*)&xout[(size_t)node * HD + j * 4] = o;
    bf4 ob;
    ob.x = f2bf(o.x); ob.y = f2bf(o.y); ob.z = f2bf(o.z); ob.w = f2bf(o.w);
    *(bf4*)&xoutb[(size_t)node * HD + j * 4] = ob;
  }
}

// ---------------- classifier: 16 lanes per pair, float4 loads ----------------
__global__ __launch_bounds__(256) void classifier_kernel(const float* __restrict__ xs, const float* __restrict__ xt,
    const int* __restrict__ ls, const int* __restrict__ lt, float* __restrict__ out, int n) {
  int g = blockIdx.x * 256 + threadIdx.x;
  int pair = g >> 4, j = g & 15;
  if (pair >= n) return;
  int a = ls[pair], b = lt[pair];
  float4 xa = *(const float4*)&xs[(size_t)a * HD + j * 4];
  float4 xb = *(const float4*)&xt[(size_t)b * HD + j * 4];
  float s = xa.x * xb.x + xa.y * xb.y + xa.z * xb.z + xa.w * xb.w;
  s = red16(s);
  if (j == 0) out[pair] = s;
}

// ---------------- launch ----------------
extern "C" void kernel_launch(void* const* d_in, const int* in_sizes, int n_in,
                              void* d_out, int out_size, void* d_ws, size_t ws_size,
                              hipStream_t stream) {
  const float* src_emb = (const float*)d_in[0];
  const float* tgt_emb = (const float*)d_in[1];
  const float* Wq = (const float*)d_in[2];
  const float* bq = (const float*)d_in[3];
  const float* Wk = (const float*)d_in[4];
  const float* bk = (const float*)d_in[5];
  const float* Wv = (const float*)d_in[6];
  const float* bv = (const float*)d_in[7];
  const float* Wsk = (const float*)d_in[8];
  const float* bsk = (const float*)d_in[9];
  const int* nid_s = (const int*)d_in[10];
  const int* nid_t = (const int*)d_in[11];
  const int* e_st = (const int*)d_in[12];
  const int* e_ts = (const int*)d_in[13];
  const int* e_lbl = (const int*)d_in[14];
  float* out = (float*)d_out;

  char* ws = (char*)d_ws;
  size_t off = 0;
  auto alloc = [&](size_t bytes) -> void* {
    void* p = ws + off;
    off += (bytes + 255) & ~(size_t)255;
    return p;
  };
  unsigned short* kv_big   = (unsigned short*)alloc((size_t)NSRC * 256 * 2);  // st k/v fp8 pairs
  unsigned short* q_big    = (unsigned short*)alloc((size_t)NSRC * QK * 2);   // ts q
  unsigned short* kv_small = (unsigned short*)alloc((size_t)NTGT * 256 * 2);  // ts k/v fp8 pairs
  unsigned short* q_small  = (unsigned short*)alloc((size_t)NTGT * QK * 2);   // st q
  float* xsA = (float*)alloc((size_t)NSRC * HD * 4);
  float* xsB = (float*)alloc((size_t)NSRC * HD * 4);
  float* xtA = (float*)alloc((size_t)NTGT * HD * 4);
  float* xtB = (float*)alloc((size_t)NTGT * HD * 4);
  unsigned short* xsAb = (unsigned short*)alloc((size_t)NSRC * HD * 2);
  unsigned short* xsBb = (unsigned short*)alloc((size_t)NSRC * HD * 2);
  unsigned short* xtAb = (unsigned short*)alloc((size_t)NTGT * HD * 2);
  unsigned short* xtBb = (unsigned short*)alloc((size_t)NTGT * HD * 2);
  unsigned short* Wtq = (unsigned short*)alloc((size_t)4 * 16384 * 2);
  unsigned short* Wtk = (unsigned short*)alloc((size_t)4 * 16384 * 2);
  unsigned short* Wtv = (unsigned short*)alloc((size_t)4 * 16384 * 2);
  int* rp_st = (int*)alloc((size_t)(NTGT + 1) * 4);
  int* es_st = (int*)alloc((size_t)NEDGE * 4);
  int* rp_ts = (int*)alloc((size_t)(NSRC + 1) * 4);
  int* es_ts = (int*)alloc((size_t)NEDGE * 4);
  int* cursor = (int*)alloc((size_t)NTOT * 4);
  int* counts = (int*)alloc((size_t)NTOT * 4);
  int* incl_buf = (int*)alloc((size_t)NTOT * 4);
  int* blocksums = (int*)alloc(64 * 4);
  int* boff = (int*)alloc(64 * 4);
  (void)ws_size; (void)in_sizes; (void)n_in; (void)out_size;

  auto cdiv = [](int a, int b) { return (a + b - 1) / b; };
  const int GATHER_BLK = cdiv(NTOT * HD, 256);          // 15000
  const int SETUP_BLK = 48 + GATHER_BLK + cdiv(NTOT, 256);
  const int RT_S = cdiv(NSRC, 64);                      // 782
  const int RT_T = cdiv(NTGT, 64);                      // 157
  const int G1 = cdiv(NSRC / 16, 8);                    // 391
  const int G2 = cdiv(NTGT / 16, 8);                    // 79
  const int NBLK_PROJ = 2 * (G1 + G2);                  // 940
  const int ST_BLK = cdiv(NTGT, 4);                     // 2500
  const int NBLK_AGG = ST_BLK + cdiv(NSRC, 4);          // 15000

  // fused setup: weight transpose + feature gather + counts zero
  setup_kernel<<<SETUP_BLK, 256, 0, stream>>>(Wq, Wk, Wv, Wtq, Wtk, Wtv,
                                              src_emb, nid_s, tgt_emb, nid_t,
                                              xsA, xsAb, xtA, xtAb, counts, GATHER_BLK);

  // CSR build for both edge sets
  hist_all_kernel<<<cdiv(2 * NEDGE, 256), 256, 0, stream>>>(e_st, e_ts, counts);
  scan1_kernel<<<cdiv(NTOT, 1024), 256, 0, stream>>>(counts, incl_buf, blocksums, NTOT);
  scan2_kernel<<<1, 64, 0, stream>>>(blocksums, boff, cdiv(NTOT, 1024));
  scan3_kernel<<<cdiv(NTOT, 256), 256, 0, stream>>>(incl_buf, counts, boff, rp_st, rp_ts, cursor);
  scatter_all_kernel<<<cdiv(2 * NEDGE, 256), 256, 0, stream>>>(e_st, e_ts, cursor, es_st, es_ts);

  const float* xs_cur = xsA; float* xs_nxt = xsB;
  const float* xt_cur = xtA; float* xt_nxt = xtB;
  const unsigned short* xsb_cur = xsAb; unsigned short* xsb_nxt = xsBb;
  const unsigned short* xtb_cur = xtAb; unsigned short* xtb_nxt = xtBb;
  for (int l = 0; l < 2; ++l) {
    int relu = (l == 0) ? 1 : 0;
    int p_st = l * 2 + 0, p_ts = l * 2 + 1;
    proj_all<<<NBLK_PROJ, 256, 0, stream>>>(xsb_cur, xtb_cur, Wtq, Wtk, Wtv, bq, bk, bv,
                                            kv_big, q_big, kv_small, q_small, p_st, p_ts);
    skip_all<<<RT_S + RT_T, 256, 0, stream>>>(xs_cur, xt_cur, Wsk, bsk, xs_nxt, xt_nxt, p_st, p_ts, RT_S);
    agg_all<<<NBLK_AGG, 256, 0, stream>>>(q_small, kv_big, rp_st, es_st, xt_nxt, xtb_nxt,
                                          q_big, kv_small, rp_ts, es_ts, xs_nxt, xsb_nxt,
                                          relu, ST_BLK);
    { const float* t = xs_nxt; xs_nxt = (float*)xs_cur; xs_cur = t; }
    { const float* t = xt_nxt; xt_nxt = (float*)xt_cur; xt_cur = t; }
    { const unsigned short* t = xsb_nxt; xsb_nxt = (unsigned short*)xsb_cur; xsb_cur = t; }
    { const unsigned short* t = xtb_nxt; xtb_nxt = (unsigned short*)xtb_cur; xtb_cur = t; }
  }

  classifier_kernel<<<cdiv(NLBL * 16, 256), 256, 0, stream>>>(xs_cur, xt_cur, e_lbl, e_lbl + NLBL, out, NLBL);
}

// Round 8
// 322.946 us; speedup vs baseline: 1.4070x; 1.0279x over previous
//
#include <hip/hip_runtime.h>

constexpr int NSRC = 50000;
constexpr int NTGT = 10000;
constexpr int NEDGE = 250000;
constexpr int NLBL = 200000;
constexpr int HD = 64;     // hidden dim (per head)
constexpr int NH = 4;      // heads
constexpr int QK = 256;    // HD*NH
constexpr int NTOT = NSRC + NTGT;

typedef __attribute__((ext_vector_type(8))) short bf16x8;
typedef __attribute__((ext_vector_type(4))) float f32x4;
typedef __attribute__((ext_vector_type(2))) float f32x2;

// ---------------- bf16 helpers ----------------
__device__ __forceinline__ unsigned short f2bf(float f) {
  unsigned u = __float_as_uint(f);
  u += 0x7FFFu + ((u >> 16) & 1u);   // round-to-nearest-even
  return (unsigned short)(u >> 16);
}
__device__ __forceinline__ float bf2f(unsigned short b) {
  return __uint_as_float((unsigned)b << 16);
}
struct bf4 { unsigned short x, y, z, w; };
__device__ __forceinline__ float4 bf4_to_f4(bf4 u) {
  return make_float4(bf2f(u.x), bf2f(u.y), bf2f(u.z), bf2f(u.w));
}

// ---------------- DPP 16-lane sum reduction (no LDS pipe, pure VALU) ----------------
template<int CTRL>
__device__ __forceinline__ float dpp_addf(float x) {
  int p = __builtin_amdgcn_update_dpp(0, __float_as_int(x), CTRL, 0xf, 0xf, true);
  return x + __int_as_float(p);
}
__device__ __forceinline__ float red16(float x) {
  x = dpp_addf<0xB1>(x);    // + lane^1 within quad
  x = dpp_addf<0x4E>(x);    // + lane^2 within quad
  x = dpp_addf<0x141>(x);   // + mirrored half-row (combines quads)
  x = dpp_addf<0x140>(x);   // + mirrored row (combines halves)
  return x;                 // all 16 lanes of the row hold the row sum
}

// ---------------- fused setup: weight transpose + feature gather + counts zero ----------------
__global__ __launch_bounds__(256) void setup_kernel(
    const float* __restrict__ Wq, const float* __restrict__ Wk, const float* __restrict__ Wv,
    unsigned short* __restrict__ Wtq, unsigned short* __restrict__ Wtk, unsigned short* __restrict__ Wtv,
    const float* __restrict__ semb, const int* __restrict__ sids,
    const float* __restrict__ temb, const int* __restrict__ tids,
    float* __restrict__ xs, unsigned short* __restrict__ xsb,
    float* __restrict__ xt, unsigned short* __restrict__ xtb,
    int* __restrict__ counts, int nGatherBlk) {
  __shared__ float tile[64][65];
  int b = blockIdx.x;
  int t = threadIdx.x;
  if (b < 48) {
    int mat = b >> 2, ct = b & 3;
    int grp = mat >> 2, p = mat & 3;
    const float* W = (grp == 0) ? Wq : (grp == 1) ? Wk : Wv;
    unsigned short* Wt = (grp == 0) ? Wtq : (grp == 1) ? Wtk : Wtv;
    W += (size_t)p * 16384;
    Wt += (size_t)p * 16384;
    int c = t & 63, r4 = t >> 6;
    for (int rr = 0; rr < 64; rr += 4)
      tile[rr + r4][c] = W[(size_t)(rr + r4) * 256 + ct * 64 + c];
    __syncthreads();
    for (int rr = 0; rr < 64; rr += 4) {
      int nloc = rr + r4;
      Wt[(size_t)(ct * 64 + nloc) * 64 + c] = f2bf(tile[c][nloc]);
    }
  } else if (b < 48 + nGatherBlk) {
    int i = (b - 48) * 256 + t;
    if (i < NSRC * HD) {
      float v = semb[(size_t)sids[i >> 6] * HD + (i & 63)];
      xs[i] = v;
      xsb[i] = f2bf(v);
    } else if (i < NTOT * HD) {
      int j = i - NSRC * HD;
      float v = temb[(size_t)tids[j >> 6] * HD + (j & 63)];
      xt[j] = v;
      xtb[j] = f2bf(v);
    }
  } else {
    int i = (b - 48 - nGatherBlk) * 256 + t;
    if (i < NTOT) counts[i] = 0;
  }
}

// ---------------- CSR build (both edge sets, concatenated counts) ----------------

__global__ __launch_bounds__(256) void hist_all_kernel(const int* __restrict__ e_st, const int* __restrict__ e_ts,
                                                       int* __restrict__ counts) {
  int i = blockIdx.x * 256 + threadIdx.x;
  if (i < NEDGE) atomicAdd(&counts[e_st[NEDGE + i]], 1);
  else if (i < 2 * NEDGE) atomicAdd(&counts[NTGT + e_ts[NEDGE + (i - NEDGE)]], 1);
}

__global__ __launch_bounds__(256) void scan1_kernel(const int* __restrict__ counts, int* __restrict__ incl,
                                                    int* __restrict__ blocksums, int n) {
  __shared__ int wtot[4];
  int t = threadIdx.x;
  int i0 = blockIdx.x * 1024 + t * 4;
  int e0 = (i0 + 0 < n) ? counts[i0 + 0] : 0;
  int e1 = (i0 + 1 < n) ? counts[i0 + 1] : 0;
  int e2 = (i0 + 2 < n) ? counts[i0 + 2] : 0;
  int e3 = (i0 + 3 < n) ? counts[i0 + 3] : 0;
  int s0 = e0, s1 = s0 + e1, s2 = s1 + e2, s3 = s2 + e3;
  int tsum = s3;
  int inc = tsum;
#pragma unroll
  for (int o = 1; o < 64; o <<= 1) {
    int u = __shfl_up(inc, o, 64);
    if ((t & 63) >= o) inc += u;
  }
  int wave = t >> 6;
  if ((t & 63) == 63) wtot[wave] = inc;
  __syncthreads();
  int woff = 0;
#pragma unroll
  for (int w_ = 0; w_ < 4; ++w_) if (w_ < wave) woff += wtot[w_];
  int toff = woff + inc - tsum;
  if (i0 + 0 < n) incl[i0 + 0] = toff + s0;
  if (i0 + 1 < n) incl[i0 + 1] = toff + s1;
  if (i0 + 2 < n) incl[i0 + 2] = toff + s2;
  if (i0 + 3 < n) incl[i0 + 3] = toff + s3;
  if (t == 255) blocksums[blockIdx.x] = woff + inc;
}

__global__ __launch_bounds__(64) void scan2_kernel(const int* __restrict__ blocksums, int* __restrict__ boff, int nb) {
  int t = threadIdx.x;
  int v = (t < nb) ? blocksums[t] : 0;
  int inc = v;
#pragma unroll
  for (int o = 1; o < 64; o <<= 1) {
    int u = __shfl_up(inc, o, 64);
    if (t >= o) inc += u;
  }
  if (t < nb) boff[t] = inc - v;
}

__global__ __launch_bounds__(256) void scan3_kernel(const int* __restrict__ incl, const int* __restrict__ counts,
                                                    const int* __restrict__ boff, int* __restrict__ rp_st,
                                                    int* __restrict__ rp_ts, int* __restrict__ cursor) {
  int i = blockIdx.x * 256 + threadIdx.x;
  if (i < NTOT) {
    int val = incl[i] + boff[i >> 10];
    if (i < NTGT) {
      rp_st[i + 1] = val;
      cursor[i] = val - counts[i];
      if (i == 0) rp_st[0] = 0;
    } else {
      int v2 = val - NEDGE;
      rp_ts[i - NTGT + 1] = v2;
      cursor[i] = v2 - counts[i];
      if (i == NTGT) rp_ts[0] = 0;
    }
  }
}

__global__ __launch_bounds__(256) void scatter_all_kernel(const int* __restrict__ e_st, const int* __restrict__ e_ts,
                                                          int* __restrict__ cursor, int* __restrict__ es_st,
                                                          int* __restrict__ es_ts) {
  int i = blockIdx.x * 256 + threadIdx.x;
  if (i < NEDGE) {
    int d = e_st[NEDGE + i];
    int p = atomicAdd(&cursor[d], 1);
    es_st[p] = e_st[i];
  } else if (i < 2 * NEDGE) {
    int j = i - NEDGE;
    int d = e_ts[NEDGE + j];
    int p = atomicAdd(&cursor[NTGT + d], 1);
    es_ts[p] = e_ts[j];
  }
}

// ---------------- MFMA projection dispatch per layer (kv + q only) ----------------
// R18: kv stored as packed fp8 e4m3 (k byte0, v byte1 per col).
// R21: weights-in-register + T=8 row-tile loop per block (latency fix, proven 55.8->sub-49).
__global__ __launch_bounds__(256) void proj_all(
    const unsigned short* __restrict__ xsb, const unsigned short* __restrict__ xtb,
    const unsigned short* __restrict__ Wtq, const unsigned short* __restrict__ Wtk,
    const unsigned short* __restrict__ Wtv,
    const float* __restrict__ bq, const float* __restrict__ bk, const float* __restrict__ bv,
    unsigned short* __restrict__ kv_big, unsigned short* __restrict__ q_big,
    unsigned short* __restrict__ kv_small, unsigned short* __restrict__ q_small,
    int p_st, int p_ts) {
  constexpr int T = 8;
  constexpr int T1 = NSRC / 16;             // 3125 row tiles (big)
  constexpr int T2 = NTGT / 16;             // 625 row tiles (small)
  constexpr int G1 = (T1 + T - 1) / T;      // 391
  constexpr int G2 = (T2 + T - 1) / T;      // 79
  int b = blockIdx.x;
  int t = threadIdx.x;
  int w = t >> 6, l = t & 63;
  int m = l & 15, qd = l >> 4;
  const unsigned short* xb; const unsigned short* WtA; const unsigned short* WtB = nullptr;
  const float* biasA; const float* biasB = nullptr;
  unsigned short* obuf;
  int tile0, ntiles, mode;
  if (b < G1) {                       // kv_s (params p_st)
    xb = xsb; tile0 = b * T; ntiles = min(T, T1 - tile0); mode = 0;
    WtA = Wtk + (size_t)p_st * 16384; biasA = bk + p_st * 256;
    WtB = Wtv + (size_t)p_st * 16384; biasB = bv + p_st * 256;
    obuf = kv_big;
  } else if (b < G1 + G2) {           // kv_t (params p_ts)
    xb = xtb; tile0 = (b - G1) * T; ntiles = min(T, T2 - tile0); mode = 0;
    WtA = Wtk + (size_t)p_ts * 16384; biasA = bk + p_ts * 256;
    WtB = Wtv + (size_t)p_ts * 16384; biasB = bv + p_ts * 256;
    obuf = kv_small;
  } else if (b < 2 * G1 + G2) {       // q_s (params p_ts)
    xb = xsb; tile0 = (b - G1 - G2) * T; ntiles = min(T, T1 - tile0); mode = 1;
    WtA = Wtq + (size_t)p_ts * 16384; biasA = bq + p_ts * 256;
    obuf = q_big;
  } else {                            // q_t (params p_st)
    xb = xtb; tile0 = (b - 2 * G1 - G2) * T; ntiles = min(T, T2 - tile0); mode = 1;
    WtA = Wtq + (size_t)p_st * 16384; biasA = bq + p_st * 256;
    obuf = q_small;
  }

  if (mode == 0) {
    // resident weight fragments: 16 x bf16x8 = 64 VGPRs + 8 bias floats
    bf16x8 wkl[4], wkh[4], wvl[4], wvh[4];
    float bkc[4], bvc[4];
#pragma unroll
    for (int i = 0; i < 4; ++i) {
      int col = (w * 4 + i) * 16 + m;
      const unsigned short* wk = WtA + (size_t)col * 64 + qd * 8;
      const unsigned short* wv = WtB + (size_t)col * 64 + qd * 8;
      wkl[i] = *(const bf16x8*)wk; wkh[i] = *(const bf16x8*)(wk + 32);
      wvl[i] = *(const bf16x8*)wv; wvh[i] = *(const bf16x8*)(wv + 32);
      bkc[i] = biasA[col]; bvc[i] = biasB[col];
    }
    const unsigned short* xr0 = xb + (size_t)(tile0 * 16 + m) * 64 + qd * 8;
    bf16x8 a_lo = *(const bf16x8*)xr0;
    bf16x8 a_hi = *(const bf16x8*)(xr0 + 32);
    for (int tt = 0; tt < ntiles; ++tt) {
      int ntt = (tt + 1 < ntiles) ? tt + 1 : tt;   // clamped prefetch
      const unsigned short* xn = xb + (size_t)((tile0 + ntt) * 16 + m) * 64 + qd * 8;
      bf16x8 n_lo = *(const bf16x8*)xn;
      bf16x8 n_hi = *(const bf16x8*)(xn + 32);
      int R0 = (tile0 + tt) * 16;
#pragma unroll
      for (int i = 0; i < 4; ++i) {
        f32x4 ak = {0.f, 0.f, 0.f, 0.f}, av = {0.f, 0.f, 0.f, 0.f};
        ak = __builtin_amdgcn_mfma_f32_16x16x32_bf16(a_lo, wkl[i], ak, 0, 0, 0);
        ak = __builtin_amdgcn_mfma_f32_16x16x32_bf16(a_hi, wkh[i], ak, 0, 0, 0);
        av = __builtin_amdgcn_mfma_f32_16x16x32_bf16(a_lo, wvl[i], av, 0, 0, 0);
        av = __builtin_amdgcn_mfma_f32_16x16x32_bf16(a_hi, wvh[i], av, 0, 0, 0);
        int col = (w * 4 + i) * 16 + m;
        unsigned short* obase = obuf + (size_t)(R0 + qd * 4) * 256 + col;
#pragma unroll
        for (int r = 0; r < 4; ++r) {
          unsigned pk = __builtin_amdgcn_cvt_pk_fp8_f32(ak[r] + bkc[i], av[r] + bvc[i], 0, false);
          obase[(size_t)r * 256] = (unsigned short)pk;
        }
      }
      a_lo = n_lo; a_hi = n_hi;
    }
  } else {
    bf16x8 wql[4], wqh[4];
    float bqc[4];
#pragma unroll
    for (int i = 0; i < 4; ++i) {
      int col = (w * 4 + i) * 16 + m;
      const unsigned short* wq = WtA + (size_t)col * 64 + qd * 8;
      wql[i] = *(const bf16x8*)wq; wqh[i] = *(const bf16x8*)(wq + 32);
      bqc[i] = biasA[col];
    }
    const unsigned short* xr0 = xb + (size_t)(tile0 * 16 + m) * 64 + qd * 8;
    bf16x8 a_lo = *(const bf16x8*)xr0;
    bf16x8 a_hi = *(const bf16x8*)(xr0 + 32);
    for (int tt = 0; tt < ntiles; ++tt) {
      int ntt = (tt + 1 < ntiles) ? tt + 1 : tt;
      const unsigned short* xn = xb + (size_t)((tile0 + ntt) * 16 + m) * 64 + qd * 8;
      bf16x8 n_lo = *(const bf16x8*)xn;
      bf16x8 n_hi = *(const bf16x8*)(xn + 32);
      int R0 = (tile0 + tt) * 16;
#pragma unroll
      for (int i = 0; i < 4; ++i) {
        f32x4 acc = {0.f, 0.f, 0.f, 0.f};
        acc = __builtin_amdgcn_mfma_f32_16x16x32_bf16(a_lo, wql[i], acc, 0, 0, 0);
        acc = __builtin_amdgcn_mfma_f32_16x16x32_bf16(a_hi, wqh[i], acc, 0, 0, 0);
        int col = (w * 4 + i) * 16 + m;
        unsigned short* obase = obuf + (size_t)(R0 + qd * 4) * 256 + col;
#pragma unroll
        for (int r = 0; r < 4; ++r)
          obase[(size_t)r * 256] = f2bf(acc[r] + bqc[i]);
      }
      a_lo = n_lo; a_hi = n_hi;
    }
  }
}

// ---------------- fused fp32 skip GEMM for both directions (LDS-tiled, R12-proven) ----------------
__global__ __launch_bounds__(256) void skip_all(const float* __restrict__ xs, const float* __restrict__ xt,
    const float* __restrict__ Wsk, const float* __restrict__ bsk,
    float* __restrict__ xs_nxt, float* __restrict__ xt_nxt, int p_st, int p_ts, int rtS) {
  __shared__ float Xt[64][68];
  __shared__ float Wl[64][68];
  __shared__ float bias[64];
  int t = threadIdx.x;
  const float* x; const float* W; const float* bb; float* o; int N, rbase;
  if ((int)blockIdx.x < rtS) {
    x = xs; N = NSRC; rbase = blockIdx.x * 64;
    W = Wsk + (size_t)p_ts * 4096; bb = bsk + p_ts * 64; o = xs_nxt;
  } else {
    x = xt; N = NTGT; rbase = (blockIdx.x - rtS) * 64;
    W = Wsk + (size_t)p_st * 4096; bb = bsk + p_st * 64; o = xt_nxt;
  }
#pragma unroll
  for (int i = 0; i < 4; ++i) {
    int slot = i * 256 + t;
    int row = slot >> 4;
    int k4 = slot & 15;
    float4 xv = make_float4(0.f, 0.f, 0.f, 0.f);
    if (rbase + row < N) xv = *(const float4*)&x[(size_t)(rbase + row) * 64 + k4 * 4];
    Xt[k4 * 4 + 0][row] = xv.x;
    Xt[k4 * 4 + 1][row] = xv.y;
    Xt[k4 * 4 + 2][row] = xv.z;
    Xt[k4 * 4 + 3][row] = xv.w;
  }
#pragma unroll
  for (int i = 0; i < 4; ++i) {
    int slot = i * 256 + t;
    int kk = slot >> 4;
    int c4 = slot & 15;
    float4 wv = *(const float4*)&W[(size_t)kk * 64 + c4 * 4];
    *(float4*)&Wl[kk][c4 * 4] = wv;
  }
  if (t < 64) bias[t] = bb[t];
  __syncthreads();

  int c0 = (t & 15) * 4;
  int r0 = (t >> 4) * 4;
  float acc[4][4];
#pragma unroll
  for (int i = 0; i < 4; ++i)
#pragma unroll
    for (int j = 0; j < 4; ++j) acc[i][j] = 0.f;
#pragma unroll 8
  for (int kk = 0; kk < 64; ++kk) {
    float4 xv = *(const float4*)&Xt[kk][r0];
    float4 wv = *(const float4*)&Wl[kk][c0];
    float xr[4] = {xv.x, xv.y, xv.z, xv.w};
    float wc[4] = {wv.x, wv.y, wv.z, wv.w};
#pragma unroll
    for (int i = 0; i < 4; ++i)
#pragma unroll
      for (int j = 0; j < 4; ++j) acc[i][j] = fmaf(xr[i], wc[j], acc[i][j]);
  }
#pragma unroll
  for (int i = 0; i < 4; ++i) {
    int row = rbase + r0 + i;
    if (row < N) {
      float4 ov;
      ov.x = acc[i][0] + bias[c0 + 0];
      ov.y = acc[i][1] + bias[c0 + 1];
      ov.z = acc[i][2] + bias[c0 + 2];
      ov.w = acc[i][3] + bias[c0 + 3];
      *(float4*)&o[(size_t)row * 64 + c0] = ov;
    }
  }
}

// ---------------- fused aggregation for BOTH directions: one WAVE per node ----------------
// R18: fp8 kv rows (512B, uint2/lane gather). R16 structure (unroll-4, DPP reduce, exp2).
// R22: SGPR-scalarized addressing — node id and edge indices are wave-uniform, so
// readfirstlane them into SGPRs: gathers become s[base] + v_offset(l*8), killing the
// per-lane 64-bit v_mad address chains (~16 VALU/batch). R7 counters: VALU 62.5%,
// HBM 36% -> VALU-issue had become the top term.
__global__ __launch_bounds__(256) void agg_all(
    const unsigned short* __restrict__ q_small, const unsigned short* __restrict__ kv_big,
    const int* __restrict__ rp_st, const int* __restrict__ es_st,
    float* __restrict__ xt_nxt, unsigned short* __restrict__ xtb_nxt,
    const unsigned short* __restrict__ q_big, const unsigned short* __restrict__ kv_small,
    const int* __restrict__ rp_ts, const int* __restrict__ es_ts,
    float* __restrict__ xs_nxt, unsigned short* __restrict__ xsb_nxt,
    int relu, int stBlocks) {
  const unsigned short* q; const unsigned short* kvi; const int* rowptr; const int* eisrc;
  float* xout; unsigned short* xoutb; int node;
  int l = threadIdx.x & 63;
  int wv = __builtin_amdgcn_readfirstlane(threadIdx.x >> 6);   // wave-uniform -> SGPR
  if ((int)blockIdx.x < stBlocks) {
    node = blockIdx.x * 4 + wv;
    if (node >= NTGT) return;
    q = q_small; kvi = kv_big; rowptr = rp_st; eisrc = es_st; xout = xt_nxt; xoutb = xtb_nxt;
  } else {
    node = (blockIdx.x - stBlocks) * 4 + wv;
    if (node >= NSRC) return;
    q = q_big; kvi = kv_small; rowptr = rp_ts; eisrc = es_ts; xout = xs_nxt; xoutb = xsb_nxt;
  }
  int j = l & 15;
  float4 qf = bf4_to_f4(*(const bf4*)&q[(size_t)node * QK + l * 4]);
  // fold 1/sqrt(H)=0.125 and log2(e) so the softmax uses raw v_exp (base-2)
  const float QS = 0.125f * 1.44269504088896340736f;
  qf.x *= QS; qf.y *= QS; qf.z *= QS; qf.w *= QS;
  int beg = __builtin_amdgcn_readfirstlane(rowptr[node]);
  int end = __builtin_amdgcn_readfirstlane(rowptr[node + 1]);

  float lsum = 0.f;
  float4 acc = make_float4(0.f, 0.f, 0.f, 0.f);
  int p = beg;
  for (; p + 4 <= end; p += 4) {
    int s0 = __builtin_amdgcn_readfirstlane(eisrc[p]);
    int s1 = __builtin_amdgcn_readfirstlane(eisrc[p + 1]);
    int s2 = __builtin_amdgcn_readfirstlane(eisrc[p + 2]);
    int s3 = __builtin_amdgcn_readfirstlane(eisrc[p + 3]);
    uint2 a0 = ((const uint2*)(kvi + (size_t)s0 * 256))[l];
    uint2 a1 = ((const uint2*)(kvi + (size_t)s1 * 256))[l];
    uint2 a2 = ((const uint2*)(kvi + (size_t)s2 * 256))[l];
    uint2 a3 = ((const uint2*)(kvi + (size_t)s3 * 256))[l];
    f32x2 p00 = __builtin_amdgcn_cvt_pk_f32_fp8(a0.x, false);
    f32x2 p01 = __builtin_amdgcn_cvt_pk_f32_fp8(a0.x, true);
    f32x2 p02 = __builtin_amdgcn_cvt_pk_f32_fp8(a0.y, false);
    f32x2 p03 = __builtin_amdgcn_cvt_pk_f32_fp8(a0.y, true);
    f32x2 p10 = __builtin_amdgcn_cvt_pk_f32_fp8(a1.x, false);
    f32x2 p11 = __builtin_amdgcn_cvt_pk_f32_fp8(a1.x, true);
    f32x2 p12 = __builtin_amdgcn_cvt_pk_f32_fp8(a1.y, false);
    f32x2 p13 = __builtin_amdgcn_cvt_pk_f32_fp8(a1.y, true);
    f32x2 p20 = __builtin_amdgcn_cvt_pk_f32_fp8(a2.x, false);
    f32x2 p21 = __builtin_amdgcn_cvt_pk_f32_fp8(a2.x, true);
    f32x2 p22 = __builtin_amdgcn_cvt_pk_f32_fp8(a2.y, false);
    f32x2 p23 = __builtin_amdgcn_cvt_pk_f32_fp8(a2.y, true);
    f32x2 p30 = __builtin_amdgcn_cvt_pk_f32_fp8(a3.x, false);
    f32x2 p31 = __builtin_amdgcn_cvt_pk_f32_fp8(a3.x, true);
    f32x2 p32 = __builtin_amdgcn_cvt_pk_f32_fp8(a3.y, false);
    f32x2 p33 = __builtin_amdgcn_cvt_pk_f32_fp8(a3.y, true);
    float t0 = qf.x * p00.x + qf.y * p01.x + qf.z * p02.x + qf.w * p03.x;
    float t1 = qf.x * p10.x + qf.y * p11.x + qf.z * p12.x + qf.w * p13.x;
    float t2 = qf.x * p20.x + qf.y * p21.x + qf.z * p22.x + qf.w * p23.x;
    float t3 = qf.x * p30.x + qf.y * p31.x + qf.z * p32.x + qf.w * p33.x;
    t0 = red16(t0); t1 = red16(t1); t2 = red16(t2); t3 = red16(t3);
    float w0 = __builtin_amdgcn_exp2f(t0), w1 = __builtin_amdgcn_exp2f(t1);
    float w2 = __builtin_amdgcn_exp2f(t2), w3 = __builtin_amdgcn_exp2f(t3);
    lsum += (w0 + w1) + (w2 + w3);
    acc.x = fmaf(w0, p00.y, fmaf(w1, p10.y, fmaf(w2, p20.y, fmaf(w3, p30.y, acc.x))));
    acc.y = fmaf(w0, p01.y, fmaf(w1, p11.y, fmaf(w2, p21.y, fmaf(w3, p31.y, acc.y))));
    acc.z = fmaf(w0, p02.y, fmaf(w1, p12.y, fmaf(w2, p22.y, fmaf(w3, p32.y, acc.z))));
    acc.w = fmaf(w0, p03.y, fmaf(w1, p13.y, fmaf(w2, p23.y, fmaf(w3, p33.y, acc.w))));
  }
  for (; p < end; ++p) {
    int s0 = __builtin_amdgcn_readfirstlane(eisrc[p]);
    uint2 a0 = ((const uint2*)(kvi + (size_t)s0 * 256))[l];
    f32x2 p00 = __builtin_amdgcn_cvt_pk_f32_fp8(a0.x, false);
    f32x2 p01 = __builtin_amdgcn_cvt_pk_f32_fp8(a0.x, true);
    f32x2 p02 = __builtin_amdgcn_cvt_pk_f32_fp8(a0.y, false);
    f32x2 p03 = __builtin_amdgcn_cvt_pk_f32_fp8(a0.y, true);
    float s = qf.x * p00.x + qf.y * p01.x + qf.z * p02.x + qf.w * p03.x;
    s = red16(s);
    float w = __builtin_amdgcn_exp2f(s);
    lsum += w;
    acc.x = fmaf(w, p00.y, acc.x);
    acc.y = fmaf(w, p01.y, acc.y);
    acc.z = fmaf(w, p02.y, acc.z);
    acc.w = fmaf(w, p03.y, acc.w);
  }

  float inv = (lsum > 0.f) ? 1.f / lsum : 0.f;
  float4 r;
  r.x = acc.x * inv; r.y = acc.y * inv; r.z = acc.z * inv; r.w = acc.w * inv;
  r.x += __shfl_xor(r.x, 16, 64); r.x += __shfl_xor(r.x, 32, 64);
  r.y += __shfl_xor(r.y, 16, 64); r.y += __shfl_xor(r.y, 32, 64);
  r.z += __shfl_xor(r.z, 16, 64); r.z += __shfl_xor(r.z, 32, 64);
  r.w += __shfl_xor(r.w, 16, 64); r.w += __shfl_xor(r.w, 32, 64);
  if (l < 16) {
    float4 sk = *(const float4*)&xout[(size_t)node * HD + j * 4];
    float4 o;
    o.x = sk.x + 0.25f * r.x;
    o.y = sk.y + 0.25f * r.y;
    o.z = sk.z + 0.25f * r.z;
    o.w = sk.w + 0.25f * r.w;
    if (relu) {
      o.x = fmaxf(o.x, 0.f); o.y = fmaxf(o.y, 0.f);
      o.z = fmaxf(o.z, 0.f); o.w = fmaxf(o.w, 0.f);
    }
    *(float4*)&xout[(size_t)node * HD + j * 4] = o;
    bf4 ob;
    ob.x = f2bf(o.x); ob.y = f2bf(o.y); ob.z = f2bf(o.z); ob.w = f2bf(o.w);
    *(bf4*)&xoutb[(size_t)node * HD + j * 4] = ob;
  }
}

// ---------------- classifier: 16 lanes per pair, float4 loads ----------------
__global__ __launch_bounds__(256) void classifier_kernel(const float* __restrict__ xs, const float* __restrict__ xt,
    const int* __restrict__ ls, const int* __restrict__ lt, float* __restrict__ out, int n) {
  int g = blockIdx.x * 256 + threadIdx.x;
  int pair = g >> 4, j = g & 15;
  if (pair >= n) return;
  int a = ls[pair], b = lt[pair];
  float4 xa = *(const float4*)&xs[(size_t)a * HD + j * 4];
  float4 xb = *(const float4*)&xt[(size_t)b * HD + j * 4];
  float s = xa.x * xb.x + xa.y * xb.y + xa.z * xb.z + xa.w * xb.w;
  s = red16(s);
  if (j == 0) out[pair] = s;
}

// ---------------- launch ----------------
extern "C" void kernel_launch(void* const* d_in, const int* in_sizes, int n_in,
                              void* d_out, int out_size, void* d_ws, size_t ws_size,
                              hipStream_t stream) {
  const float* src_emb = (const float*)d_in[0];
  const float* tgt_emb = (const float*)d_in[1];
  const float* Wq = (const float*)d_in[2];
  const float* bq = (const float*)d_in[3];
  const float* Wk = (const float*)d_in[4];
  const float* bk = (const float*)d_in[5];
  const float* Wv = (const float*)d_in[6];
  const float* bv = (const float*)d_in[7];
  const float* Wsk = (const float*)d_in[8];
  const float* bsk = (const float*)d_in[9];
  const int* nid_s = (const int*)d_in[10];
  const int* nid_t = (const int*)d_in[11];
  const int* e_st = (const int*)d_in[12];
  const int* e_ts = (const int*)d_in[13];
  const int* e_lbl = (const int*)d_in[14];
  float* out = (float*)d_out;

  char* ws = (char*)d_ws;
  size_t off = 0;
  auto alloc = [&](size_t bytes) -> void* {
    void* p = ws + off;
    off += (bytes + 255) & ~(size_t)255;
    return p;
  };
  unsigned short* kv_big   = (unsigned short*)alloc((size_t)NSRC * 256 * 2);  // st k/v fp8 pairs
  unsigned short* q_big    = (unsigned short*)alloc((size_t)NSRC * QK * 2);   // ts q
  unsigned short* kv_small = (unsigned short*)alloc((size_t)NTGT * 256 * 2);  // ts k/v fp8 pairs
  unsigned short* q_small  = (unsigned short*)alloc((size_t)NTGT * QK * 2);   // st q
  float* xsA = (float*)alloc((size_t)NSRC * HD * 4);
  float* xsB = (float*)alloc((size_t)NSRC * HD * 4);
  float* xtA = (float*)alloc((size_t)NTGT * HD * 4);
  float* xtB = (float*)alloc((size_t)NTGT * HD * 4);
  unsigned short* xsAb = (unsigned short*)alloc((size_t)NSRC * HD * 2);
  unsigned short* xsBb = (unsigned short*)alloc((size_t)NSRC * HD * 2);
  unsigned short* xtAb = (unsigned short*)alloc((size_t)NTGT * HD * 2);
  unsigned short* xtBb = (unsigned short*)alloc((size_t)NTGT * HD * 2);
  unsigned short* Wtq = (unsigned short*)alloc((size_t)4 * 16384 * 2);
  unsigned short* Wtk = (unsigned short*)alloc((size_t)4 * 16384 * 2);
  unsigned short* Wtv = (unsigned short*)alloc((size_t)4 * 16384 * 2);
  int* rp_st = (int*)alloc((size_t)(NTGT + 1) * 4);
  int* es_st = (int*)alloc((size_t)NEDGE * 4);
  int* rp_ts = (int*)alloc((size_t)(NSRC + 1) * 4);
  int* es_ts = (int*)alloc((size_t)NEDGE * 4);
  int* cursor = (int*)alloc((size_t)NTOT * 4);
  int* counts = (int*)alloc((size_t)NTOT * 4);
  int* incl_buf = (int*)alloc((size_t)NTOT * 4);
  int* blocksums = (int*)alloc(64 * 4);
  int* boff = (int*)alloc(64 * 4);
  (void)ws_size; (void)in_sizes; (void)n_in; (void)out_size;

  auto cdiv = [](int a, int b) { return (a + b - 1) / b; };
  const int GATHER_BLK = cdiv(NTOT * HD, 256);          // 15000
  const int SETUP_BLK = 48 + GATHER_BLK + cdiv(NTOT, 256);
  const int RT_S = cdiv(NSRC, 64);                      // 782
  const int RT_T = cdiv(NTGT, 64);                      // 157
  const int G1 = cdiv(NSRC / 16, 8);                    // 391
  const int G2 = cdiv(NTGT / 16, 8);                    // 79
  const int NBLK_PROJ = 2 * (G1 + G2);                  // 940
  const int ST_BLK = cdiv(NTGT, 4);                     // 2500
  const int NBLK_AGG = ST_BLK + cdiv(NSRC, 4);          // 15000

  // fused setup: weight transpose + feature gather + counts zero
  setup_kernel<<<SETUP_BLK, 256, 0, stream>>>(Wq, Wk, Wv, Wtq, Wtk, Wtv,
                                              src_emb, nid_s, tgt_emb, nid_t,
                                              xsA, xsAb, xtA, xtAb, counts, GATHER_BLK);

  // CSR build for both edge sets
  hist_all_kernel<<<cdiv(2 * NEDGE, 256), 256, 0, stream>>>(e_st, e_ts, counts);
  scan1_kernel<<<cdiv(NTOT, 1024), 256, 0, stream>>>(counts, incl_buf, blocksums, NTOT);
  scan2_kernel<<<1, 64, 0, stream>>>(blocksums, boff, cdiv(NTOT, 1024));
  scan3_kernel<<<cdiv(NTOT, 256), 256, 0, stream>>>(incl_buf, counts, boff, rp_st, rp_ts, cursor);
  scatter_all_kernel<<<cdiv(2 * NEDGE, 256), 256, 0, stream>>>(e_st, e_ts, cursor, es_st, es_ts);

  const float* xs_cur = xsA; float* xs_nxt = xsB;
  const float* xt_cur = xtA; float* xt_nxt = xtB;
  const unsigned short* xsb_cur = xsAb; unsigned short* xsb_nxt = xsBb;
  const unsigned short* xtb_cur = xtAb; unsigned short* xtb_nxt = xtBb;
  for (int l = 0; l < 2; ++l) {
    int relu = (l == 0) ? 1 : 0;
    int p_st = l * 2 + 0, p_ts = l * 2 + 1;
    proj_all<<<NBLK_PROJ, 256, 0, stream>>>(xsb_cur, xtb_cur, Wtq, Wtk, Wtv, bq, bk, bv,
                                            kv_big, q_big, kv_small, q_small, p_st, p_ts);
    skip_all<<<RT_S + RT_T, 256, 0, stream>>>(xs_cur, xt_cur, Wsk, bsk, xs_nxt, xt_nxt, p_st, p_ts, RT_S);
    agg_all<<<NBLK_AGG, 256, 0, stream>>>(q_small, kv_big, rp_st, es_st, xt_nxt, xtb_nxt,
                                          q_big, kv_small, rp_ts, es_ts, xs_nxt, xsb_nxt,
                                          relu, ST_BLK);
    { const float* t = xs_nxt; xs_nxt = (float*)xs_cur; xs_cur = t; }
    { const float* t = xt_nxt; xt_nxt = (float*)xt_cur; xt_cur = t; }
    { const unsigned short* t = xsb_nxt; xsb_nxt = (unsigned short*)xsb_cur; xsb_cur = t; }
    { const unsigned short* t = xtb_nxt; xtb_nxt = (unsigned short*)xtb_cur; xtb_cur = t; }
  }

  classifier_kernel<<<cdiv(NLBL * 16, 256), 256, 0, stream>>>(xs_cur, xt_cur, e_lbl, e_lbl + NLBL, out, NLBL);
}

// Round 9
// 322.854 us; speedup vs baseline: 1.4074x; 1.0003x over previous
//
#include <hip/hip_runtime.h>

constexpr int NSRC = 50000;
constexpr int NTGT = 10000;
constexpr int NEDGE = 250000;
constexpr int NLBL = 200000;
constexpr int HD = 64;     // hidden dim (per head)
constexpr int NH = 4;      // heads
constexpr int QK = 256;    // HD*NH
constexpr int NTOT = NSRC + NTGT;

typedef __attribute__((ext_vector_type(8))) short bf16x8;
typedef __attribute__((ext_vector_type(4))) float f32x4;
typedef __attribute__((ext_vector_type(2))) float f32x2;

// ---------------- bf16 helpers ----------------
__device__ __forceinline__ unsigned short f2bf(float f) {
  unsigned u = __float_as_uint(f);
  u += 0x7FFFu + ((u >> 16) & 1u);   // round-to-nearest-even
  return (unsigned short)(u >> 16);
}
__device__ __forceinline__ float bf2f(unsigned short b) {
  return __uint_as_float((unsigned)b << 16);
}
struct bf4 { unsigned short x, y, z, w; };
__device__ __forceinline__ float4 bf4_to_f4(bf4 u) {
  return make_float4(bf2f(u.x), bf2f(u.y), bf2f(u.z), bf2f(u.w));
}

// ---------------- DPP 16-lane sum reduction (no LDS pipe, pure VALU) ----------------
template<int CTRL>
__device__ __forceinline__ float dpp_addf(float x) {
  int p = __builtin_amdgcn_update_dpp(0, __float_as_int(x), CTRL, 0xf, 0xf, true);
  return x + __int_as_float(p);
}
__device__ __forceinline__ float red16(float x) {
  x = dpp_addf<0xB1>(x);    // + lane^1 within quad
  x = dpp_addf<0x4E>(x);    // + lane^2 within quad
  x = dpp_addf<0x141>(x);   // + mirrored half-row (combines quads)
  x = dpp_addf<0x140>(x);   // + mirrored row (combines halves)
  return x;                 // all 16 lanes of the row hold the row sum
}

// 4-term dot as fma chain: 4 VALU ops instead of 7 (R23 trim)
__device__ __forceinline__ float dot4f(float4 q, float a, float b, float c, float d) {
  return fmaf(q.w, d, fmaf(q.z, c, fmaf(q.y, b, q.x * a)));
}

// ---------------- fused setup: weight transpose + feature gather + counts zero ----------------
__global__ __launch_bounds__(256) void setup_kernel(
    const float* __restrict__ Wq, const float* __restrict__ Wk, const float* __restrict__ Wv,
    unsigned short* __restrict__ Wtq, unsigned short* __restrict__ Wtk, unsigned short* __restrict__ Wtv,
    const float* __restrict__ semb, const int* __restrict__ sids,
    const float* __restrict__ temb, const int* __restrict__ tids,
    float* __restrict__ xs, unsigned short* __restrict__ xsb,
    float* __restrict__ xt, unsigned short* __restrict__ xtb,
    int* __restrict__ counts, int nGatherBlk) {
  __shared__ float tile[64][65];
  int b = blockIdx.x;
  int t = threadIdx.x;
  if (b < 48) {
    int mat = b >> 2, ct = b & 3;
    int grp = mat >> 2, p = mat & 3;
    const float* W = (grp == 0) ? Wq : (grp == 1) ? Wk : Wv;
    unsigned short* Wt = (grp == 0) ? Wtq : (grp == 1) ? Wtk : Wtv;
    W += (size_t)p * 16384;
    Wt += (size_t)p * 16384;
    int c = t & 63, r4 = t >> 6;
    for (int rr = 0; rr < 64; rr += 4)
      tile[rr + r4][c] = W[(size_t)(rr + r4) * 256 + ct * 64 + c];
    __syncthreads();
    for (int rr = 0; rr < 64; rr += 4) {
      int nloc = rr + r4;
      Wt[(size_t)(ct * 64 + nloc) * 64 + c] = f2bf(tile[c][nloc]);
    }
  } else if (b < 48 + nGatherBlk) {
    int i = (b - 48) * 256 + t;
    if (i < NSRC * HD) {
      float v = semb[(size_t)sids[i >> 6] * HD + (i & 63)];
      xs[i] = v;
      xsb[i] = f2bf(v);
    } else if (i < NTOT * HD) {
      int j = i - NSRC * HD;
      float v = temb[(size_t)tids[j >> 6] * HD + (j & 63)];
      xt[j] = v;
      xtb[j] = f2bf(v);
    }
  } else {
    int i = (b - 48 - nGatherBlk) * 256 + t;
    if (i < NTOT) counts[i] = 0;
  }
}

// ---------------- CSR build (both edge sets, concatenated counts) ----------------

__global__ __launch_bounds__(256) void hist_all_kernel(const int* __restrict__ e_st, const int* __restrict__ e_ts,
                                                       int* __restrict__ counts) {
  int i = blockIdx.x * 256 + threadIdx.x;
  if (i < NEDGE) atomicAdd(&counts[e_st[NEDGE + i]], 1);
  else if (i < 2 * NEDGE) atomicAdd(&counts[NTGT + e_ts[NEDGE + (i - NEDGE)]], 1);
}

__global__ __launch_bounds__(256) void scan1_kernel(const int* __restrict__ counts, int* __restrict__ incl,
                                                    int* __restrict__ blocksums, int n) {
  __shared__ int wtot[4];
  int t = threadIdx.x;
  int i0 = blockIdx.x * 1024 + t * 4;
  int e0 = (i0 + 0 < n) ? counts[i0 + 0] : 0;
  int e1 = (i0 + 1 < n) ? counts[i0 + 1] : 0;
  int e2 = (i0 + 2 < n) ? counts[i0 + 2] : 0;
  int e3 = (i0 + 3 < n) ? counts[i0 + 3] : 0;
  int s0 = e0, s1 = s0 + e1, s2 = s1 + e2, s3 = s2 + e3;
  int tsum = s3;
  int inc = tsum;
#pragma unroll
  for (int o = 1; o < 64; o <<= 1) {
    int u = __shfl_up(inc, o, 64);
    if ((t & 63) >= o) inc += u;
  }
  int wave = t >> 6;
  if ((t & 63) == 63) wtot[wave] = inc;
  __syncthreads();
  int woff = 0;
#pragma unroll
  for (int w_ = 0; w_ < 4; ++w_) if (w_ < wave) woff += wtot[w_];
  int toff = woff + inc - tsum;
  if (i0 + 0 < n) incl[i0 + 0] = toff + s0;
  if (i0 + 1 < n) incl[i0 + 1] = toff + s1;
  if (i0 + 2 < n) incl[i0 + 2] = toff + s2;
  if (i0 + 3 < n) incl[i0 + 3] = toff + s3;
  if (t == 255) blocksums[blockIdx.x] = woff + inc;
}

__global__ __launch_bounds__(64) void scan2_kernel(const int* __restrict__ blocksums, int* __restrict__ boff, int nb) {
  int t = threadIdx.x;
  int v = (t < nb) ? blocksums[t] : 0;
  int inc = v;
#pragma unroll
  for (int o = 1; o < 64; o <<= 1) {
    int u = __shfl_up(inc, o, 64);
    if (t >= o) inc += u;
  }
  if (t < nb) boff[t] = inc - v;
}

__global__ __launch_bounds__(256) void scan3_kernel(const int* __restrict__ incl, const int* __restrict__ counts,
                                                    const int* __restrict__ boff, int* __restrict__ rp_st,
                                                    int* __restrict__ rp_ts, int* __restrict__ cursor) {
  int i = blockIdx.x * 256 + threadIdx.x;
  if (i < NTOT) {
    int val = incl[i] + boff[i >> 10];
    if (i < NTGT) {
      rp_st[i + 1] = val;
      cursor[i] = val - counts[i];
      if (i == 0) rp_st[0] = 0;
    } else {
      int v2 = val - NEDGE;
      rp_ts[i - NTGT + 1] = v2;
      cursor[i] = v2 - counts[i];
      if (i == NTGT) rp_ts[0] = 0;
    }
  }
}

__global__ __launch_bounds__(256) void scatter_all_kernel(const int* __restrict__ e_st, const int* __restrict__ e_ts,
                                                          int* __restrict__ cursor, int* __restrict__ es_st,
                                                          int* __restrict__ es_ts) {
  int i = blockIdx.x * 256 + threadIdx.x;
  if (i < NEDGE) {
    int d = e_st[NEDGE + i];
    int p = atomicAdd(&cursor[d], 1);
    es_st[p] = e_st[i];
  } else if (i < 2 * NEDGE) {
    int j = i - NEDGE;
    int d = e_ts[NEDGE + j];
    int p = atomicAdd(&cursor[NTGT + d], 1);
    es_ts[p] = e_ts[j];
  }
}

// ---------------- MFMA projection dispatch per layer (kv + q only) ----------------
// R18: kv stored as packed fp8 e4m3 (k byte0, v byte1 per col).
// R21: weights-in-register + T=8 row-tile loop per block (latency fix, proven 55.8->sub-49).
__global__ __launch_bounds__(256) void proj_all(
    const unsigned short* __restrict__ xsb, const unsigned short* __restrict__ xtb,
    const unsigned short* __restrict__ Wtq, const unsigned short* __restrict__ Wtk,
    const unsigned short* __restrict__ Wtv,
    const float* __restrict__ bq, const float* __restrict__ bk, const float* __restrict__ bv,
    unsigned short* __restrict__ kv_big, unsigned short* __restrict__ q_big,
    unsigned short* __restrict__ kv_small, unsigned short* __restrict__ q_small,
    int p_st, int p_ts) {
  constexpr int T = 8;
  constexpr int T1 = NSRC / 16;             // 3125 row tiles (big)
  constexpr int T2 = NTGT / 16;             // 625 row tiles (small)
  constexpr int G1 = (T1 + T - 1) / T;      // 391
  constexpr int G2 = (T2 + T - 1) / T;      // 79
  int b = blockIdx.x;
  int t = threadIdx.x;
  int w = t >> 6, l = t & 63;
  int m = l & 15, qd = l >> 4;
  const unsigned short* xb; const unsigned short* WtA; const unsigned short* WtB = nullptr;
  const float* biasA; const float* biasB = nullptr;
  unsigned short* obuf;
  int tile0, ntiles, mode;
  if (b < G1) {                       // kv_s (params p_st)
    xb = xsb; tile0 = b * T; ntiles = min(T, T1 - tile0); mode = 0;
    WtA = Wtk + (size_t)p_st * 16384; biasA = bk + p_st * 256;
    WtB = Wtv + (size_t)p_st * 16384; biasB = bv + p_st * 256;
    obuf = kv_big;
  } else if (b < G1 + G2) {           // kv_t (params p_ts)
    xb = xtb; tile0 = (b - G1) * T; ntiles = min(T, T2 - tile0); mode = 0;
    WtA = Wtk + (size_t)p_ts * 16384; biasA = bk + p_ts * 256;
    WtB = Wtv + (size_t)p_ts * 16384; biasB = bv + p_ts * 256;
    obuf = kv_small;
  } else if (b < 2 * G1 + G2) {       // q_s (params p_ts)
    xb = xsb; tile0 = (b - G1 - G2) * T; ntiles = min(T, T1 - tile0); mode = 1;
    WtA = Wtq + (size_t)p_ts * 16384; biasA = bq + p_ts * 256;
    obuf = q_big;
  } else {                            // q_t (params p_st)
    xb = xtb; tile0 = (b - 2 * G1 - G2) * T; ntiles = min(T, T2 - tile0); mode = 1;
    WtA = Wtq + (size_t)p_st * 16384; biasA = bq + p_st * 256;
    obuf = q_small;
  }

  if (mode == 0) {
    // resident weight fragments: 16 x bf16x8 = 64 VGPRs + 8 bias floats
    bf16x8 wkl[4], wkh[4], wvl[4], wvh[4];
    float bkc[4], bvc[4];
#pragma unroll
    for (int i = 0; i < 4; ++i) {
      int col = (w * 4 + i) * 16 + m;
      const unsigned short* wk = WtA + (size_t)col * 64 + qd * 8;
      const unsigned short* wv = WtB + (size_t)col * 64 + qd * 8;
      wkl[i] = *(const bf16x8*)wk; wkh[i] = *(const bf16x8*)(wk + 32);
      wvl[i] = *(const bf16x8*)wv; wvh[i] = *(const bf16x8*)(wv + 32);
      bkc[i] = biasA[col]; bvc[i] = biasB[col];
    }
    const unsigned short* xr0 = xb + (size_t)(tile0 * 16 + m) * 64 + qd * 8;
    bf16x8 a_lo = *(const bf16x8*)xr0;
    bf16x8 a_hi = *(const bf16x8*)(xr0 + 32);
    for (int tt = 0; tt < ntiles; ++tt) {
      int ntt = (tt + 1 < ntiles) ? tt + 1 : tt;   // clamped prefetch
      const unsigned short* xn = xb + (size_t)((tile0 + ntt) * 16 + m) * 64 + qd * 8;
      bf16x8 n_lo = *(const bf16x8*)xn;
      bf16x8 n_hi = *(const bf16x8*)(xn + 32);
      int R0 = (tile0 + tt) * 16;
#pragma unroll
      for (int i = 0; i < 4; ++i) {
        f32x4 ak = {0.f, 0.f, 0.f, 0.f}, av = {0.f, 0.f, 0.f, 0.f};
        ak = __builtin_amdgcn_mfma_f32_16x16x32_bf16(a_lo, wkl[i], ak, 0, 0, 0);
        ak = __builtin_amdgcn_mfma_f32_16x16x32_bf16(a_hi, wkh[i], ak, 0, 0, 0);
        av = __builtin_amdgcn_mfma_f32_16x16x32_bf16(a_lo, wvl[i], av, 0, 0, 0);
        av = __builtin_amdgcn_mfma_f32_16x16x32_bf16(a_hi, wvh[i], av, 0, 0, 0);
        int col = (w * 4 + i) * 16 + m;
        unsigned short* obase = obuf + (size_t)(R0 + qd * 4) * 256 + col;
#pragma unroll
        for (int r = 0; r < 4; ++r) {
          unsigned pk = __builtin_amdgcn_cvt_pk_fp8_f32(ak[r] + bkc[i], av[r] + bvc[i], 0, false);
          obase[(size_t)r * 256] = (unsigned short)pk;
        }
      }
      a_lo = n_lo; a_hi = n_hi;
    }
  } else {
    bf16x8 wql[4], wqh[4];
    float bqc[4];
#pragma unroll
    for (int i = 0; i < 4; ++i) {
      int col = (w * 4 + i) * 16 + m;
      const unsigned short* wq = WtA + (size_t)col * 64 + qd * 8;
      wql[i] = *(const bf16x8*)wq; wqh[i] = *(const bf16x8*)(wq + 32);
      bqc[i] = biasA[col];
    }
    const unsigned short* xr0 = xb + (size_t)(tile0 * 16 + m) * 64 + qd * 8;
    bf16x8 a_lo = *(const bf16x8*)xr0;
    bf16x8 a_hi = *(const bf16x8*)(xr0 + 32);
    for (int tt = 0; tt < ntiles; ++tt) {
      int ntt = (tt + 1 < ntiles) ? tt + 1 : tt;
      const unsigned short* xn = xb + (size_t)((tile0 + ntt) * 16 + m) * 64 + qd * 8;
      bf16x8 n_lo = *(const bf16x8*)xn;
      bf16x8 n_hi = *(const bf16x8*)(xn + 32);
      int R0 = (tile0 + tt) * 16;
#pragma unroll
      for (int i = 0; i < 4; ++i) {
        f32x4 acc = {0.f, 0.f, 0.f, 0.f};
        acc = __builtin_amdgcn_mfma_f32_16x16x32_bf16(a_lo, wql[i], acc, 0, 0, 0);
        acc = __builtin_amdgcn_mfma_f32_16x16x32_bf16(a_hi, wqh[i], acc, 0, 0, 0);
        int col = (w * 4 + i) * 16 + m;
        unsigned short* obase = obuf + (size_t)(R0 + qd * 4) * 256 + col;
#pragma unroll
        for (int r = 0; r < 4; ++r)
          obase[(size_t)r * 256] = f2bf(acc[r] + bqc[i]);
      }
      a_lo = n_lo; a_hi = n_hi;
    }
  }
}

// ---------------- fused fp32 skip GEMM for both directions (LDS-tiled, R12-proven) ----------------
__global__ __launch_bounds__(256) void skip_all(const float* __restrict__ xs, const float* __restrict__ xt,
    const float* __restrict__ Wsk, const float* __restrict__ bsk,
    float* __restrict__ xs_nxt, float* __restrict__ xt_nxt, int p_st, int p_ts, int rtS) {
  __shared__ float Xt[64][68];
  __shared__ float Wl[64][68];
  __shared__ float bias[64];
  int t = threadIdx.x;
  const float* x; const float* W; const float* bb; float* o; int N, rbase;
  if ((int)blockIdx.x < rtS) {
    x = xs; N = NSRC; rbase = blockIdx.x * 64;
    W = Wsk + (size_t)p_ts * 4096; bb = bsk + p_ts * 64; o = xs_nxt;
  } else {
    x = xt; N = NTGT; rbase = (blockIdx.x - rtS) * 64;
    W = Wsk + (size_t)p_st * 4096; bb = bsk + p_st * 64; o = xt_nxt;
  }
#pragma unroll
  for (int i = 0; i < 4; ++i) {
    int slot = i * 256 + t;
    int row = slot >> 4;
    int k4 = slot & 15;
    float4 xv = make_float4(0.f, 0.f, 0.f, 0.f);
    if (rbase + row < N) xv = *(const float4*)&x[(size_t)(rbase + row) * 64 + k4 * 4];
    Xt[k4 * 4 + 0][row] = xv.x;
    Xt[k4 * 4 + 1][row] = xv.y;
    Xt[k4 * 4 + 2][row] = xv.z;
    Xt[k4 * 4 + 3][row] = xv.w;
  }
#pragma unroll
  for (int i = 0; i < 4; ++i) {
    int slot = i * 256 + t;
    int kk = slot >> 4;
    int c4 = slot & 15;
    float4 wv = *(const float4*)&W[(size_t)kk * 64 + c4 * 4];
    *(float4*)&Wl[kk][c4 * 4] = wv;
  }
  if (t < 64) bias[t] = bb[t];
  __syncthreads();

  int c0 = (t & 15) * 4;
  int r0 = (t >> 4) * 4;
  float acc[4][4];
#pragma unroll
  for (int i = 0; i < 4; ++i)
#pragma unroll
    for (int j = 0; j < 4; ++j) acc[i][j] = 0.f;
#pragma unroll 8
  for (int kk = 0; kk < 64; ++kk) {
    float4 xv = *(const float4*)&Xt[kk][r0];
    float4 wv = *(const float4*)&Wl[kk][c0];
    float xr[4] = {xv.x, xv.y, xv.z, xv.w};
    float wc[4] = {wv.x, wv.y, wv.z, wv.w};
#pragma unroll
    for (int i = 0; i < 4; ++i)
#pragma unroll
      for (int j = 0; j < 4; ++j) acc[i][j] = fmaf(xr[i], wc[j], acc[i][j]);
  }
#pragma unroll
  for (int i = 0; i < 4; ++i) {
    int row = rbase + r0 + i;
    if (row < N) {
      float4 ov;
      ov.x = acc[i][0] + bias[c0 + 0];
      ov.y = acc[i][1] + bias[c0 + 1];
      ov.z = acc[i][2] + bias[c0 + 2];
      ov.w = acc[i][3] + bias[c0 + 3];
      *(float4*)&o[(size_t)row * 64 + c0] = ov;
    }
  }
}

// ---------------- fused aggregation for BOTH directions: one WAVE per node ----------------
// R18: fp8 kv rows (512B, uint2/lane gather). R16 structure (unroll-4, DPP reduce, exp2).
// R22: SGPR-scalarized addressing (VALU 62.5->57.6, 49->45us).
// R23: fma-chain dots (7->4 VALU ops per edge-dot, ~14% VALU trim).
__global__ __launch_bounds__(256) void agg_all(
    const unsigned short* __restrict__ q_small, const unsigned short* __restrict__ kv_big,
    const int* __restrict__ rp_st, const int* __restrict__ es_st,
    float* __restrict__ xt_nxt, unsigned short* __restrict__ xtb_nxt,
    const unsigned short* __restrict__ q_big, const unsigned short* __restrict__ kv_small,
    const int* __restrict__ rp_ts, const int* __restrict__ es_ts,
    float* __restrict__ xs_nxt, unsigned short* __restrict__ xsb_nxt,
    int relu, int stBlocks) {
  const unsigned short* q; const unsigned short* kvi; const int* rowptr; const int* eisrc;
  float* xout; unsigned short* xoutb; int node;
  int l = threadIdx.x & 63;
  int wv = __builtin_amdgcn_readfirstlane(threadIdx.x >> 6);   // wave-uniform -> SGPR
  if ((int)blockIdx.x < stBlocks) {
    node = blockIdx.x * 4 + wv;
    if (node >= NTGT) return;
    q = q_small; kvi = kv_big; rowptr = rp_st; eisrc = es_st; xout = xt_nxt; xoutb = xtb_nxt;
  } else {
    node = (blockIdx.x - stBlocks) * 4 + wv;
    if (node >= NSRC) return;
    q = q_big; kvi = kv_small; rowptr = rp_ts; eisrc = es_ts; xout = xs_nxt; xoutb = xsb_nxt;
  }
  int j = l & 15;
  float4 qf = bf4_to_f4(*(const bf4*)&q[(size_t)node * QK + l * 4]);
  // fold 1/sqrt(H)=0.125 and log2(e) so the softmax uses raw v_exp (base-2)
  const float QS = 0.125f * 1.44269504088896340736f;
  qf.x *= QS; qf.y *= QS; qf.z *= QS; qf.w *= QS;
  int beg = __builtin_amdgcn_readfirstlane(rowptr[node]);
  int end = __builtin_amdgcn_readfirstlane(rowptr[node + 1]);

  float lsum = 0.f;
  float4 acc = make_float4(0.f, 0.f, 0.f, 0.f);
  int p = beg;
  for (; p + 4 <= end; p += 4) {
    int s0 = __builtin_amdgcn_readfirstlane(eisrc[p]);
    int s1 = __builtin_amdgcn_readfirstlane(eisrc[p + 1]);
    int s2 = __builtin_amdgcn_readfirstlane(eisrc[p + 2]);
    int s3 = __builtin_amdgcn_readfirstlane(eisrc[p + 3]);
    uint2 a0 = ((const uint2*)(kvi + (size_t)s0 * 256))[l];
    uint2 a1 = ((const uint2*)(kvi + (size_t)s1 * 256))[l];
    uint2 a2 = ((const uint2*)(kvi + (size_t)s2 * 256))[l];
    uint2 a3 = ((const uint2*)(kvi + (size_t)s3 * 256))[l];
    f32x2 p00 = __builtin_amdgcn_cvt_pk_f32_fp8(a0.x, false);
    f32x2 p01 = __builtin_amdgcn_cvt_pk_f32_fp8(a0.x, true);
    f32x2 p02 = __builtin_amdgcn_cvt_pk_f32_fp8(a0.y, false);
    f32x2 p03 = __builtin_amdgcn_cvt_pk_f32_fp8(a0.y, true);
    f32x2 p10 = __builtin_amdgcn_cvt_pk_f32_fp8(a1.x, false);
    f32x2 p11 = __builtin_amdgcn_cvt_pk_f32_fp8(a1.x, true);
    f32x2 p12 = __builtin_amdgcn_cvt_pk_f32_fp8(a1.y, false);
    f32x2 p13 = __builtin_amdgcn_cvt_pk_f32_fp8(a1.y, true);
    f32x2 p20 = __builtin_amdgcn_cvt_pk_f32_fp8(a2.x, false);
    f32x2 p21 = __builtin_amdgcn_cvt_pk_f32_fp8(a2.x, true);
    f32x2 p22 = __builtin_amdgcn_cvt_pk_f32_fp8(a2.y, false);
    f32x2 p23 = __builtin_amdgcn_cvt_pk_f32_fp8(a2.y, true);
    f32x2 p30 = __builtin_amdgcn_cvt_pk_f32_fp8(a3.x, false);
    f32x2 p31 = __builtin_amdgcn_cvt_pk_f32_fp8(a3.x, true);
    f32x2 p32 = __builtin_amdgcn_cvt_pk_f32_fp8(a3.y, false);
    f32x2 p33 = __builtin_amdgcn_cvt_pk_f32_fp8(a3.y, true);
    float t0 = dot4f(qf, p00.x, p01.x, p02.x, p03.x);
    float t1 = dot4f(qf, p10.x, p11.x, p12.x, p13.x);
    float t2 = dot4f(qf, p20.x, p21.x, p22.x, p23.x);
    float t3 = dot4f(qf, p30.x, p31.x, p32.x, p33.x);
    t0 = red16(t0); t1 = red16(t1); t2 = red16(t2); t3 = red16(t3);
    float w0 = __builtin_amdgcn_exp2f(t0), w1 = __builtin_amdgcn_exp2f(t1);
    float w2 = __builtin_amdgcn_exp2f(t2), w3 = __builtin_amdgcn_exp2f(t3);
    lsum += (w0 + w1) + (w2 + w3);
    acc.x = fmaf(w0, p00.y, fmaf(w1, p10.y, fmaf(w2, p20.y, fmaf(w3, p30.y, acc.x))));
    acc.y = fmaf(w0, p01.y, fmaf(w1, p11.y, fmaf(w2, p21.y, fmaf(w3, p31.y, acc.y))));
    acc.z = fmaf(w0, p02.y, fmaf(w1, p12.y, fmaf(w2, p22.y, fmaf(w3, p32.y, acc.z))));
    acc.w = fmaf(w0, p03.y, fmaf(w1, p13.y, fmaf(w2, p23.y, fmaf(w3, p33.y, acc.w))));
  }
  for (; p < end; ++p) {
    int s0 = __builtin_amdgcn_readfirstlane(eisrc[p]);
    uint2 a0 = ((const uint2*)(kvi + (size_t)s0 * 256))[l];
    f32x2 p00 = __builtin_amdgcn_cvt_pk_f32_fp8(a0.x, false);
    f32x2 p01 = __builtin_amdgcn_cvt_pk_f32_fp8(a0.x, true);
    f32x2 p02 = __builtin_amdgcn_cvt_pk_f32_fp8(a0.y, false);
    f32x2 p03 = __builtin_amdgcn_cvt_pk_f32_fp8(a0.y, true);
    float s = dot4f(qf, p00.x, p01.x, p02.x, p03.x);
    s = red16(s);
    float w = __builtin_amdgcn_exp2f(s);
    lsum += w;
    acc.x = fmaf(w, p00.y, acc.x);
    acc.y = fmaf(w, p01.y, acc.y);
    acc.z = fmaf(w, p02.y, acc.z);
    acc.w = fmaf(w, p03.y, acc.w);
  }

  float inv = (lsum > 0.f) ? 1.f / lsum : 0.f;
  float4 r;
  r.x = acc.x * inv; r.y = acc.y * inv; r.z = acc.z * inv; r.w = acc.w * inv;
  r.x += __shfl_xor(r.x, 16, 64); r.x += __shfl_xor(r.x, 32, 64);
  r.y += __shfl_xor(r.y, 16, 64); r.y += __shfl_xor(r.y, 32, 64);
  r.z += __shfl_xor(r.z, 16, 64); r.z += __shfl_xor(r.z, 32, 64);
  r.w += __shfl_xor(r.w, 16, 64); r.w += __shfl_xor(r.w, 32, 64);
  if (l < 16) {
    float4 sk = *(const float4*)&xout[(size_t)node * HD + j * 4];
    float4 o;
    o.x = sk.x + 0.25f * r.x;
    o.y = sk.y + 0.25f * r.y;
    o.z = sk.z + 0.25f * r.z;
    o.w = sk.w + 0.25f * r.w;
    if (relu) {
      o.x = fmaxf(o.x, 0.f); o.y = fmaxf(o.y, 0.f);
      o.z = fmaxf(o.z, 0.f); o.w = fmaxf(o.w, 0.f);
    }
    *(float4*)&xout[(size_t)node * HD + j * 4] = o;
    bf4 ob;
    ob.x = f2bf(o.x); ob.y = f2bf(o.y); ob.z = f2bf(o.z); ob.w = f2bf(o.w);
    *(bf4*)&xoutb[(size_t)node * HD + j * 4] = ob;
  }
}

// ---------------- classifier: 16 lanes per pair, float4 loads ----------------
__global__ __launch_bounds__(256) void classifier_kernel(const float* __restrict__ xs, const float* __restrict__ xt,
    const int* __restrict__ ls, const int* __restrict__ lt, float* __restrict__ out, int n) {
  int g = blockIdx.x * 256 + threadIdx.x;
  int pair = g >> 4, j = g & 15;
  if (pair >= n) return;
  int a = ls[pair], b = lt[pair];
  float4 xa = *(const float4*)&xs[(size_t)a * HD + j * 4];
  float4 xb = *(const float4*)&xt[(size_t)b * HD + j * 4];
  float s = fmaf(xa.w, xb.w, fmaf(xa.z, xb.z, fmaf(xa.y, xb.y, xa.x * xb.x)));
  s = red16(s);
  if (j == 0) out[pair] = s;
}

// ---------------- launch ----------------
extern "C" void kernel_launch(void* const* d_in, const int* in_sizes, int n_in,
                              void* d_out, int out_size, void* d_ws, size_t ws_size,
                              hipStream_t stream) {
  const float* src_emb = (const float*)d_in[0];
  const float* tgt_emb = (const float*)d_in[1];
  const float* Wq = (const float*)d_in[2];
  const float* bq = (const float*)d_in[3];
  const float* Wk = (const float*)d_in[4];
  const float* bk = (const float*)d_in[5];
  const float* Wv = (const float*)d_in[6];
  const float* bv = (const float*)d_in[7];
  const float* Wsk = (const float*)d_in[8];
  const float* bsk = (const float*)d_in[9];
  const int* nid_s = (const int*)d_in[10];
  const int* nid_t = (const int*)d_in[11];
  const int* e_st = (const int*)d_in[12];
  const int* e_ts = (const int*)d_in[13];
  const int* e_lbl = (const int*)d_in[14];
  float* out = (float*)d_out;

  char* ws = (char*)d_ws;
  size_t off = 0;
  auto alloc = [&](size_t bytes) -> void* {
    void* p = ws + off;
    off += (bytes + 255) & ~(size_t)255;
    return p;
  };
  unsigned short* kv_big   = (unsigned short*)alloc((size_t)NSRC * 256 * 2);  // st k/v fp8 pairs
  unsigned short* q_big    = (unsigned short*)alloc((size_t)NSRC * QK * 2);   // ts q
  unsigned short* kv_small = (unsigned short*)alloc((size_t)NTGT * 256 * 2);  // ts k/v fp8 pairs
  unsigned short* q_small  = (unsigned short*)alloc((size_t)NTGT * QK * 2);   // st q
  float* xsA = (float*)alloc((size_t)NSRC * HD * 4);
  float* xsB = (float*)alloc((size_t)NSRC * HD * 4);
  float* xtA = (float*)alloc((size_t)NTGT * HD * 4);
  float* xtB = (float*)alloc((size_t)NTGT * HD * 4);
  unsigned short* xsAb = (unsigned short*)alloc((size_t)NSRC * HD * 2);
  unsigned short* xsBb = (unsigned short*)alloc((size_t)NSRC * HD * 2);
  unsigned short* xtAb = (unsigned short*)alloc((size_t)NTGT * HD * 2);
  unsigned short* xtBb = (unsigned short*)alloc((size_t)NTGT * HD * 2);
  unsigned short* Wtq = (unsigned short*)alloc((size_t)4 * 16384 * 2);
  unsigned short* Wtk = (unsigned short*)alloc((size_t)4 * 16384 * 2);
  unsigned short* Wtv = (unsigned short*)alloc((size_t)4 * 16384 * 2);
  int* rp_st = (int*)alloc((size_t)(NTGT + 1) * 4);
  int* es_st = (int*)alloc((size_t)NEDGE * 4);
  int* rp_ts = (int*)alloc((size_t)(NSRC + 1) * 4);
  int* es_ts = (int*)alloc((size_t)NEDGE * 4);
  int* cursor = (int*)alloc((size_t)NTOT * 4);
  int* counts = (int*)alloc((size_t)NTOT * 4);
  int* incl_buf = (int*)alloc((size_t)NTOT * 4);
  int* blocksums = (int*)alloc(64 * 4);
  int* boff = (int*)alloc(64 * 4);
  (void)ws_size; (void)in_sizes; (void)n_in; (void)out_size;

  auto cdiv = [](int a, int b) { return (a + b - 1) / b; };
  const int GATHER_BLK = cdiv(NTOT * HD, 256);          // 15000
  const int SETUP_BLK = 48 + GATHER_BLK + cdiv(NTOT, 256);
  const int RT_S = cdiv(NSRC, 64);                      // 782
  const int RT_T = cdiv(NTGT, 64);                      // 157
  const int G1 = cdiv(NSRC / 16, 8);                    // 391
  const int G2 = cdiv(NTGT / 16, 8);                    // 79
  const int NBLK_PROJ = 2 * (G1 + G2);                  // 940
  const int ST_BLK = cdiv(NTGT, 4);                     // 2500
  const int NBLK_AGG = ST_BLK + cdiv(NSRC, 4);          // 15000

  // fused setup: weight transpose + feature gather + counts zero
  setup_kernel<<<SETUP_BLK, 256, 0, stream>>>(Wq, Wk, Wv, Wtq, Wtk, Wtv,
                                              src_emb, nid_s, tgt_emb, nid_t,
                                              xsA, xsAb, xtA, xtAb, counts, GATHER_BLK);

  // CSR build for both edge sets
  hist_all_kernel<<<cdiv(2 * NEDGE, 256), 256, 0, stream>>>(e_st, e_ts, counts);
  scan1_kernel<<<cdiv(NTOT, 1024), 256, 0, stream>>>(counts, incl_buf, blocksums, NTOT);
  scan2_kernel<<<1, 64, 0, stream>>>(blocksums, boff, cdiv(NTOT, 1024));
  scan3_kernel<<<cdiv(NTOT, 256), 256, 0, stream>>>(incl_buf, counts, boff, rp_st, rp_ts, cursor);
  scatter_all_kernel<<<cdiv(2 * NEDGE, 256), 256, 0, stream>>>(e_st, e_ts, cursor, es_st, es_ts);

  const float* xs_cur = xsA; float* xs_nxt = xsB;
  const float* xt_cur = xtA; float* xt_nxt = xtB;
  const unsigned short* xsb_cur = xsAb; unsigned short* xsb_nxt = xsBb;
  const unsigned short* xtb_cur = xtAb; unsigned short* xtb_nxt = xtBb;
  for (int l = 0; l < 2; ++l) {
    int relu = (l == 0) ? 1 : 0;
    int p_st = l * 2 + 0, p_ts = l * 2 + 1;
    proj_all<<<NBLK_PROJ, 256, 0, stream>>>(xsb_cur, xtb_cur, Wtq, Wtk, Wtv, bq, bk, bv,
                                            kv_big, q_big, kv_small, q_small, p_st, p_ts);
    skip_all<<<RT_S + RT_T, 256, 0, stream>>>(xs_cur, xt_cur, Wsk, bsk, xs_nxt, xt_nxt, p_st, p_ts, RT_S);
    agg_all<<<NBLK_AGG, 256, 0, stream>>>(q_small, kv_big, rp_st, es_st, xt_nxt, xtb_nxt,
                                          q_big, kv_small, rp_ts, es_ts, xs_nxt, xsb_nxt,
                                          relu, ST_BLK);
    { const float* t = xs_nxt; xs_nxt = (float*)xs_cur; xs_cur = t; }
    { const float* t = xt_nxt; xt_nxt = (float*)xt_cur; xt_cur = t; }
    { const unsigned short* t = xsb_nxt; xsb_nxt = (unsigned short*)xsb_cur; xsb_cur = t; }
    { const unsigned short* t = xtb_nxt; xtb_nxt = (unsigned short*)xtb_cur; xtb_cur = t; }
  }

  classifier_kernel<<<cdiv(NLBL * 16, 256), 256, 0, stream>>>(xs_cur, xt_cur, e_lbl, e_lbl + NLBL, out, NLBL);
}

// Round 10
// 298.203 us; speedup vs baseline: 1.5238x; 1.0827x over previous
//
#include <hip/hip_runtime.h>

constexpr int NSRC = 50000;
constexpr int NTGT = 10000;
constexpr int NEDGE = 250000;
constexpr int NLBL = 200000;
constexpr int HD = 64;     // hidden dim (per head)
constexpr int NH = 4;      // heads
constexpr int QK = 256;    // HD*NH
constexpr int NTOT = NSRC + NTGT;

typedef __attribute__((ext_vector_type(8))) short bf16x8;
typedef __attribute__((ext_vector_type(4))) float f32x4;
typedef __attribute__((ext_vector_type(2))) float f32x2;

// ---------------- bf16 helpers ----------------
__device__ __forceinline__ unsigned short f2bf(float f) {
  unsigned u = __float_as_uint(f);
  u += 0x7FFFu + ((u >> 16) & 1u);   // round-to-nearest-even
  return (unsigned short)(u >> 16);
}
__device__ __forceinline__ float bf2f(unsigned short b) {
  return __uint_as_float((unsigned)b << 16);
}
struct bf4 { unsigned short x, y, z, w; };
__device__ __forceinline__ float4 bf4_to_f4(bf4 u) {
  return make_float4(bf2f(u.x), bf2f(u.y), bf2f(u.z), bf2f(u.w));
}

// ---------------- DPP 16-lane sum reduction (no LDS pipe, pure VALU) ----------------
template<int CTRL>
__device__ __forceinline__ float dpp_addf(float x) {
  int p = __builtin_amdgcn_update_dpp(0, __float_as_int(x), CTRL, 0xf, 0xf, true);
  return x + __int_as_float(p);
}
__device__ __forceinline__ float red16(float x) {
  x = dpp_addf<0xB1>(x);    // + lane^1 within quad
  x = dpp_addf<0x4E>(x);    // + lane^2 within quad
  x = dpp_addf<0x141>(x);   // + mirrored half-row (combines quads)
  x = dpp_addf<0x140>(x);   // + mirrored row (combines halves)
  return x;                 // all 16 lanes of the row hold the row sum
}

// 4-term dot as fma chain: 4 VALU ops instead of 7 (R23 trim)
__device__ __forceinline__ float dot4f(float4 q, float a, float b, float c, float d) {
  return fmaf(q.w, d, fmaf(q.z, c, fmaf(q.y, b, q.x * a)));
}

// ---------------- fused setup: weight transposes + feature gather + counts zero ----------------
// R24: also transposes Ws (skip weights) to bf16 (b in [48,52)); gather no longer
// writes the layer-0 f32 x copies (dead after skip fusion into proj).
__global__ __launch_bounds__(256) void setup_kernel(
    const float* __restrict__ Wq, const float* __restrict__ Wk, const float* __restrict__ Wv,
    const float* __restrict__ Wsk,
    unsigned short* __restrict__ Wtq, unsigned short* __restrict__ Wtk, unsigned short* __restrict__ Wtv,
    unsigned short* __restrict__ Wts,
    const float* __restrict__ semb, const int* __restrict__ sids,
    const float* __restrict__ temb, const int* __restrict__ tids,
    unsigned short* __restrict__ xsb, unsigned short* __restrict__ xtb,
    int* __restrict__ counts, int nGatherBlk) {
  __shared__ float tile[64][65];
  int b = blockIdx.x;
  int t = threadIdx.x;
  if (b < 48) {
    int mat = b >> 2, ct = b & 3;
    int grp = mat >> 2, p = mat & 3;
    const float* W = (grp == 0) ? Wq : (grp == 1) ? Wk : Wv;
    unsigned short* Wt = (grp == 0) ? Wtq : (grp == 1) ? Wtk : Wtv;
    W += (size_t)p * 16384;
    Wt += (size_t)p * 16384;
    int c = t & 63, r4 = t >> 6;
    for (int rr = 0; rr < 64; rr += 4)
      tile[rr + r4][c] = W[(size_t)(rr + r4) * 256 + ct * 64 + c];
    __syncthreads();
    for (int rr = 0; rr < 64; rr += 4) {
      int nloc = rr + r4;
      Wt[(size_t)(ct * 64 + nloc) * 64 + c] = f2bf(tile[c][nloc]);
    }
  } else if (b < 52) {
    // skip-weight transpose: Ws[p] 64x64 -> Wts[p] (col-major rows), bf16
    int p = b - 48;
    const float* W = Wsk + (size_t)p * 4096;
    unsigned short* Wt = Wts + (size_t)p * 4096;
    int c = t & 63, r4 = t >> 6;
    for (int rr = 0; rr < 64; rr += 4)
      tile[rr + r4][c] = W[(size_t)(rr + r4) * 64 + c];
    __syncthreads();
    for (int rr = 0; rr < 64; rr += 4)
      Wt[(size_t)(rr + r4) * 64 + c] = f2bf(tile[c][rr + r4]);
  } else if (b < 52 + nGatherBlk) {
    int i = (b - 52) * 256 + t;
    if (i < NSRC * HD) {
      xsb[i] = f2bf(semb[(size_t)sids[i >> 6] * HD + (i & 63)]);
    } else if (i < NTOT * HD) {
      int j = i - NSRC * HD;
      xtb[j] = f2bf(temb[(size_t)tids[j >> 6] * HD + (j & 63)]);
    }
  } else {
    int i = (b - 52 - nGatherBlk) * 256 + t;
    if (i < NTOT) counts[i] = 0;
  }
}

// ---------------- CSR build (both edge sets, concatenated counts) ----------------

__global__ __launch_bounds__(256) void hist_all_kernel(const int* __restrict__ e_st, const int* __restrict__ e_ts,
                                                       int* __restrict__ counts) {
  int i = blockIdx.x * 256 + threadIdx.x;
  if (i < NEDGE) atomicAdd(&counts[e_st[NEDGE + i]], 1);
  else if (i < 2 * NEDGE) atomicAdd(&counts[NTGT + e_ts[NEDGE + (i - NEDGE)]], 1);
}

__global__ __launch_bounds__(256) void scan1_kernel(const int* __restrict__ counts, int* __restrict__ incl,
                                                    int* __restrict__ blocksums, int n) {
  __shared__ int wtot[4];
  int t = threadIdx.x;
  int i0 = blockIdx.x * 1024 + t * 4;
  int e0 = (i0 + 0 < n) ? counts[i0 + 0] : 0;
  int e1 = (i0 + 1 < n) ? counts[i0 + 1] : 0;
  int e2 = (i0 + 2 < n) ? counts[i0 + 2] : 0;
  int e3 = (i0 + 3 < n) ? counts[i0 + 3] : 0;
  int s0 = e0, s1 = s0 + e1, s2 = s1 + e2, s3 = s2 + e3;
  int tsum = s3;
  int inc = tsum;
#pragma unroll
  for (int o = 1; o < 64; o <<= 1) {
    int u = __shfl_up(inc, o, 64);
    if ((t & 63) >= o) inc += u;
  }
  int wave = t >> 6;
  if ((t & 63) == 63) wtot[wave] = inc;
  __syncthreads();
  int woff = 0;
#pragma unroll
  for (int w_ = 0; w_ < 4; ++w_) if (w_ < wave) woff += wtot[w_];
  int toff = woff + inc - tsum;
  if (i0 + 0 < n) incl[i0 + 0] = toff + s0;
  if (i0 + 1 < n) incl[i0 + 1] = toff + s1;
  if (i0 + 2 < n) incl[i0 + 2] = toff + s2;
  if (i0 + 3 < n) incl[i0 + 3] = toff + s3;
  if (t == 255) blocksums[blockIdx.x] = woff + inc;
}

__global__ __launch_bounds__(64) void scan2_kernel(const int* __restrict__ blocksums, int* __restrict__ boff, int nb) {
  int t = threadIdx.x;
  int v = (t < nb) ? blocksums[t] : 0;
  int inc = v;
#pragma unroll
  for (int o = 1; o < 64; o <<= 1) {
    int u = __shfl_up(inc, o, 64);
    if (t >= o) inc += u;
  }
  if (t < nb) boff[t] = inc - v;
}

__global__ __launch_bounds__(256) void scan3_kernel(const int* __restrict__ incl, const int* __restrict__ counts,
                                                    const int* __restrict__ boff, int* __restrict__ rp_st,
                                                    int* __restrict__ rp_ts, int* __restrict__ cursor) {
  int i = blockIdx.x * 256 + threadIdx.x;
  if (i < NTOT) {
    int val = incl[i] + boff[i >> 10];
    if (i < NTGT) {
      rp_st[i + 1] = val;
      cursor[i] = val - counts[i];
      if (i == 0) rp_st[0] = 0;
    } else {
      int v2 = val - NEDGE;
      rp_ts[i - NTGT + 1] = v2;
      cursor[i] = v2 - counts[i];
      if (i == NTGT) rp_ts[0] = 0;
    }
  }
}

__global__ __launch_bounds__(256) void scatter_all_kernel(const int* __restrict__ e_st, const int* __restrict__ e_ts,
                                                          int* __restrict__ cursor, int* __restrict__ es_st,
                                                          int* __restrict__ es_ts) {
  int i = blockIdx.x * 256 + threadIdx.x;
  if (i < NEDGE) {
    int d = e_st[NEDGE + i];
    int p = atomicAdd(&cursor[d], 1);
    es_st[p] = e_st[i];
  } else if (i < 2 * NEDGE) {
    int j = i - NEDGE;
    int d = e_ts[NEDGE + j];
    int p = atomicAdd(&cursor[NTGT + d], 1);
    es_ts[p] = e_ts[j];
  }
}

// ---------------- MFMA projection dispatch per layer (kv + q + fused skip) ----------------
// R18: kv stored as packed fp8 e4m3 (k byte0, v byte1 per col).
// R21: weights-in-register + T=8 row-tile loop per block (latency fix).
// R24: skip GEMM fused into q-mode blocks (5th col-iter: 64 skip cols = 4 waves x 16;
// same bf16 A-fragments, 2 extra MFMA, f32 out to x*_nxt). skip_all kernel deleted —
// its x re-reads and 2 dispatches were pure overhead. Param map verified: q_s/skip_xs
// both p_ts; q_t/skip_xt both p_st.
__global__ __launch_bounds__(256) void proj_all(
    const unsigned short* __restrict__ xsb, const unsigned short* __restrict__ xtb,
    const unsigned short* __restrict__ Wtq, const unsigned short* __restrict__ Wtk,
    const unsigned short* __restrict__ Wtv, const unsigned short* __restrict__ Wts,
    const float* __restrict__ bq, const float* __restrict__ bk, const float* __restrict__ bv,
    const float* __restrict__ bsk,
    unsigned short* __restrict__ kv_big, unsigned short* __restrict__ q_big,
    unsigned short* __restrict__ kv_small, unsigned short* __restrict__ q_small,
    float* __restrict__ xs_nxt, float* __restrict__ xt_nxt,
    int p_st, int p_ts) {
  constexpr int T = 8;
  constexpr int T1 = NSRC / 16;             // 3125 row tiles (big)
  constexpr int T2 = NTGT / 16;             // 625 row tiles (small)
  constexpr int G1 = (T1 + T - 1) / T;      // 391
  constexpr int G2 = (T2 + T - 1) / T;      // 79
  int b = blockIdx.x;
  int t = threadIdx.x;
  int w = t >> 6, l = t & 63;
  int m = l & 15, qd = l >> 4;
  const unsigned short* xb; const unsigned short* WtA; const unsigned short* WtB = nullptr;
  const float* biasA; const float* biasB = nullptr;
  unsigned short* obuf;
  float* skip_out = nullptr;
  int tile0, ntiles, mode, psk = 0;
  if (b < G1) {                       // kv_s (params p_st)
    xb = xsb; tile0 = b * T; ntiles = min(T, T1 - tile0); mode = 0;
    WtA = Wtk + (size_t)p_st * 16384; biasA = bk + p_st * 256;
    WtB = Wtv + (size_t)p_st * 16384; biasB = bv + p_st * 256;
    obuf = kv_big;
  } else if (b < G1 + G2) {           // kv_t (params p_ts)
    xb = xtb; tile0 = (b - G1) * T; ntiles = min(T, T2 - tile0); mode = 0;
    WtA = Wtk + (size_t)p_ts * 16384; biasA = bk + p_ts * 256;
    WtB = Wtv + (size_t)p_ts * 16384; biasB = bv + p_ts * 256;
    obuf = kv_small;
  } else if (b < 2 * G1 + G2) {       // q_s + skip_xs (params p_ts)
    xb = xsb; tile0 = (b - G1 - G2) * T; ntiles = min(T, T1 - tile0); mode = 1;
    WtA = Wtq + (size_t)p_ts * 16384; biasA = bq + p_ts * 256;
    obuf = q_big; skip_out = xs_nxt; psk = p_ts;
  } else {                            // q_t + skip_xt (params p_st)
    xb = xtb; tile0 = (b - 2 * G1 - G2) * T; ntiles = min(T, T2 - tile0); mode = 1;
    WtA = Wtq + (size_t)p_st * 16384; biasA = bq + p_st * 256;
    obuf = q_small; skip_out = xt_nxt; psk = p_st;
  }

  if (mode == 0) {
    // resident weight fragments: 16 x bf16x8 = 64 VGPRs + 8 bias floats
    bf16x8 wkl[4], wkh[4], wvl[4], wvh[4];
    float bkc[4], bvc[4];
#pragma unroll
    for (int i = 0; i < 4; ++i) {
      int col = (w * 4 + i) * 16 + m;
      const unsigned short* wk = WtA + (size_t)col * 64 + qd * 8;
      const unsigned short* wv = WtB + (size_t)col * 64 + qd * 8;
      wkl[i] = *(const bf16x8*)wk; wkh[i] = *(const bf16x8*)(wk + 32);
      wvl[i] = *(const bf16x8*)wv; wvh[i] = *(const bf16x8*)(wv + 32);
      bkc[i] = biasA[col]; bvc[i] = biasB[col];
    }
    const unsigned short* xr0 = xb + (size_t)(tile0 * 16 + m) * 64 + qd * 8;
    bf16x8 a_lo = *(const bf16x8*)xr0;
    bf16x8 a_hi = *(const bf16x8*)(xr0 + 32);
    for (int tt = 0; tt < ntiles; ++tt) {
      int ntt = (tt + 1 < ntiles) ? tt + 1 : tt;   // clamped prefetch
      const unsigned short* xn = xb + (size_t)((tile0 + ntt) * 16 + m) * 64 + qd * 8;
      bf16x8 n_lo = *(const bf16x8*)xn;
      bf16x8 n_hi = *(const bf16x8*)(xn + 32);
      int R0 = (tile0 + tt) * 16;
#pragma unroll
      for (int i = 0; i < 4; ++i) {
        f32x4 ak = {0.f, 0.f, 0.f, 0.f}, av = {0.f, 0.f, 0.f, 0.f};
        ak = __builtin_amdgcn_mfma_f32_16x16x32_bf16(a_lo, wkl[i], ak, 0, 0, 0);
        ak = __builtin_amdgcn_mfma_f32_16x16x32_bf16(a_hi, wkh[i], ak, 0, 0, 0);
        av = __builtin_amdgcn_mfma_f32_16x16x32_bf16(a_lo, wvl[i], av, 0, 0, 0);
        av = __builtin_amdgcn_mfma_f32_16x16x32_bf16(a_hi, wvh[i], av, 0, 0, 0);
        int col = (w * 4 + i) * 16 + m;
        unsigned short* obase = obuf + (size_t)(R0 + qd * 4) * 256 + col;
#pragma unroll
        for (int r = 0; r < 4; ++r) {
          unsigned pk = __builtin_amdgcn_cvt_pk_fp8_f32(ak[r] + bkc[i], av[r] + bvc[i], 0, false);
          obase[(size_t)r * 256] = (unsigned short)pk;
        }
      }
      a_lo = n_lo; a_hi = n_hi;
    }
  } else {
    bf16x8 wql[4], wqh[4];
    float bqc[4];
#pragma unroll
    for (int i = 0; i < 4; ++i) {
      int col = (w * 4 + i) * 16 + m;
      const unsigned short* wq = WtA + (size_t)col * 64 + qd * 8;
      wql[i] = *(const bf16x8*)wq; wqh[i] = *(const bf16x8*)(wq + 32);
      bqc[i] = biasA[col];
    }
    // resident skip fragments: lane handles skip col = w*16+m
    int scol = w * 16 + m;
    const unsigned short* ws = Wts + (size_t)psk * 4096 + (size_t)scol * 64 + qd * 8;
    bf16x8 wsl_ = *(const bf16x8*)ws;
    bf16x8 wsh_ = *(const bf16x8*)(ws + 32);
    float bsc = bsk[psk * 64 + scol];
    const unsigned short* xr0 = xb + (size_t)(tile0 * 16 + m) * 64 + qd * 8;
    bf16x8 a_lo = *(const bf16x8*)xr0;
    bf16x8 a_hi = *(const bf16x8*)(xr0 + 32);
    for (int tt = 0; tt < ntiles; ++tt) {
      int ntt = (tt + 1 < ntiles) ? tt + 1 : tt;
      const unsigned short* xn = xb + (size_t)((tile0 + ntt) * 16 + m) * 64 + qd * 8;
      bf16x8 n_lo = *(const bf16x8*)xn;
      bf16x8 n_hi = *(const bf16x8*)(xn + 32);
      int R0 = (tile0 + tt) * 16;
#pragma unroll
      for (int i = 0; i < 4; ++i) {
        f32x4 acc = {0.f, 0.f, 0.f, 0.f};
        acc = __builtin_amdgcn_mfma_f32_16x16x32_bf16(a_lo, wql[i], acc, 0, 0, 0);
        acc = __builtin_amdgcn_mfma_f32_16x16x32_bf16(a_hi, wqh[i], acc, 0, 0, 0);
        int col = (w * 4 + i) * 16 + m;
        unsigned short* obase = obuf + (size_t)(R0 + qd * 4) * 256 + col;
#pragma unroll
        for (int r = 0; r < 4; ++r)
          obase[(size_t)r * 256] = f2bf(acc[r] + bqc[i]);
      }
      // fused skip: one more 64-col GEMM slice, f32 out
      {
        f32x4 sa = {0.f, 0.f, 0.f, 0.f};
        sa = __builtin_amdgcn_mfma_f32_16x16x32_bf16(a_lo, wsl_, sa, 0, 0, 0);
        sa = __builtin_amdgcn_mfma_f32_16x16x32_bf16(a_hi, wsh_, sa, 0, 0, 0);
        float* so = skip_out + (size_t)(R0 + qd * 4) * 64 + scol;
#pragma unroll
        for (int r = 0; r < 4; ++r)
          so[(size_t)r * 64] = sa[r] + bsc;
      }
      a_lo = n_lo; a_hi = n_hi;
    }
  }
}

// ---------------- fused aggregation for BOTH directions: one WAVE per node ----------------
// R18: fp8 kv rows (512B, uint2/lane gather). R16 structure (unroll-4, DPP reduce, exp2).
// R22: SGPR-scalarized addressing. R23: fma-chain dots.
__global__ __launch_bounds__(256) void agg_all(
    const unsigned short* __restrict__ q_small, const unsigned short* __restrict__ kv_big,
    const int* __restrict__ rp_st, const int* __restrict__ es_st,
    float* __restrict__ xt_nxt, unsigned short* __restrict__ xtb_nxt,
    const unsigned short* __restrict__ q_big, const unsigned short* __restrict__ kv_small,
    const int* __restrict__ rp_ts, const int* __restrict__ es_ts,
    float* __restrict__ xs_nxt, unsigned short* __restrict__ xsb_nxt,
    int relu, int stBlocks) {
  const unsigned short* q; const unsigned short* kvi; const int* rowptr; const int* eisrc;
  float* xout; unsigned short* xoutb; int node;
  int l = threadIdx.x & 63;
  int wv = __builtin_amdgcn_readfirstlane(threadIdx.x >> 6);   // wave-uniform -> SGPR
  if ((int)blockIdx.x < stBlocks) {
    node = blockIdx.x * 4 + wv;
    if (node >= NTGT) return;
    q = q_small; kvi = kv_big; rowptr = rp_st; eisrc = es_st; xout = xt_nxt; xoutb = xtb_nxt;
  } else {
    node = (blockIdx.x - stBlocks) * 4 + wv;
    if (node >= NSRC) return;
    q = q_big; kvi = kv_small; rowptr = rp_ts; eisrc = es_ts; xout = xs_nxt; xoutb = xsb_nxt;
  }
  int j = l & 15;
  float4 qf = bf4_to_f4(*(const bf4*)&q[(size_t)node * QK + l * 4]);
  // fold 1/sqrt(H)=0.125 and log2(e) so the softmax uses raw v_exp (base-2)
  const float QS = 0.125f * 1.44269504088896340736f;
  qf.x *= QS; qf.y *= QS; qf.z *= QS; qf.w *= QS;
  int beg = __builtin_amdgcn_readfirstlane(rowptr[node]);
  int end = __builtin_amdgcn_readfirstlane(rowptr[node + 1]);

  float lsum = 0.f;
  float4 acc = make_float4(0.f, 0.f, 0.f, 0.f);
  int p = beg;
  for (; p + 4 <= end; p += 4) {
    int s0 = __builtin_amdgcn_readfirstlane(eisrc[p]);
    int s1 = __builtin_amdgcn_readfirstlane(eisrc[p + 1]);
    int s2 = __builtin_amdgcn_readfirstlane(eisrc[p + 2]);
    int s3 = __builtin_amdgcn_readfirstlane(eisrc[p + 3]);
    uint2 a0 = ((const uint2*)(kvi + (size_t)s0 * 256))[l];
    uint2 a1 = ((const uint2*)(kvi + (size_t)s1 * 256))[l];
    uint2 a2 = ((const uint2*)(kvi + (size_t)s2 * 256))[l];
    uint2 a3 = ((const uint2*)(kvi + (size_t)s3 * 256))[l];
    f32x2 p00 = __builtin_amdgcn_cvt_pk_f32_fp8(a0.x, false);
    f32x2 p01 = __builtin_amdgcn_cvt_pk_f32_fp8(a0.x, true);
    f32x2 p02 = __builtin_amdgcn_cvt_pk_f32_fp8(a0.y, false);
    f32x2 p03 = __builtin_amdgcn_cvt_pk_f32_fp8(a0.y, true);
    f32x2 p10 = __builtin_amdgcn_cvt_pk_f32_fp8(a1.x, false);
    f32x2 p11 = __builtin_amdgcn_cvt_pk_f32_fp8(a1.x, true);
    f32x2 p12 = __builtin_amdgcn_cvt_pk_f32_fp8(a1.y, false);
    f32x2 p13 = __builtin_amdgcn_cvt_pk_f32_fp8(a1.y, true);
    f32x2 p20 = __builtin_amdgcn_cvt_pk_f32_fp8(a2.x, false);
    f32x2 p21 = __builtin_amdgcn_cvt_pk_f32_fp8(a2.x, true);
    f32x2 p22 = __builtin_amdgcn_cvt_pk_f32_fp8(a2.y, false);
    f32x2 p23 = __builtin_amdgcn_cvt_pk_f32_fp8(a2.y, true);
    f32x2 p30 = __builtin_amdgcn_cvt_pk_f32_fp8(a3.x, false);
    f32x2 p31 = __builtin_amdgcn_cvt_pk_f32_fp8(a3.x, true);
    f32x2 p32 = __builtin_amdgcn_cvt_pk_f32_fp8(a3.y, false);
    f32x2 p33 = __builtin_amdgcn_cvt_pk_f32_fp8(a3.y, true);
    float t0 = dot4f(qf, p00.x, p01.x, p02.x, p03.x);
    float t1 = dot4f(qf, p10.x, p11.x, p12.x, p13.x);
    float t2 = dot4f(qf, p20.x, p21.x, p22.x, p23.x);
    float t3 = dot4f(qf, p30.x, p31.x, p32.x, p33.x);
    t0 = red16(t0); t1 = red16(t1); t2 = red16(t2); t3 = red16(t3);
    float w0 = __builtin_amdgcn_exp2f(t0), w1 = __builtin_amdgcn_exp2f(t1);
    float w2 = __builtin_amdgcn_exp2f(t2), w3 = __builtin_amdgcn_exp2f(t3);
    lsum += (w0 + w1) + (w2 + w3);
    acc.x = fmaf(w0, p00.y, fmaf(w1, p10.y, fmaf(w2, p20.y, fmaf(w3, p30.y, acc.x))));
    acc.y = fmaf(w0, p01.y, fmaf(w1, p11.y, fmaf(w2, p21.y, fmaf(w3, p31.y, acc.y))));
    acc.z = fmaf(w0, p02.y, fmaf(w1, p12.y, fmaf(w2, p22.y, fmaf(w3, p32.y, acc.z))));
    acc.w = fmaf(w0, p03.y, fmaf(w1, p13.y, fmaf(w2, p23.y, fmaf(w3, p33.y, acc.w))));
  }
  for (; p < end; ++p) {
    int s0 = __builtin_amdgcn_readfirstlane(eisrc[p]);
    uint2 a0 = ((const uint2*)(kvi + (size_t)s0 * 256))[l];
    f32x2 p00 = __builtin_amdgcn_cvt_pk_f32_fp8(a0.x, false);
    f32x2 p01 = __builtin_amdgcn_cvt_pk_f32_fp8(a0.x, true);
    f32x2 p02 = __builtin_amdgcn_cvt_pk_f32_fp8(a0.y, false);
    f32x2 p03 = __builtin_amdgcn_cvt_pk_f32_fp8(a0.y, true);
    float s = dot4f(qf, p00.x, p01.x, p02.x, p03.x);
    s = red16(s);
    float w = __builtin_amdgcn_exp2f(s);
    lsum += w;
    acc.x = fmaf(w, p00.y, acc.x);
    acc.y = fmaf(w, p01.y, acc.y);
    acc.z = fmaf(w, p02.y, acc.z);
    acc.w = fmaf(w, p03.y, acc.w);
  }

  float inv = (lsum > 0.f) ? 1.f / lsum : 0.f;
  float4 r;
  r.x = acc.x * inv; r.y = acc.y * inv; r.z = acc.z * inv; r.w = acc.w * inv;
  r.x += __shfl_xor(r.x, 16, 64); r.x += __shfl_xor(r.x, 32, 64);
  r.y += __shfl_xor(r.y, 16, 64); r.y += __shfl_xor(r.y, 32, 64);
  r.z += __shfl_xor(r.z, 16, 64); r.z += __shfl_xor(r.z, 32, 64);
  r.w += __shfl_xor(r.w, 16, 64); r.w += __shfl_xor(r.w, 32, 64);
  if (l < 16) {
    float4 sk = *(const float4*)&xout[(size_t)node * HD + j * 4];
    float4 o;
    o.x = sk.x + 0.25f * r.x;
    o.y = sk.y + 0.25f * r.y;
    o.z = sk.z + 0.25f * r.z;
    o.w = sk.w + 0.25f * r.w;
    if (relu) {
      o.x = fmaxf(o.x, 0.f); o.y = fmaxf(o.y, 0.f);
      o.z = fmaxf(o.z, 0.f); o.w = fmaxf(o.w, 0.f);
    }
    *(float4*)&xout[(size_t)node * HD + j * 4] = o;
    bf4 ob;
    ob.x = f2bf(o.x); ob.y = f2bf(o.y); ob.z = f2bf(o.z); ob.w = f2bf(o.w);
    *(bf4*)&xoutb[(size_t)node * HD + j * 4] = ob;
  }
}

// ---------------- classifier: 16 lanes per pair, float4 loads ----------------
__global__ __launch_bounds__(256) void classifier_kernel(const float* __restrict__ xs, const float* __restrict__ xt,
    const int* __restrict__ ls, const int* __restrict__ lt, float* __restrict__ out, int n) {
  int g = blockIdx.x * 256 + threadIdx.x;
  int pair = g >> 4, j = g & 15;
  if (pair >= n) return;
  int a = ls[pair], b = lt[pair];
  float4 xa = *(const float4*)&xs[(size_t)a * HD + j * 4];
  float4 xb = *(const float4*)&xt[(size_t)b * HD + j * 4];
  float s = fmaf(xa.w, xb.w, fmaf(xa.z, xb.z, fmaf(xa.y, xb.y, xa.x * xb.x)));
  s = red16(s);
  if (j == 0) out[pair] = s;
}

// ---------------- launch ----------------
extern "C" void kernel_launch(void* const* d_in, const int* in_sizes, int n_in,
                              void* d_out, int out_size, void* d_ws, size_t ws_size,
                              hipStream_t stream) {
  const float* src_emb = (const float*)d_in[0];
  const float* tgt_emb = (const float*)d_in[1];
  const float* Wq = (const float*)d_in[2];
  const float* bq = (const float*)d_in[3];
  const float* Wk = (const float*)d_in[4];
  const float* bk = (const float*)d_in[5];
  const float* Wv = (const float*)d_in[6];
  const float* bv = (const float*)d_in[7];
  const float* Wsk = (const float*)d_in[8];
  const float* bsk = (const float*)d_in[9];
  const int* nid_s = (const int*)d_in[10];
  const int* nid_t = (const int*)d_in[11];
  const int* e_st = (const int*)d_in[12];
  const int* e_ts = (const int*)d_in[13];
  const int* e_lbl = (const int*)d_in[14];
  float* out = (float*)d_out;

  char* ws = (char*)d_ws;
  size_t off = 0;
  auto alloc = [&](size_t bytes) -> void* {
    void* p = ws + off;
    off += (bytes + 255) & ~(size_t)255;
    return p;
  };
  unsigned short* kv_big   = (unsigned short*)alloc((size_t)NSRC * 256 * 2);  // st k/v fp8 pairs
  unsigned short* q_big    = (unsigned short*)alloc((size_t)NSRC * QK * 2);   // ts q
  unsigned short* kv_small = (unsigned short*)alloc((size_t)NTGT * 256 * 2);  // ts k/v fp8 pairs
  unsigned short* q_small  = (unsigned short*)alloc((size_t)NTGT * QK * 2);   // st q
  float* xsA = (float*)alloc((size_t)NSRC * HD * 4);
  float* xsB = (float*)alloc((size_t)NSRC * HD * 4);
  float* xtA = (float*)alloc((size_t)NTGT * HD * 4);
  float* xtB = (float*)alloc((size_t)NTGT * HD * 4);
  unsigned short* xsAb = (unsigned short*)alloc((size_t)NSRC * HD * 2);
  unsigned short* xsBb = (unsigned short*)alloc((size_t)NSRC * HD * 2);
  unsigned short* xtAb = (unsigned short*)alloc((size_t)NTGT * HD * 2);
  unsigned short* xtBb = (unsigned short*)alloc((size_t)NTGT * HD * 2);
  unsigned short* Wtq = (unsigned short*)alloc((size_t)4 * 16384 * 2);
  unsigned short* Wtk = (unsigned short*)alloc((size_t)4 * 16384 * 2);
  unsigned short* Wtv = (unsigned short*)alloc((size_t)4 * 16384 * 2);
  unsigned short* Wts = (unsigned short*)alloc((size_t)4 * 4096 * 2);
  int* rp_st = (int*)alloc((size_t)(NTGT + 1) * 4);
  int* es_st = (int*)alloc((size_t)NEDGE * 4);
  int* rp_ts = (int*)alloc((size_t)(NSRC + 1) * 4);
  int* es_ts = (int*)alloc((size_t)NEDGE * 4);
  int* cursor = (int*)alloc((size_t)NTOT * 4);
  int* counts = (int*)alloc((size_t)NTOT * 4);
  int* incl_buf = (int*)alloc((size_t)NTOT * 4);
  int* blocksums = (int*)alloc(64 * 4);
  int* boff = (int*)alloc(64 * 4);
  (void)ws_size; (void)in_sizes; (void)n_in; (void)out_size;

  auto cdiv = [](int a, int b) { return (a + b - 1) / b; };
  const int GATHER_BLK = cdiv(NTOT * HD, 256);          // 15000
  const int SETUP_BLK = 52 + GATHER_BLK + cdiv(NTOT, 256);
  const int G1 = cdiv(NSRC / 16, 8);                    // 391
  const int G2 = cdiv(NTGT / 16, 8);                    // 79
  const int NBLK_PROJ = 2 * (G1 + G2);                  // 940
  const int ST_BLK = cdiv(NTGT, 4);                     // 2500
  const int NBLK_AGG = ST_BLK + cdiv(NSRC, 4);          // 15000

  // fused setup: weight transposes (qkv + skip) + feature gather (bf16 only) + counts zero
  setup_kernel<<<SETUP_BLK, 256, 0, stream>>>(Wq, Wk, Wv, Wsk, Wtq, Wtk, Wtv, Wts,
                                              src_emb, nid_s, tgt_emb, nid_t,
                                              xsAb, xtAb, counts, GATHER_BLK);

  // CSR build for both edge sets
  hist_all_kernel<<<cdiv(2 * NEDGE, 256), 256, 0, stream>>>(e_st, e_ts, counts);
  scan1_kernel<<<cdiv(NTOT, 1024), 256, 0, stream>>>(counts, incl_buf, blocksums, NTOT);
  scan2_kernel<<<1, 64, 0, stream>>>(blocksums, boff, cdiv(NTOT, 1024));
  scan3_kernel<<<cdiv(NTOT, 256), 256, 0, stream>>>(incl_buf, counts, boff, rp_st, rp_ts, cursor);
  scatter_all_kernel<<<cdiv(2 * NEDGE, 256), 256, 0, stream>>>(e_st, e_ts, cursor, es_st, es_ts);

  float* xs_cur = xsA; float* xs_nxt = xsB;
  float* xt_cur = xtA; float* xt_nxt = xtB;
  const unsigned short* xsb_cur = xsAb; unsigned short* xsb_nxt = xsBb;
  const unsigned short* xtb_cur = xtAb; unsigned short* xtb_nxt = xtBb;
  for (int l = 0; l < 2; ++l) {
    int relu = (l == 0) ? 1 : 0;
    int p_st = l * 2 + 0, p_ts = l * 2 + 1;
    proj_all<<<NBLK_PROJ, 256, 0, stream>>>(xsb_cur, xtb_cur, Wtq, Wtk, Wtv, Wts,
                                            bq, bk, bv, bsk,
                                            kv_big, q_big, kv_small, q_small,
                                            xs_nxt, xt_nxt, p_st, p_ts);
    agg_all<<<NBLK_AGG, 256, 0, stream>>>(q_small, kv_big, rp_st, es_st, xt_nxt, xtb_nxt,
                                          q_big, kv_small, rp_ts, es_ts, xs_nxt, xsb_nxt,
                                          relu, ST_BLK);
    { float* t = xs_nxt; xs_nxt = xs_cur; xs_cur = t; }
    { float* t = xt_nxt; xt_nxt = xt_cur; xt_cur = t; }
    { const unsigned short* t = xsb_nxt; xsb_nxt = (unsigned short*)xsb_cur; xsb_cur = t; }
    { const unsigned short* t = xtb_nxt; xtb_nxt = (unsigned short*)xtb_cur; xtb_cur = t; }
  }

  classifier_kernel<<<cdiv(NLBL * 16, 256), 256, 0, stream>>>(xs_cur, xt_cur, e_lbl, e_lbl + NLBL, out, NLBL);
}

// Round 11
// 294.999 us; speedup vs baseline: 1.5403x; 1.0109x over previous
//
#include <hip/hip_runtime.h>

constexpr int NSRC = 50000;
constexpr int NTGT = 10000;
constexpr int NEDGE = 250000;
constexpr int NLBL = 200000;
constexpr int HD = 64;     // hidden dim (per head)
constexpr int NH = 4;      // heads
constexpr int QK = 256;    // HD*NH
constexpr int NTOT = NSRC + NTGT;

typedef __attribute__((ext_vector_type(8))) short bf16x8;
typedef __attribute__((ext_vector_type(4))) float f32x4;
typedef __attribute__((ext_vector_type(2))) float f32x2;

// ---------------- bf16 helpers ----------------
__device__ __forceinline__ unsigned short f2bf(float f) {
  unsigned u = __float_as_uint(f);
  u += 0x7FFFu + ((u >> 16) & 1u);   // round-to-nearest-even
  return (unsigned short)(u >> 16);
}
__device__ __forceinline__ float bf2f(unsigned short b) {
  return __uint_as_float((unsigned)b << 16);
}
struct bf4 { unsigned short x, y, z, w; };
__device__ __forceinline__ float4 bf4_to_f4(bf4 u) {
  return make_float4(bf2f(u.x), bf2f(u.y), bf2f(u.z), bf2f(u.w));
}

// ---------------- DPP 16-lane sum reduction (no LDS pipe, pure VALU) ----------------
template<int CTRL>
__device__ __forceinline__ float dpp_addf(float x) {
  int p = __builtin_amdgcn_update_dpp(0, __float_as_int(x), CTRL, 0xf, 0xf, true);
  return x + __int_as_float(p);
}
__device__ __forceinline__ float red16(float x) {
  x = dpp_addf<0xB1>(x);    // + lane^1 within quad
  x = dpp_addf<0x4E>(x);    // + lane^2 within quad
  x = dpp_addf<0x141>(x);   // + mirrored half-row (combines quads)
  x = dpp_addf<0x140>(x);   // + mirrored row (combines halves)
  return x;                 // all 16 lanes of the row hold the row sum
}

// 4-term dot as fma chain: 4 VALU ops instead of 7 (R23 trim)
__device__ __forceinline__ float dot4f(float4 q, float a, float b, float c, float d) {
  return fmaf(q.w, d, fmaf(q.z, c, fmaf(q.y, b, q.x * a)));
}

// ---------------- fused setup: weight transposes + feature gather + counts zero ----------------
__global__ __launch_bounds__(256) void setup_kernel(
    const float* __restrict__ Wq, const float* __restrict__ Wk, const float* __restrict__ Wv,
    const float* __restrict__ Wsk,
    unsigned short* __restrict__ Wtq, unsigned short* __restrict__ Wtk, unsigned short* __restrict__ Wtv,
    unsigned short* __restrict__ Wts,
    const float* __restrict__ semb, const int* __restrict__ sids,
    const float* __restrict__ temb, const int* __restrict__ tids,
    unsigned short* __restrict__ xsb, unsigned short* __restrict__ xtb,
    int* __restrict__ counts, int nGatherBlk) {
  __shared__ float tile[64][65];
  int b = blockIdx.x;
  int t = threadIdx.x;
  if (b < 48) {
    int mat = b >> 2, ct = b & 3;
    int grp = mat >> 2, p = mat & 3;
    const float* W = (grp == 0) ? Wq : (grp == 1) ? Wk : Wv;
    unsigned short* Wt = (grp == 0) ? Wtq : (grp == 1) ? Wtk : Wtv;
    W += (size_t)p * 16384;
    Wt += (size_t)p * 16384;
    int c = t & 63, r4 = t >> 6;
    for (int rr = 0; rr < 64; rr += 4)
      tile[rr + r4][c] = W[(size_t)(rr + r4) * 256 + ct * 64 + c];
    __syncthreads();
    for (int rr = 0; rr < 64; rr += 4) {
      int nloc = rr + r4;
      Wt[(size_t)(ct * 64 + nloc) * 64 + c] = f2bf(tile[c][nloc]);
    }
  } else if (b < 52) {
    // skip-weight transpose: Ws[p] 64x64 -> Wts[p] (col-major rows), bf16
    int p = b - 48;
    const float* W = Wsk + (size_t)p * 4096;
    unsigned short* Wt = Wts + (size_t)p * 4096;
    int c = t & 63, r4 = t >> 6;
    for (int rr = 0; rr < 64; rr += 4)
      tile[rr + r4][c] = W[(size_t)(rr + r4) * 64 + c];
    __syncthreads();
    for (int rr = 0; rr < 64; rr += 4)
      Wt[(size_t)(rr + r4) * 64 + c] = f2bf(tile[c][rr + r4]);
  } else if (b < 52 + nGatherBlk) {
    int i = (b - 52) * 256 + t;
    if (i < NSRC * HD) {
      xsb[i] = f2bf(semb[(size_t)sids[i >> 6] * HD + (i & 63)]);
    } else if (i < NTOT * HD) {
      int j = i - NSRC * HD;
      xtb[j] = f2bf(temb[(size_t)tids[j >> 6] * HD + (j & 63)]);
    }
  } else {
    int i = (b - 52 - nGatherBlk) * 256 + t;
    if (i < NTOT) counts[i] = 0;
  }
}

// ---------------- CSR build (both edge sets, concatenated counts) ----------------

__global__ __launch_bounds__(256) void hist_all_kernel(const int* __restrict__ e_st, const int* __restrict__ e_ts,
                                                       int* __restrict__ counts) {
  int i = blockIdx.x * 256 + threadIdx.x;
  if (i < NEDGE) atomicAdd(&counts[e_st[NEDGE + i]], 1);
  else if (i < 2 * NEDGE) atomicAdd(&counts[NTGT + e_ts[NEDGE + (i - NEDGE)]], 1);
}

__global__ __launch_bounds__(256) void scan1_kernel(const int* __restrict__ counts, int* __restrict__ incl,
                                                    int* __restrict__ blocksums, int n) {
  __shared__ int wtot[4];
  int t = threadIdx.x;
  int i0 = blockIdx.x * 1024 + t * 4;
  int e0 = (i0 + 0 < n) ? counts[i0 + 0] : 0;
  int e1 = (i0 + 1 < n) ? counts[i0 + 1] : 0;
  int e2 = (i0 + 2 < n) ? counts[i0 + 2] : 0;
  int e3 = (i0 + 3 < n) ? counts[i0 + 3] : 0;
  int s0 = e0, s1 = s0 + e1, s2 = s1 + e2, s3 = s2 + e3;
  int tsum = s3;
  int inc = tsum;
#pragma unroll
  for (int o = 1; o < 64; o <<= 1) {
    int u = __shfl_up(inc, o, 64);
    if ((t & 63) >= o) inc += u;
  }
  int wave = t >> 6;
  if ((t & 63) == 63) wtot[wave] = inc;
  __syncthreads();
  int woff = 0;
#pragma unroll
  for (int w_ = 0; w_ < 4; ++w_) if (w_ < wave) woff += wtot[w_];
  int toff = woff + inc - tsum;
  if (i0 + 0 < n) incl[i0 + 0] = toff + s0;
  if (i0 + 1 < n) incl[i0 + 1] = toff + s1;
  if (i0 + 2 < n) incl[i0 + 2] = toff + s2;
  if (i0 + 3 < n) incl[i0 + 3] = toff + s3;
  if (t == 255) blocksums[blockIdx.x] = woff + inc;
}

__global__ __launch_bounds__(64) void scan2_kernel(const int* __restrict__ blocksums, int* __restrict__ boff, int nb) {
  int t = threadIdx.x;
  int v = (t < nb) ? blocksums[t] : 0;
  int inc = v;
#pragma unroll
  for (int o = 1; o < 64; o <<= 1) {
    int u = __shfl_up(inc, o, 64);
    if (t >= o) inc += u;
  }
  if (t < nb) boff[t] = inc - v;
}

__global__ __launch_bounds__(256) void scan3_kernel(const int* __restrict__ incl, const int* __restrict__ counts,
                                                    const int* __restrict__ boff, int* __restrict__ rp_st,
                                                    int* __restrict__ rp_ts, int* __restrict__ cursor) {
  int i = blockIdx.x * 256 + threadIdx.x;
  if (i < NTOT) {
    int val = incl[i] + boff[i >> 10];
    if (i < NTGT) {
      rp_st[i + 1] = val;
      cursor[i] = val - counts[i];
      if (i == 0) rp_st[0] = 0;
    } else {
      int v2 = val - NEDGE;
      rp_ts[i - NTGT + 1] = v2;
      cursor[i] = v2 - counts[i];
      if (i == NTGT) rp_ts[0] = 0;
    }
  }
}

__global__ __launch_bounds__(256) void scatter_all_kernel(const int* __restrict__ e_st, const int* __restrict__ e_ts,
                                                          int* __restrict__ cursor, int* __restrict__ es_st,
                                                          int* __restrict__ es_ts) {
  int i = blockIdx.x * 256 + threadIdx.x;
  if (i < NEDGE) {
    int d = e_st[NEDGE + i];
    int p = atomicAdd(&cursor[d], 1);
    es_st[p] = e_st[i];
  } else if (i < 2 * NEDGE) {
    int j = i - NEDGE;
    int d = e_ts[NEDGE + j];
    int p = atomicAdd(&cursor[NTGT + d], 1);
    es_ts[p] = e_ts[j];
  }
}

// ---------------- MFMA projection dispatch per layer (kv + q + fused skip) ----------------
// R18: kv packed fp8 e4m3 (k byte0, v byte1). R21: weights-in-register + T=8 row loop.
// R24: skip GEMM fused into q-mode blocks. R25: q also fp8 (1B/col, 256B rows) —
// halves q write traffic here and q read traffic in agg.
__global__ __launch_bounds__(256) void proj_all(
    const unsigned short* __restrict__ xsb, const unsigned short* __restrict__ xtb,
    const unsigned short* __restrict__ Wtq, const unsigned short* __restrict__ Wtk,
    const unsigned short* __restrict__ Wtv, const unsigned short* __restrict__ Wts,
    const float* __restrict__ bq, const float* __restrict__ bk, const float* __restrict__ bv,
    const float* __restrict__ bsk,
    unsigned short* __restrict__ kv_big, unsigned char* __restrict__ q_big,
    unsigned short* __restrict__ kv_small, unsigned char* __restrict__ q_small,
    float* __restrict__ xs_nxt, float* __restrict__ xt_nxt,
    int p_st, int p_ts) {
  constexpr int T = 8;
  constexpr int T1 = NSRC / 16;             // 3125 row tiles (big)
  constexpr int T2 = NTGT / 16;             // 625 row tiles (small)
  constexpr int G1 = (T1 + T - 1) / T;      // 391
  constexpr int G2 = (T2 + T - 1) / T;      // 79
  int b = blockIdx.x;
  int t = threadIdx.x;
  int w = t >> 6, l = t & 63;
  int m = l & 15, qd = l >> 4;
  const unsigned short* xb; const unsigned short* WtA; const unsigned short* WtB = nullptr;
  const float* biasA; const float* biasB = nullptr;
  unsigned short* okv = nullptr;
  unsigned char* oq = nullptr;
  float* skip_out = nullptr;
  int tile0, ntiles, mode, psk = 0;
  if (b < G1) {                       // kv_s (params p_st)
    xb = xsb; tile0 = b * T; ntiles = min(T, T1 - tile0); mode = 0;
    WtA = Wtk + (size_t)p_st * 16384; biasA = bk + p_st * 256;
    WtB = Wtv + (size_t)p_st * 16384; biasB = bv + p_st * 256;
    okv = kv_big;
  } else if (b < G1 + G2) {           // kv_t (params p_ts)
    xb = xtb; tile0 = (b - G1) * T; ntiles = min(T, T2 - tile0); mode = 0;
    WtA = Wtk + (size_t)p_ts * 16384; biasA = bk + p_ts * 256;
    WtB = Wtv + (size_t)p_ts * 16384; biasB = bv + p_ts * 256;
    okv = kv_small;
  } else if (b < 2 * G1 + G2) {       // q_s + skip_xs (params p_ts)
    xb = xsb; tile0 = (b - G1 - G2) * T; ntiles = min(T, T1 - tile0); mode = 1;
    WtA = Wtq + (size_t)p_ts * 16384; biasA = bq + p_ts * 256;
    oq = q_big; skip_out = xs_nxt; psk = p_ts;
  } else {                            // q_t + skip_xt (params p_st)
    xb = xtb; tile0 = (b - 2 * G1 - G2) * T; ntiles = min(T, T2 - tile0); mode = 1;
    WtA = Wtq + (size_t)p_st * 16384; biasA = bq + p_st * 256;
    oq = q_small; skip_out = xt_nxt; psk = p_st;
  }

  if (mode == 0) {
    // resident weight fragments: 16 x bf16x8 = 64 VGPRs + 8 bias floats
    bf16x8 wkl[4], wkh[4], wvl[4], wvh[4];
    float bkc[4], bvc[4];
#pragma unroll
    for (int i = 0; i < 4; ++i) {
      int col = (w * 4 + i) * 16 + m;
      const unsigned short* wk = WtA + (size_t)col * 64 + qd * 8;
      const unsigned short* wv = WtB + (size_t)col * 64 + qd * 8;
      wkl[i] = *(const bf16x8*)wk; wkh[i] = *(const bf16x8*)(wk + 32);
      wvl[i] = *(const bf16x8*)wv; wvh[i] = *(const bf16x8*)(wv + 32);
      bkc[i] = biasA[col]; bvc[i] = biasB[col];
    }
    const unsigned short* xr0 = xb + (size_t)(tile0 * 16 + m) * 64 + qd * 8;
    bf16x8 a_lo = *(const bf16x8*)xr0;
    bf16x8 a_hi = *(const bf16x8*)(xr0 + 32);
    for (int tt = 0; tt < ntiles; ++tt) {
      int ntt = (tt + 1 < ntiles) ? tt + 1 : tt;   // clamped prefetch
      const unsigned short* xn = xb + (size_t)((tile0 + ntt) * 16 + m) * 64 + qd * 8;
      bf16x8 n_lo = *(const bf16x8*)xn;
      bf16x8 n_hi = *(const bf16x8*)(xn + 32);
      int R0 = (tile0 + tt) * 16;
#pragma unroll
      for (int i = 0; i < 4; ++i) {
        f32x4 ak = {0.f, 0.f, 0.f, 0.f}, av = {0.f, 0.f, 0.f, 0.f};
        ak = __builtin_amdgcn_mfma_f32_16x16x32_bf16(a_lo, wkl[i], ak, 0, 0, 0);
        ak = __builtin_amdgcn_mfma_f32_16x16x32_bf16(a_hi, wkh[i], ak, 0, 0, 0);
        av = __builtin_amdgcn_mfma_f32_16x16x32_bf16(a_lo, wvl[i], av, 0, 0, 0);
        av = __builtin_amdgcn_mfma_f32_16x16x32_bf16(a_hi, wvh[i], av, 0, 0, 0);
        int col = (w * 4 + i) * 16 + m;
        unsigned short* obase = okv + (size_t)(R0 + qd * 4) * 256 + col;
#pragma unroll
        for (int r = 0; r < 4; ++r) {
          unsigned pk = __builtin_amdgcn_cvt_pk_fp8_f32(ak[r] + bkc[i], av[r] + bvc[i], 0, false);
          obase[(size_t)r * 256] = (unsigned short)pk;
        }
      }
      a_lo = n_lo; a_hi = n_hi;
    }
  } else {
    bf16x8 wql[4], wqh[4];
    float bqc[4];
#pragma unroll
    for (int i = 0; i < 4; ++i) {
      int col = (w * 4 + i) * 16 + m;
      const unsigned short* wq = WtA + (size_t)col * 64 + qd * 8;
      wql[i] = *(const bf16x8*)wq; wqh[i] = *(const bf16x8*)(wq + 32);
      bqc[i] = biasA[col];
    }
    // resident skip fragments: lane handles skip col = w*16+m
    int scol = w * 16 + m;
    const unsigned short* ws = Wts + (size_t)psk * 4096 + (size_t)scol * 64 + qd * 8;
    bf16x8 wsl_ = *(const bf16x8*)ws;
    bf16x8 wsh_ = *(const bf16x8*)(ws + 32);
    float bsc = bsk[psk * 64 + scol];
    const unsigned short* xr0 = xb + (size_t)(tile0 * 16 + m) * 64 + qd * 8;
    bf16x8 a_lo = *(const bf16x8*)xr0;
    bf16x8 a_hi = *(const bf16x8*)(xr0 + 32);
    for (int tt = 0; tt < ntiles; ++tt) {
      int ntt = (tt + 1 < ntiles) ? tt + 1 : tt;
      const unsigned short* xn = xb + (size_t)((tile0 + ntt) * 16 + m) * 64 + qd * 8;
      bf16x8 n_lo = *(const bf16x8*)xn;
      bf16x8 n_hi = *(const bf16x8*)(xn + 32);
      int R0 = (tile0 + tt) * 16;
#pragma unroll
      for (int i = 0; i < 4; ++i) {
        f32x4 acc = {0.f, 0.f, 0.f, 0.f};
        acc = __builtin_amdgcn_mfma_f32_16x16x32_bf16(a_lo, wql[i], acc, 0, 0, 0);
        acc = __builtin_amdgcn_mfma_f32_16x16x32_bf16(a_hi, wqh[i], acc, 0, 0, 0);
        int col = (w * 4 + i) * 16 + m;
        unsigned char* obase = oq + (size_t)(R0 + qd * 4) * 256 + col;
#pragma unroll
        for (int r = 0; r < 4; ++r) {
          unsigned pk = __builtin_amdgcn_cvt_pk_fp8_f32(acc[r] + bqc[i], 0.f, 0, false);
          obase[(size_t)r * 256] = (unsigned char)pk;
        }
      }
      // fused skip: one more 64-col GEMM slice, f32 out
      {
        f32x4 sa = {0.f, 0.f, 0.f, 0.f};
        sa = __builtin_amdgcn_mfma_f32_16x16x32_bf16(a_lo, wsl_, sa, 0, 0, 0);
        sa = __builtin_amdgcn_mfma_f32_16x16x32_bf16(a_hi, wsh_, sa, 0, 0, 0);
        float* so = skip_out + (size_t)(R0 + qd * 4) * 64 + scol;
#pragma unroll
        for (int r = 0; r < 4; ++r)
          so[(size_t)r * 64] = sa[r] + bsc;
      }
      a_lo = n_lo; a_hi = n_hi;
    }
  }
}

// ---------------- fused aggregation for BOTH directions: one WAVE per node ----------------
// R18: fp8 kv rows (512B). R22: SGPR addressing. R23: fma-chain dots.
// R25: fp8 q rows (256B, uint/lane + 2 cvt) — halves q stream traffic.
__global__ __launch_bounds__(256) void agg_all(
    const unsigned char* __restrict__ q_small, const unsigned short* __restrict__ kv_big,
    const int* __restrict__ rp_st, const int* __restrict__ es_st,
    float* __restrict__ xt_nxt, unsigned short* __restrict__ xtb_nxt,
    const unsigned char* __restrict__ q_big, const unsigned short* __restrict__ kv_small,
    const int* __restrict__ rp_ts, const int* __restrict__ es_ts,
    float* __restrict__ xs_nxt, unsigned short* __restrict__ xsb_nxt,
    int relu, int stBlocks) {
  const unsigned char* q; const unsigned short* kvi; const int* rowptr; const int* eisrc;
  float* xout; unsigned short* xoutb; int node;
  int l = threadIdx.x & 63;
  int wv = __builtin_amdgcn_readfirstlane(threadIdx.x >> 6);   // wave-uniform -> SGPR
  if ((int)blockIdx.x < stBlocks) {
    node = blockIdx.x * 4 + wv;
    if (node >= NTGT) return;
    q = q_small; kvi = kv_big; rowptr = rp_st; eisrc = es_st; xout = xt_nxt; xoutb = xtb_nxt;
  } else {
    node = (blockIdx.x - stBlocks) * 4 + wv;
    if (node >= NSRC) return;
    q = q_big; kvi = kv_small; rowptr = rp_ts; eisrc = es_ts; xout = xs_nxt; xoutb = xsb_nxt;
  }
  int j = l & 15;
  unsigned qw = *(const unsigned*)(q + (size_t)node * 256 + l * 4);
  f32x2 qlo = __builtin_amdgcn_cvt_pk_f32_fp8(qw, false);
  f32x2 qhi = __builtin_amdgcn_cvt_pk_f32_fp8(qw, true);
  // fold 1/sqrt(H)=0.125 and log2(e) so the softmax uses raw v_exp (base-2)
  const float QS = 0.125f * 1.44269504088896340736f;
  float4 qf = make_float4(qlo.x * QS, qlo.y * QS, qhi.x * QS, qhi.y * QS);
  int beg = __builtin_amdgcn_readfirstlane(rowptr[node]);
  int end = __builtin_amdgcn_readfirstlane(rowptr[node + 1]);

  float lsum = 0.f;
  float4 acc = make_float4(0.f, 0.f, 0.f, 0.f);
  int p = beg;
  for (; p + 4 <= end; p += 4) {
    int s0 = __builtin_amdgcn_readfirstlane(eisrc[p]);
    int s1 = __builtin_amdgcn_readfirstlane(eisrc[p + 1]);
    int s2 = __builtin_amdgcn_readfirstlane(eisrc[p + 2]);
    int s3 = __builtin_amdgcn_readfirstlane(eisrc[p + 3]);
    uint2 a0 = ((const uint2*)(kvi + (size_t)s0 * 256))[l];
    uint2 a1 = ((const uint2*)(kvi + (size_t)s1 * 256))[l];
    uint2 a2 = ((const uint2*)(kvi + (size_t)s2 * 256))[l];
    uint2 a3 = ((const uint2*)(kvi + (size_t)s3 * 256))[l];
    f32x2 p00 = __builtin_amdgcn_cvt_pk_f32_fp8(a0.x, false);
    f32x2 p01 = __builtin_amdgcn_cvt_pk_f32_fp8(a0.x, true);
    f32x2 p02 = __builtin_amdgcn_cvt_pk_f32_fp8(a0.y, false);
    f32x2 p03 = __builtin_amdgcn_cvt_pk_f32_fp8(a0.y, true);
    f32x2 p10 = __builtin_amdgcn_cvt_pk_f32_fp8(a1.x, false);
    f32x2 p11 = __builtin_amdgcn_cvt_pk_f32_fp8(a1.x, true);
    f32x2 p12 = __builtin_amdgcn_cvt_pk_f32_fp8(a1.y, false);
    f32x2 p13 = __builtin_amdgcn_cvt_pk_f32_fp8(a1.y, true);
    f32x2 p20 = __builtin_amdgcn_cvt_pk_f32_fp8(a2.x, false);
    f32x2 p21 = __builtin_amdgcn_cvt_pk_f32_fp8(a2.x, true);
    f32x2 p22 = __builtin_amdgcn_cvt_pk_f32_fp8(a2.y, false);
    f32x2 p23 = __builtin_amdgcn_cvt_pk_f32_fp8(a2.y, true);
    f32x2 p30 = __builtin_amdgcn_cvt_pk_f32_fp8(a3.x, false);
    f32x2 p31 = __builtin_amdgcn_cvt_pk_f32_fp8(a3.x, true);
    f32x2 p32 = __builtin_amdgcn_cvt_pk_f32_fp8(a3.y, false);
    f32x2 p33 = __builtin_amdgcn_cvt_pk_f32_fp8(a3.y, true);
    float t0 = dot4f(qf, p00.x, p01.x, p02.x, p03.x);
    float t1 = dot4f(qf, p10.x, p11.x, p12.x, p13.x);
    float t2 = dot4f(qf, p20.x, p21.x, p22.x, p23.x);
    float t3 = dot4f(qf, p30.x, p31.x, p32.x, p33.x);
    t0 = red16(t0); t1 = red16(t1); t2 = red16(t2); t3 = red16(t3);
    float w0 = __builtin_amdgcn_exp2f(t0), w1 = __builtin_amdgcn_exp2f(t1);
    float w2 = __builtin_amdgcn_exp2f(t2), w3 = __builtin_amdgcn_exp2f(t3);
    lsum += (w0 + w1) + (w2 + w3);
    acc.x = fmaf(w0, p00.y, fmaf(w1, p10.y, fmaf(w2, p20.y, fmaf(w3, p30.y, acc.x))));
    acc.y = fmaf(w0, p01.y, fmaf(w1, p11.y, fmaf(w2, p21.y, fmaf(w3, p31.y, acc.y))));
    acc.z = fmaf(w0, p02.y, fmaf(w1, p12.y, fmaf(w2, p22.y, fmaf(w3, p32.y, acc.z))));
    acc.w = fmaf(w0, p03.y, fmaf(w1, p13.y, fmaf(w2, p23.y, fmaf(w3, p33.y, acc.w))));
  }
  for (; p < end; ++p) {
    int s0 = __builtin_amdgcn_readfirstlane(eisrc[p]);
    uint2 a0 = ((const uint2*)(kvi + (size_t)s0 * 256))[l];
    f32x2 p00 = __builtin_amdgcn_cvt_pk_f32_fp8(a0.x, false);
    f32x2 p01 = __builtin_amdgcn_cvt_pk_f32_fp8(a0.x, true);
    f32x2 p02 = __builtin_amdgcn_cvt_pk_f32_fp8(a0.y, false);
    f32x2 p03 = __builtin_amdgcn_cvt_pk_f32_fp8(a0.y, true);
    float s = dot4f(qf, p00.x, p01.x, p02.x, p03.x);
    s = red16(s);
    float w = __builtin_amdgcn_exp2f(s);
    lsum += w;
    acc.x = fmaf(w, p00.y, acc.x);
    acc.y = fmaf(w, p01.y, acc.y);
    acc.z = fmaf(w, p02.y, acc.z);
    acc.w = fmaf(w, p03.y, acc.w);
  }

  float inv = (lsum > 0.f) ? 1.f / lsum : 0.f;
  float4 r;
  r.x = acc.x * inv; r.y = acc.y * inv; r.z = acc.z * inv; r.w = acc.w * inv;
  r.x += __shfl_xor(r.x, 16, 64); r.x += __shfl_xor(r.x, 32, 64);
  r.y += __shfl_xor(r.y, 16, 64); r.y += __shfl_xor(r.y, 32, 64);
  r.z += __shfl_xor(r.z, 16, 64); r.z += __shfl_xor(r.z, 32, 64);
  r.w += __shfl_xor(r.w, 16, 64); r.w += __shfl_xor(r.w, 32, 64);
  if (l < 16) {
    float4 sk = *(const float4*)&xout[(size_t)node * HD + j * 4];
    float4 o;
    o.x = sk.x + 0.25f * r.x;
    o.y = sk.y + 0.25f * r.y;
    o.z = sk.z + 0.25f * r.z;
    o.w = sk.w + 0.25f * r.w;
    if (relu) {
      o.x = fmaxf(o.x, 0.f); o.y = fmaxf(o.y, 0.f);
      o.z = fmaxf(o.z, 0.f); o.w = fmaxf(o.w, 0.f);
    }
    *(float4*)&xout[(size_t)node * HD + j * 4] = o;
    bf4 ob;
    ob.x = f2bf(o.x); ob.y = f2bf(o.y); ob.z = f2bf(o.z); ob.w = f2bf(o.w);
    *(bf4*)&xoutb[(size_t)node * HD + j * 4] = ob;
  }
}

// ---------------- classifier: 16 lanes per pair, float4 loads ----------------
__global__ __launch_bounds__(256) void classifier_kernel(const float* __restrict__ xs, const float* __restrict__ xt,
    const int* __restrict__ ls, const int* __restrict__ lt, float* __restrict__ out, int n) {
  int g = blockIdx.x * 256 + threadIdx.x;
  int pair = g >> 4, j = g & 15;
  if (pair >= n) return;
  int a = ls[pair], b = lt[pair];
  float4 xa = *(const float4*)&xs[(size_t)a * HD + j * 4];
  float4 xb = *(const float4*)&xt[(size_t)b * HD + j * 4];
  float s = fmaf(xa.w, xb.w, fmaf(xa.z, xb.z, fmaf(xa.y, xb.y, xa.x * xb.x)));
  s = red16(s);
  if (j == 0) out[pair] = s;
}

// ---------------- launch ----------------
extern "C" void kernel_launch(void* const* d_in, const int* in_sizes, int n_in,
                              void* d_out, int out_size, void* d_ws, size_t ws_size,
                              hipStream_t stream) {
  const float* src_emb = (const float*)d_in[0];
  const float* tgt_emb = (const float*)d_in[1];
  const float* Wq = (const float*)d_in[2];
  const float* bq = (const float*)d_in[3];
  const float* Wk = (const float*)d_in[4];
  const float* bk = (const float*)d_in[5];
  const float* Wv = (const float*)d_in[6];
  const float* bv = (const float*)d_in[7];
  const float* Wsk = (const float*)d_in[8];
  const float* bsk = (const float*)d_in[9];
  const int* nid_s = (const int*)d_in[10];
  const int* nid_t = (const int*)d_in[11];
  const int* e_st = (const int*)d_in[12];
  const int* e_ts = (const int*)d_in[13];
  const int* e_lbl = (const int*)d_in[14];
  float* out = (float*)d_out;

  char* ws = (char*)d_ws;
  size_t off = 0;
  auto alloc = [&](size_t bytes) -> void* {
    void* p = ws + off;
    off += (bytes + 255) & ~(size_t)255;
    return p;
  };
  unsigned short* kv_big   = (unsigned short*)alloc((size_t)NSRC * 256 * 2);  // st k/v fp8 pairs
  unsigned char*  q_big    = (unsigned char*)alloc((size_t)NSRC * 256);       // ts q fp8
  unsigned short* kv_small = (unsigned short*)alloc((size_t)NTGT * 256 * 2);  // ts k/v fp8 pairs
  unsigned char*  q_small  = (unsigned char*)alloc((size_t)NTGT * 256);       // st q fp8
  float* xsA = (float*)alloc((size_t)NSRC * HD * 4);
  float* xsB = (float*)alloc((size_t)NSRC * HD * 4);
  float* xtA = (float*)alloc((size_t)NTGT * HD * 4);
  float* xtB = (float*)alloc((size_t)NTGT * HD * 4);
  unsigned short* xsAb = (unsigned short*)alloc((size_t)NSRC * HD * 2);
  unsigned short* xsBb = (unsigned short*)alloc((size_t)NSRC * HD * 2);
  unsigned short* xtAb = (unsigned short*)alloc((size_t)NTGT * HD * 2);
  unsigned short* xtBb = (unsigned short*)alloc((size_t)NTGT * HD * 2);
  unsigned short* Wtq = (unsigned short*)alloc((size_t)4 * 16384 * 2);
  unsigned short* Wtk = (unsigned short*)alloc((size_t)4 * 16384 * 2);
  unsigned short* Wtv = (unsigned short*)alloc((size_t)4 * 16384 * 2);
  unsigned short* Wts = (unsigned short*)alloc((size_t)4 * 4096 * 2);
  int* rp_st = (int*)alloc((size_t)(NTGT + 1) * 4);
  int* es_st = (int*)alloc((size_t)NEDGE * 4);
  int* rp_ts = (int*)alloc((size_t)(NSRC + 1) * 4);
  int* es_ts = (int*)alloc((size_t)NEDGE * 4);
  int* cursor = (int*)alloc((size_t)NTOT * 4);
  int* counts = (int*)alloc((size_t)NTOT * 4);
  int* incl_buf = (int*)alloc((size_t)NTOT * 4);
  int* blocksums = (int*)alloc(64 * 4);
  int* boff = (int*)alloc(64 * 4);
  (void)ws_size; (void)in_sizes; (void)n_in; (void)out_size;

  auto cdiv = [](int a, int b) { return (a + b - 1) / b; };
  const int GATHER_BLK = cdiv(NTOT * HD, 256);          // 15000
  const int SETUP_BLK = 52 + GATHER_BLK + cdiv(NTOT, 256);
  const int G1 = cdiv(NSRC / 16, 8);                    // 391
  const int G2 = cdiv(NTGT / 16, 8);                    // 79
  const int NBLK_PROJ = 2 * (G1 + G2);                  // 940
  const int ST_BLK = cdiv(NTGT, 4);                     // 2500
  const int NBLK_AGG = ST_BLK + cdiv(NSRC, 4);          // 15000

  // fused setup: weight transposes (qkv + skip) + feature gather (bf16 only) + counts zero
  setup_kernel<<<SETUP_BLK, 256, 0, stream>>>(Wq, Wk, Wv, Wsk, Wtq, Wtk, Wtv, Wts,
                                              src_emb, nid_s, tgt_emb, nid_t,
                                              xsAb, xtAb, counts, GATHER_BLK);

  // CSR build for both edge sets
  hist_all_kernel<<<cdiv(2 * NEDGE, 256), 256, 0, stream>>>(e_st, e_ts, counts);
  scan1_kernel<<<cdiv(NTOT, 1024), 256, 0, stream>>>(counts, incl_buf, blocksums, NTOT);
  scan2_kernel<<<1, 64, 0, stream>>>(blocksums, boff, cdiv(NTOT, 1024));
  scan3_kernel<<<cdiv(NTOT, 256), 256, 0, stream>>>(incl_buf, counts, boff, rp_st, rp_ts, cursor);
  scatter_all_kernel<<<cdiv(2 * NEDGE, 256), 256, 0, stream>>>(e_st, e_ts, cursor, es_st, es_ts);

  float* xs_cur = xsA; float* xs_nxt = xsB;
  float* xt_cur = xtA; float* xt_nxt = xtB;
  const unsigned short* xsb_cur = xsAb; unsigned short* xsb_nxt = xsBb;
  const unsigned short* xtb_cur = xtAb; unsigned short* xtb_nxt = xtBb;
  for (int l = 0; l < 2; ++l) {
    int relu = (l == 0) ? 1 : 0;
    int p_st = l * 2 + 0, p_ts = l * 2 + 1;
    proj_all<<<NBLK_PROJ, 256, 0, stream>>>(xsb_cur, xtb_cur, Wtq, Wtk, Wtv, Wts,
                                            bq, bk, bv, bsk,
                                            kv_big, q_big, kv_small, q_small,
                                            xs_nxt, xt_nxt, p_st, p_ts);
    agg_all<<<NBLK_AGG, 256, 0, stream>>>(q_small, kv_big, rp_st, es_st, xt_nxt, xtb_nxt,
                                          q_big, kv_small, rp_ts, es_ts, xs_nxt, xsb_nxt,
                                          relu, ST_BLK);
    { float* t = xs_nxt; xs_nxt = xs_cur; xs_cur = t; }
    { float* t = xt_nxt; xt_nxt = xt_cur; xt_cur = t; }
    { const unsigned short* t = xsb_nxt; xsb_nxt = (unsigned short*)xsb_cur; xsb_cur = t; }
    { const unsigned short* t = xtb_nxt; xtb_nxt = (unsigned short*)xtb_cur; xtb_cur = t; }
  }

  classifier_kernel<<<cdiv(NLBL * 16, 256), 256, 0, stream>>>(xs_cur, xt_cur, e_lbl, e_lbl + NLBL, out, NLBL);
}